// Round 1
// baseline (2886.116 us; speedup 1.0000x reference)
//
#include <hip/hip_runtime.h>
#include <hip/hip_bf16.h>
#include <math.h>

#define DPROJ 2320
#define CONVD 1280

__device__ __forceinline__ float siluf(float x) { return x / (1.f + __expf(-x)); }

// ---------------- small prep kernels ----------------

__global__ void gather_kernel(const int* __restrict__ pidx, const float* __restrict__ pertE,
                              float* __restrict__ cemb) {
    int idx = blockIdx.x * 256 + threadIdx.x;   // 1024
    int b = idx >> 7, k = idx & 127;
    cemb[idx] = pertE[(size_t)pidx[b] * 128 + k];
}

__global__ void wfold_kernel(const float* __restrict__ headW,
                             const float* __restrict__ fOutW, const float* __restrict__ fNw,
                             const float* __restrict__ bOutW, const float* __restrict__ bNw,
                             float* __restrict__ wf2, float* __restrict__ wb2) {
    int idx = blockIdx.x * 256 + threadIdx.x;   // 2048
    int dir = idx >> 10, d = idx & 1023;
    const float* W  = dir ? bOutW : fOutW;
    const float* nw = dir ? bNw : fNw;
    float s = 0.f;
    for (int m = 0; m < 512; ++m) s += headW[m] * W[(size_t)m * 1024 + d];
    (dir ? wb2 : wf2)[d] = s * nw[d];
}

__global__ void genefeat_kernel(const int* __restrict__ chridx, const float* __restrict__ gid,
                                const float* __restrict__ path, const float* __restrict__ chrE,
                                float* __restrict__ gf) {
    int idx = blockIdx.x * 256 + threadIdx.x;   // 2048*384
    int g = idx / 384, j = idx % 384;
    float v;
    if (j < 128)      v = gid[(size_t)g * 128 + j];
    else if (j < 256) v = path[(size_t)g * 128 + (j - 128)];
    else if (j < 320) v = chrE[(size_t)chridx[g] * 64 + (j - 256)];
    else return;      // cols 320..383 written by the locus GEMM
    gf[idx] = v;
}

// ---------------- generic tiled fp32 GEMM: C[m,n] = act(bias[n] + sum_k A[m,k]*W[n,k]) ----------------

__global__ __launch_bounds__(256) void gemm_kernel(
    const float* __restrict__ A, const float* __restrict__ W,
    const float* __restrict__ bias, float* __restrict__ C,
    int M, int N, int K, int ldc, int act) {
    __shared__ __align__(16) float As[16][68];
    __shared__ __align__(16) float Ws[16][68];
    const int tid = threadIdx.x;
    const int tx = tid & 15, ty = tid >> 4;
    const int bm = blockIdx.y * 64, bn = blockIdx.x * 64;
    const int lr = tid >> 2;
    const int lk = (tid & 3) * 4;
    float acc[4][4];
#pragma unroll
    for (int i = 0; i < 4; ++i)
#pragma unroll
        for (int j = 0; j < 4; ++j) acc[i][j] = 0.f;

    for (int k0 = 0; k0 < K; k0 += 16) {
        const int am = bm + lr;
        const int wn = bn + lr;
        float4 av = make_float4(0.f, 0.f, 0.f, 0.f), wv = make_float4(0.f, 0.f, 0.f, 0.f);
        if (am < M) av = *(const float4*)&A[(size_t)am * K + k0 + lk];
        if (wn < N) wv = *(const float4*)&W[(size_t)wn * K + k0 + lk];
        __syncthreads();
        As[lk + 0][lr] = av.x; As[lk + 1][lr] = av.y; As[lk + 2][lr] = av.z; As[lk + 3][lr] = av.w;
        Ws[lk + 0][lr] = wv.x; Ws[lk + 1][lr] = wv.y; Ws[lk + 2][lr] = wv.z; Ws[lk + 3][lr] = wv.w;
        __syncthreads();
#pragma unroll
        for (int kk = 0; kk < 16; ++kk) {
            float4 a = *(const float4*)&As[kk][ty * 4];
            float4 w = *(const float4*)&Ws[kk][tx * 4];
            float aa[4] = {a.x, a.y, a.z, a.w}, ww[4] = {w.x, w.y, w.z, w.w};
#pragma unroll
            for (int i = 0; i < 4; ++i)
#pragma unroll
                for (int j = 0; j < 4; ++j) acc[i][j] += aa[i] * ww[j];
        }
    }
#pragma unroll
    for (int i = 0; i < 4; ++i) {
        const int m = bm + ty * 4 + i;
        if (m >= M) continue;
#pragma unroll
        for (int j = 0; j < 4; ++j) {
            const int n = bn + tx * 4 + j;
            if (n >= N) continue;
            float v = acc[i][j] + (bias ? bias[n] : 0.f);
            if (act == 1) v = 0.5f * v * (1.f + erff(v * 0.70710678118654752f));
            C[(size_t)m * ldc + n] = v;
        }
    }
}

// ---------------- dt / dA precompute ----------------

__global__ void dt_kernel(const float* __restrict__ zx, const float* __restrict__ dt_bias,
                          const float* __restrict__ A_log, float* __restrict__ dt_o,
                          float* __restrict__ dA_o, int flip) {
    int idx = blockIdx.x * 256 + threadIdx.x;   // 32768
    int r = idx >> 4, h = idx & 15;
    int row = flip ? (2047 - r) : r;
    float raw = zx[(size_t)row * DPROJ + 2304 + h] + dt_bias[h];
    float dt = (raw > 20.f) ? raw : log1pf(expf(raw));
    float dA = expf(-dt * expf(A_log[h]));
    dt_o[idx] = dt;
    dA_o[idx] = dA;
}

__global__ void dtpb_kernel(const float* __restrict__ zxc, const float* __restrict__ dt_bias,
                            const float* __restrict__ A_log, float* __restrict__ dt_o,
                            float* __restrict__ dA_o) {
    int idx = threadIdx.x;   // 128
    int b = idx >> 4, h = idx & 15;
    float raw = zxc[(size_t)b * DPROJ + 2304 + h] + dt_bias[h];
    float dt = (raw > 20.f) ? raw : log1pf(expf(raw));
    float dA = expf(-dt * expf(A_log[h]));
    dt_o[idx] = dt;
    dA_o[idx] = dA;
}

// ---------------- causal depthwise conv (+SiLU) ----------------

// shared fwd conv, t = 4..2048, stored at [t-4][c]
__global__ void convFsh_kernel(const float* __restrict__ zxf, const float* __restrict__ cw,
                               const float* __restrict__ cb, float* __restrict__ outp) {
    int idx = blockIdx.x * 256 + threadIdx.x;
    if (idx >= 2045 * 1280) return;
    int t4 = idx / 1280, c = idx % 1280;
    float4 w4 = *(const float4*)&cw[c * 4];
    float acc = cb[c];
    acc += zxf[(size_t)(t4 + 0) * DPROJ + 1024 + c] * w4.x;
    acc += zxf[(size_t)(t4 + 1) * DPROJ + 1024 + c] * w4.y;
    acc += zxf[(size_t)(t4 + 2) * DPROJ + 1024 + c] * w4.z;
    acc += zxf[(size_t)(t4 + 3) * DPROJ + 1024 + c] * w4.w;
    outp[idx] = siluf(acc);
}

// per-batch fwd conv, t = 0..3  [b][t][c]
__global__ void convFpb_kernel(const float* __restrict__ zxf, const float* __restrict__ zxc,
                               const float* __restrict__ cw, const float* __restrict__ cb,
                               float* __restrict__ outp) {
    int idx = blockIdx.x * 256 + threadIdx.x;   // 8*4*1280
    int b = idx / 5120;
    int r = idx % 5120;
    int t = r / 1280, c = r % 1280;
    float4 w4 = *(const float4*)&cw[c * 4];
    float w[4] = {w4.x, w4.y, w4.z, w4.w};
    float acc = cb[c];
#pragma unroll
    for (int k = 0; k < 4; ++k) {
        int j = t - 3 + k;
        float x = 0.f;
        if (j == 0)      x = zxc[(size_t)b * DPROJ + 1024 + c];
        else if (j >= 1) x = zxf[(size_t)(j - 1) * DPROJ + 1024 + c];
        acc += x * w[k];
    }
    outp[idx] = siluf(acc);
}

// shared bwd conv over flipped sequence, s = 0..2047 (cond never enters)
__global__ void convBsh_kernel(const float* __restrict__ zxb, const float* __restrict__ cw,
                               const float* __restrict__ cb, float* __restrict__ outp) {
    int idx = blockIdx.x * 256 + threadIdx.x;   // 2048*1280
    int s = idx / 1280, c = idx % 1280;
    float4 w4 = *(const float4*)&cw[c * 4];
    float w[4] = {w4.x, w4.y, w4.z, w4.w};
    float acc = cb[c];
#pragma unroll
    for (int k = 0; k < 4; ++k) {
        int j = s - 3 + k;
        if (j >= 0) acc += zxb[(size_t)(2047 - j) * DPROJ + 1024 + c] * w[k];
    }
    outp[idx] = siluf(acc);
}

// ---------------- the combined fwd+bwd selective scan ----------------
// blocks 0..127: fwd (b = blk>>4, h = blk&15), T=2049, per-batch first 4 steps
// blocks 128..143: bwd shared (h = blk-128), T=2048
// thread layout: pblk = tid>>4 (owns p = pblk*4+i), nblk = tid&15 (owns n = nblk*8+j)
// emits per-step per-pblk pair (sum g*w, sum g^2); final kernel reduces + RMSNorm + dot.

__global__ __launch_bounds__(256) void scan_kernel(
    const float* __restrict__ convFs, const float* __restrict__ convFp,
    const float* __restrict__ zx_f,
    const float* __restrict__ dtFs, const float* __restrict__ dAFs,
    const float* __restrict__ dtFp, const float* __restrict__ dAFp,
    const float* __restrict__ fD, const float* __restrict__ wf2,
    float* __restrict__ yF,
    const float* __restrict__ convBs, const float* __restrict__ zx_b,
    const float* __restrict__ dtBs, const float* __restrict__ dABs,
    const float* __restrict__ bD, const float* __restrict__ wb2,
    float* __restrict__ yB) {
    const int tid = threadIdx.x;
    const int blk = blockIdx.x;
    const bool fwd = blk < 128;
    const int b = fwd ? (blk >> 4) : 0;
    const int h = fwd ? (blk & 15) : (blk - 128);
    const int T = fwd ? 2049 : 2048;

    const float* Dv = fwd ? fD : bD;
    const float* wv = fwd ? wf2 : wb2;
    float* yout = fwd ? yF : yB;

    const int nblk = tid & 15;
    const int pblk = tid >> 4;

    __shared__ __align__(16) float sx[2][64];
    __shared__ __align__(16) float sz[2][64];
    __shared__ __align__(16) float sBC[2][384];
    __shared__ float smisc[2][2];

    float hs[4][8];
#pragma unroll
    for (int i = 0; i < 4; ++i)
#pragma unroll
        for (int j = 0; j < 8; ++j) hs[i][j] = 0.f;

    float wreg[4];
    const float Dh = Dv[h];
#pragma unroll
    for (int i = 0; i < 4; ++i) wreg[i] = wv[h * 64 + pblk * 4 + i];

    auto rowp = [&](int t) -> const float* {
        if (fwd) return (t < 4) ? (convFp + (size_t)(b * 4 + t) * CONVD)
                                : (convFs + (size_t)(t - 4) * CONVD);
        return convBs + (size_t)t * CONVD;
    };
    auto zrowp = [&](int t) -> const float* {
        if (fwd) return zx_f + (size_t)(t - 1) * DPROJ;   // only valid t>=1
        return zx_b + (size_t)(2047 - t) * DPROJ;
    };
    auto dtp = [&](int t) -> const float* {
        if (fwd) return (t == 0) ? (dtFp + b * 16 + h) : (dtFs + (size_t)(t - 1) * 16 + h);
        return dtBs + (size_t)t * 16 + h;
    };
    auto dApp = [&](int t) -> const float* {
        if (fwd) return (t == 0) ? (dAFp + b * 16 + h) : (dAFs + (size_t)(t - 1) * 16 + h);
        return dABs + (size_t)t * 16 + h;
    };

    auto fetch = [&](int v, const float* row, const float* zr, bool zok,
                     const float* dq, const float* aq) -> float {
        if (v < 64) return row[h * 64 + v];
        if (v < 320) return row[1024 + (v - 64)];
        if (v < 384) return zok ? zr[h * 64 + (v - 320)] : 0.f;
        if (v == 384) return *dq;
        return *aq;
    };
    auto stash = [&](int v, float x, int buf) {
        if (v < 64) sx[buf][v] = x;
        else if (v < 320) { int n = v - 64; sBC[buf][(n >> 3) * 12 + (n & 7)] = x; }
        else if (v < 384) sz[buf][v - 320] = x;
        else smisc[buf][v - 384] = x;
    };

    {   // prologue: stage t=0 into buffer 0
        const float* row = rowp(0);
        const float* zr = zrowp(fwd ? 1 : 0);   // dummy-safe pointer for fwd t=0
        bool zok = !fwd;
        const float* dq = dtp(0);
        const float* aq = dApp(0);
        stash(tid, fetch(tid, row, zr, zok, dq, aq), 0);
        if (tid < 130) stash(tid + 256, fetch(tid + 256, row, zr, zok, dq, aq), 0);
    }
    __syncthreads();

    for (int t = 0; t < T; ++t) {
        const int cur = t & 1, nxt = cur ^ 1;
        float r0 = 0.f, r1 = 0.f;
        const bool havenext = (t + 1) < T;
        if (havenext) {   // issue prefetch loads, consumed after compute
            const float* row = rowp(t + 1);
            const float* zr = zrowp(t + 1);
            const float* dq = dtp(t + 1);
            const float* aq = dApp(t + 1);
            r0 = fetch(tid, row, zr, true, dq, aq);
            if (tid < 130) r1 = fetch(tid + 256, row, zr, true, dq, aq);
        }
        // compute step t from LDS[cur]
        const float dtv = smisc[cur][0];
        const float dAv = smisc[cur][1];
        float4 xv4 = *(const float4*)&sx[cur][pblk * 4];
        float xv[4] = {xv4.x, xv4.y, xv4.z, xv4.w};
        const float4 B0 = *(const float4*)&sBC[cur][nblk * 12];
        const float4 B1 = *(const float4*)&sBC[cur][nblk * 12 + 4];
        const float4 C0 = *(const float4*)&sBC[cur][(16 + nblk) * 12];
        const float4 C1 = *(const float4*)&sBC[cur][(16 + nblk) * 12 + 4];
        float Bv[8] = {B0.x, B0.y, B0.z, B0.w, B1.x, B1.y, B1.z, B1.w};
        float Cv[8] = {C0.x, C0.y, C0.z, C0.w, C1.x, C1.y, C1.z, C1.w};
        float part[4] = {0.f, 0.f, 0.f, 0.f};
#pragma unroll
        for (int i = 0; i < 4; ++i) {
            const float cxi = dtv * xv[i];
#pragma unroll
            for (int j = 0; j < 8; ++j) {
                hs[i][j] = dAv * hs[i][j] + cxi * Bv[j];
                part[i] += hs[i][j] * Cv[j];
            }
        }
#pragma unroll
        for (int m = 1; m < 16; m <<= 1) {
#pragma unroll
            for (int i = 0; i < 4; ++i) part[i] += __shfl_xor(part[i], m);
        }
        const bool emit = fwd ? (t >= 1) : true;
        if (emit && nblk == 0) {
            float4 zv4 = *(const float4*)&sz[cur][pblk * 4];
            float zv[4] = {zv4.x, zv4.y, zv4.z, zv4.w};
            float a1 = 0.f, a2 = 0.f;
#pragma unroll
            for (int i = 0; i < 4; ++i) {
                float yvi = part[i] + Dh * xv[i];
                float gvi = yvi * siluf(zv[i]);
                a2 += gvi * gvi;
                a1 += gvi * wreg[i];
            }
            size_t oidx;
            if (fwd) oidx = ((((size_t)b * 2049 + t) * 16 + h) * 16 + pblk) * 2;
            else     oidx = (((size_t)t * 16 + h) * 16 + pblk) * 2;
            yout[oidx]     = a1;
            yout[oidx + 1] = a2;
        }
        if (havenext) {
            stash(tid, r0, nxt);
            if (tid < 130) stash(tid + 256, r1, nxt);
        }
        __syncthreads();
    }
}

// ---------------- final combine: reduce partials, RMSNorm, add directions + head bias ----------------

__global__ __launch_bounds__(64) void final_kernel(
    const float* __restrict__ yF, const float* __restrict__ yB,
    const float* __restrict__ headB, float* __restrict__ out) {
    const int o = blockIdx.x;   // 0..16383
    const int b = o >> 11, g = o & 2047;
    const int tid = threadIdx.x;
    const float4* fp = (const float4*)(yF + ((size_t)b * 2049 + (g + 1)) * 512);
    const float4* bp = (const float4*)(yB + ((size_t)(2047 - g)) * 512);
    float f1 = 0.f, f2 = 0.f, b1 = 0.f, b2 = 0.f;
#pragma unroll
    for (int q = 0; q < 2; ++q) {
        float4 v = fp[tid * 2 + q];
        f1 += v.x + v.z; f2 += v.y + v.w;
        float4 u = bp[tid * 2 + q];
        b1 += u.x + u.z; b2 += u.y + u.w;
    }
#pragma unroll
    for (int m = 32; m >= 1; m >>= 1) {
        f1 += __shfl_down(f1, m);
        f2 += __shfl_down(f2, m);
        b1 += __shfl_down(b1, m);
        b2 += __shfl_down(b2, m);
    }
    if (tid == 0)
        out[o] = f1 * rsqrtf(f2 * (1.f / 1024.f) + 1e-5f) +
                 b1 * rsqrtf(b2 * (1.f / 1024.f) + 1e-5f) + headB[0];
}

// ---------------- launch ----------------

extern "C" void kernel_launch(void* const* d_in, const int* in_sizes, int n_in,
                              void* d_out, int out_size, void* d_ws, size_t ws_size,
                              hipStream_t stream) {
    const int*   pidx   = (const int*)  d_in[0];
    const int*   chridx = (const int*)  d_in[1];
    const float* locusF = (const float*)d_in[2];
    const float* pathF  = (const float*)d_in[3];
    const float* pertE  = (const float*)d_in[4];
    const float* gidE   = (const float*)d_in[5];
    const float* chrE   = (const float*)d_in[6];
    const float* locusW = (const float*)d_in[7];
    const float* locusB = (const float*)d_in[8];
    const float* condW  = (const float*)d_in[9];
    const float* condB  = (const float*)d_in[10];
    const float* inW    = (const float*)d_in[11];
    const float* inB    = (const float*)d_in[12];
    const float* headW  = (const float*)d_in[13];
    const float* headB  = (const float*)d_in[14];
    const float* fInW   = (const float*)d_in[15];
    const float* fCw    = (const float*)d_in[16];
    const float* fCb    = (const float*)d_in[17];
    const float* fDtB   = (const float*)d_in[18];
    const float* fAlog  = (const float*)d_in[19];
    const float* fDp    = (const float*)d_in[20];
    const float* fNw    = (const float*)d_in[21];
    const float* fOutW  = (const float*)d_in[22];
    const float* bInW   = (const float*)d_in[23];
    const float* bCw    = (const float*)d_in[24];
    const float* bCb    = (const float*)d_in[25];
    const float* bDtB   = (const float*)d_in[26];
    const float* bAlog  = (const float*)d_in[27];
    const float* bDp    = (const float*)d_in[28];
    const float* bNw    = (const float*)d_in[29];
    const float* bOutW  = (const float*)d_in[30];
    float* out = (float*)d_out;
    (void)in_sizes; (void)n_in; (void)out_size; (void)ws_size;

    float* ws = (float*)d_ws;
    size_t off = 0;
    auto alloc = [&](size_t n) { size_t r = off; off += (n + 15) & ~(size_t)15; return r; };
    float* gf     = ws + alloc(2048UL * 384);
    float* cond   = ws + alloc(8UL * 384);
    float* cemb   = ws + alloc(8UL * 128);
    float* ug     = ws + alloc(2048UL * 512);
    float* uc     = ws + alloc(8UL * 512);
    float* zxf    = ws + alloc(2048UL * DPROJ);
    float* zxb    = ws + alloc(2048UL * DPROJ);
    float* zxc    = ws + alloc(8UL * DPROJ);
    float* convFs = ws + alloc(2045UL * CONVD);
    float* convFp = ws + alloc(8UL * 4 * CONVD);
    float* convBs = ws + alloc(2048UL * CONVD);
    float* dtFs   = ws + alloc(2048UL * 16);
    float* dAFs   = ws + alloc(2048UL * 16);
    float* dtFp   = ws + alloc(128);
    float* dAFp   = ws + alloc(128);
    float* dtBs   = ws + alloc(2048UL * 16);
    float* dABs   = ws + alloc(2048UL * 16);
    float* wf2    = ws + alloc(1024);
    float* wb2    = ws + alloc(1024);
    float* yF     = ws + alloc(8UL * 2049 * 512);
    float* yB     = ws + alloc(2048UL * 512);

    gather_kernel<<<4, 256, 0, stream>>>(pidx, pertE, cemb);
    wfold_kernel<<<8, 256, 0, stream>>>(headW, fOutW, fNw, bOutW, bNw, wf2, wb2);
    genefeat_kernel<<<3072, 256, 0, stream>>>(chridx, gidE, pathF, chrE, gf);
    gemm_kernel<<<dim3(1, 32), 256, 0, stream>>>(locusF, locusW, locusB, gf + 320, 2048, 64, 64, 384, 1);
    gemm_kernel<<<dim3(6, 1), 256, 0, stream>>>(cemb, condW, condB, cond, 8, 384, 128, 384, 0);
    gemm_kernel<<<dim3(8, 32), 256, 0, stream>>>(gf, inW, inB, ug, 2048, 512, 384, 512, 0);
    gemm_kernel<<<dim3(8, 1), 256, 0, stream>>>(cond, inW, inB, uc, 8, 512, 384, 512, 0);
    gemm_kernel<<<dim3(37, 32), 256, 0, stream>>>(ug, fInW, nullptr, zxf, 2048, DPROJ, 512, DPROJ, 0);
    gemm_kernel<<<dim3(37, 32), 256, 0, stream>>>(ug, bInW, nullptr, zxb, 2048, DPROJ, 512, DPROJ, 0);
    gemm_kernel<<<dim3(37, 1), 256, 0, stream>>>(uc, fInW, nullptr, zxc, 8, DPROJ, 512, DPROJ, 0);
    dt_kernel<<<128, 256, 0, stream>>>(zxf, fDtB, fAlog, dtFs, dAFs, 0);
    dt_kernel<<<128, 256, 0, stream>>>(zxb, bDtB, bAlog, dtBs, dABs, 1);
    dtpb_kernel<<<1, 128, 0, stream>>>(zxc, fDtB, fAlog, dtFp, dAFp);
    convFsh_kernel<<<(2045 * 1280 + 255) / 256, 256, 0, stream>>>(zxf, fCw, fCb, convFs);
    convFpb_kernel<<<160, 256, 0, stream>>>(zxf, zxc, fCw, fCb, convFp);
    convBsh_kernel<<<10240, 256, 0, stream>>>(zxb, bCw, bCb, convBs);
    scan_kernel<<<144, 256, 0, stream>>>(convFs, convFp, zxf, dtFs, dAFs, dtFp, dAFp,
                                         fDp, wf2, yF, convBs, zxb, dtBs, dABs, bDp, wb2, yB);
    final_kernel<<<16384, 64, 0, stream>>>(yF, yB, headB, out);
}

// Round 2
// 659.761 us; speedup vs baseline: 4.3745x; 4.3745x over previous
//
#include <hip/hip_runtime.h>
#include <hip/hip_bf16.h>
#include <math.h>

#define DPROJ 2320
#define CONVD 1280

__device__ __forceinline__ float siluf(float x) { return x / (1.f + __expf(-x)); }
__device__ __forceinline__ float bfu(unsigned short s) { return __uint_as_float(((unsigned)s) << 16); }
__device__ __forceinline__ unsigned short f2bf(float f) {
    unsigned u = __float_as_uint(f);
    unsigned r = (u + 0x7FFFu + ((u >> 16) & 1u)) >> 16;
    return (unsigned short)r;
}

// ---------------- small prep kernels ----------------

__global__ void gather_kernel(const int* __restrict__ pidx, const float* __restrict__ pertE,
                              float* __restrict__ cemb) {
    int idx = blockIdx.x * 256 + threadIdx.x;   // 1024
    int b = idx >> 7, k = idx & 127;
    cemb[idx] = pertE[(size_t)pidx[b] * 128 + k];
}

__global__ void wfold_kernel(const float* __restrict__ headW,
                             const float* __restrict__ fOutW, const float* __restrict__ fNw,
                             const float* __restrict__ bOutW, const float* __restrict__ bNw,
                             float* __restrict__ wf2, float* __restrict__ wb2) {
    int idx = blockIdx.x * 256 + threadIdx.x;   // 2048
    int dir = idx >> 10, d = idx & 1023;
    const float* W  = dir ? bOutW : fOutW;
    const float* nw = dir ? bNw : fNw;
    float s = 0.f;
    for (int m = 0; m < 512; ++m) s += headW[m] * W[(size_t)m * 1024 + d];
    (dir ? wb2 : wf2)[d] = s * nw[d];
}

__global__ void genefeat_kernel(const int* __restrict__ chridx, const float* __restrict__ gid,
                                const float* __restrict__ path, const float* __restrict__ chrE,
                                float* __restrict__ gf) {
    int idx = blockIdx.x * 256 + threadIdx.x;   // 2048*384
    int g = idx / 384, j = idx % 384;
    float v;
    if (j < 128)      v = gid[(size_t)g * 128 + j];
    else if (j < 256) v = path[(size_t)g * 128 + (j - 128)];
    else if (j < 320) v = chrE[(size_t)chridx[g] * 64 + (j - 256)];
    else return;      // cols 320..383 written by the locus GEMM
    gf[idx] = v;
}

// ---------------- generic tiled fp32 GEMM ----------------

__global__ __launch_bounds__(256) void gemm_kernel(
    const float* __restrict__ A, const float* __restrict__ W,
    const float* __restrict__ bias, float* __restrict__ C,
    int M, int N, int K, int ldc, int act) {
    __shared__ __align__(16) float As[16][68];
    __shared__ __align__(16) float Ws[16][68];
    const int tid = threadIdx.x;
    const int tx = tid & 15, ty = tid >> 4;
    const int bm = blockIdx.y * 64, bn = blockIdx.x * 64;
    const int lr = tid >> 2;
    const int lk = (tid & 3) * 4;
    float acc[4][4];
#pragma unroll
    for (int i = 0; i < 4; ++i)
#pragma unroll
        for (int j = 0; j < 4; ++j) acc[i][j] = 0.f;

    for (int k0 = 0; k0 < K; k0 += 16) {
        const int am = bm + lr;
        const int wn = bn + lr;
        float4 av = make_float4(0.f, 0.f, 0.f, 0.f), wv = make_float4(0.f, 0.f, 0.f, 0.f);
        if (am < M) av = *(const float4*)&A[(size_t)am * K + k0 + lk];
        if (wn < N) wv = *(const float4*)&W[(size_t)wn * K + k0 + lk];
        __syncthreads();
        As[lk + 0][lr] = av.x; As[lk + 1][lr] = av.y; As[lk + 2][lr] = av.z; As[lk + 3][lr] = av.w;
        Ws[lk + 0][lr] = wv.x; Ws[lk + 1][lr] = wv.y; Ws[lk + 2][lr] = wv.z; Ws[lk + 3][lr] = wv.w;
        __syncthreads();
#pragma unroll
        for (int kk = 0; kk < 16; ++kk) {
            float4 a = *(const float4*)&As[kk][ty * 4];
            float4 w = *(const float4*)&Ws[kk][tx * 4];
            float aa[4] = {a.x, a.y, a.z, a.w}, ww[4] = {w.x, w.y, w.z, w.w};
#pragma unroll
            for (int i = 0; i < 4; ++i)
#pragma unroll
                for (int j = 0; j < 4; ++j) acc[i][j] += aa[i] * ww[j];
        }
    }
#pragma unroll
    for (int i = 0; i < 4; ++i) {
        const int m = bm + ty * 4 + i;
        if (m >= M) continue;
#pragma unroll
        for (int j = 0; j < 4; ++j) {
            const int n = bn + tx * 4 + j;
            if (n >= N) continue;
            float v = acc[i][j] + (bias ? bias[n] : 0.f);
            if (act == 1) v = 0.5f * v * (1.f + erff(v * 0.70710678118654752f));
            C[(size_t)m * ldc + n] = v;
        }
    }
}

// ---------------- dt precompute ----------------

__global__ void dt_kernel(const float* __restrict__ zx, const float* __restrict__ dt_bias,
                          float* __restrict__ dt_o, int flip) {
    int idx = blockIdx.x * 256 + threadIdx.x;   // 32768
    int r = idx >> 4, h = idx & 15;
    int row = flip ? (2047 - r) : r;
    float raw = zx[(size_t)row * DPROJ + 2304 + h] + dt_bias[h];
    float dt = (raw > 20.f) ? raw : log1pf(expf(raw));
    dt_o[idx] = dt;
}

__global__ void dtpb_kernel(const float* __restrict__ zxc, const float* __restrict__ dt_bias,
                            float* __restrict__ dt_o) {
    int idx = threadIdx.x;   // 128
    int b = idx >> 4, h = idx & 15;
    float raw = zxc[(size_t)b * DPROJ + 2304 + h] + dt_bias[h];
    float dt = (raw > 20.f) ? raw : log1pf(expf(raw));
    dt_o[idx] = dt;
}

// chunk-local inclusive cumsum of ldA = -dt*exp(A_log)
__global__ void cum_kernel(const float* __restrict__ dtFs, const float* __restrict__ dtBs,
                           const float* __restrict__ fAlog, const float* __restrict__ bAlog,
                           float* __restrict__ cumF, float* __restrict__ cumB) {
    int id = blockIdx.x * 256 + threadIdx.x;   // 1024
    int dir = id >> 9, k = id & 511, h = k >> 5, c = k & 31;
    const float* dt = dir ? dtBs : dtFs;
    const float* Al = dir ? bAlog : fAlog;
    float* cum = dir ? cumB : cumF;
    float a = expf(Al[h]);
    float acc = 0.f;
    for (int s = 0; s < 64; ++s) {
        int j = c * 64 + s;
        acc += -dt[j * 16 + h] * a;
        cum[h * 2048 + j] = acc;
    }
}

// ---------------- causal depthwise conv (+SiLU) ----------------

__global__ void convFsh_kernel(const float* __restrict__ zxf, const float* __restrict__ cw,
                               const float* __restrict__ cb, float* __restrict__ outp) {
    int idx = blockIdx.x * 256 + threadIdx.x;
    if (idx >= 2045 * 1280) return;
    int t4 = idx / 1280, c = idx % 1280;
    float4 w4 = *(const float4*)&cw[c * 4];
    float acc = cb[c];
    acc += zxf[(size_t)(t4 + 0) * DPROJ + 1024 + c] * w4.x;
    acc += zxf[(size_t)(t4 + 1) * DPROJ + 1024 + c] * w4.y;
    acc += zxf[(size_t)(t4 + 2) * DPROJ + 1024 + c] * w4.z;
    acc += zxf[(size_t)(t4 + 3) * DPROJ + 1024 + c] * w4.w;
    outp[idx] = siluf(acc);
}

__global__ void convFpb_kernel(const float* __restrict__ zxf, const float* __restrict__ zxc,
                               const float* __restrict__ cw, const float* __restrict__ cb,
                               float* __restrict__ outp) {
    int idx = blockIdx.x * 256 + threadIdx.x;   // 8*4*1280
    int b = idx / 5120;
    int r = idx % 5120;
    int t = r / 1280, c = r % 1280;
    float4 w4 = *(const float4*)&cw[c * 4];
    float w[4] = {w4.x, w4.y, w4.z, w4.w};
    float acc = cb[c];
#pragma unroll
    for (int k = 0; k < 4; ++k) {
        int j = t - 3 + k;
        float x = 0.f;
        if (j == 0)      x = zxc[(size_t)b * DPROJ + 1024 + c];
        else if (j >= 1) x = zxf[(size_t)(j - 1) * DPROJ + 1024 + c];
        acc += x * w[k];
    }
    outp[idx] = siluf(acc);
}

__global__ void convBsh_kernel(const float* __restrict__ zxb, const float* __restrict__ cw,
                               const float* __restrict__ cb, float* __restrict__ outp) {
    int idx = blockIdx.x * 256 + threadIdx.x;   // 2048*1280
    int s = idx / 1280, c = idx % 1280;
    float4 w4 = *(const float4*)&cw[c * 4];
    float w[4] = {w4.x, w4.y, w4.z, w4.w};
    float acc = cb[c];
#pragma unroll
    for (int k = 0; k < 4; ++k) {
        int j = s - 3 + k;
        if (j >= 0) acc += zxb[(size_t)(2047 - j) * DPROJ + 1024 + c] * w[k];
    }
    outp[idx] = siluf(acc);
}

// ---------------- intra-chunk kernel ----------------
// iid<128: fwd chunk0 per-batch (b=iid>>4,h=iid&15); iid<624: fwd shared c>=1; else bwd.
// Computes Yintra[64x64] and U[128x64] (both bf16 out).

__global__ __launch_bounds__(256) void intra_kernel(
    const float* __restrict__ convFs, const float* __restrict__ convFp,
    const float* __restrict__ convBs,
    const float* __restrict__ dtFs, const float* __restrict__ dtBs,
    const float* __restrict__ cumF, const float* __restrict__ cumB,
    unsigned short* __restrict__ YiF0, unsigned short* __restrict__ YiFs,
    unsigned short* __restrict__ YiB,
    unsigned short* __restrict__ UF0, unsigned short* __restrict__ UFs,
    unsigned short* __restrict__ UB) {
    __shared__ __align__(16) unsigned char smraw[17408 * 3 + 512];
    unsigned short* Bt = (unsigned short*)smraw;              // 64 x 136 halves
    unsigned short* Ct = (unsigned short*)(smraw + 17408);    // 64 x 136 halves
    float* Sm = (float*)(smraw + 17408);                      // 64 x 68 (aliases Ct)
    float* Xt = (float*)(smraw + 2 * 17408);                  // 64 x 68
    float* scum = (float*)(smraw + 3 * 17408);                // 64
    float* sdt = scum + 64;                                   // 64

    const int iid = blockIdx.x;
    int dir, b = 0, h, c;
    unsigned short *Yout, *Uout;
    if (iid < 128)      { dir = 0; b = iid >> 4; h = iid & 15; c = 0;
                          Yout = YiF0 + (size_t)(b * 16 + h) * 4096; Uout = UF0 + (size_t)(b * 16 + h) * 8192; }
    else if (iid < 624) { int k = iid - 128; dir = 0; c = 1 + (k >> 4); h = k & 15;
                          Yout = YiFs + (size_t)(c * 16 + h) * 4096; Uout = UFs + (size_t)(c * 16 + h) * 8192; }
    else                { int k = iid - 624; dir = 1; c = k >> 4; h = k & 15;
                          Yout = YiB + (size_t)(c * 16 + h) * 4096;  Uout = UB + (size_t)(c * 16 + h) * 8192; }
    const float* dtA = dir ? dtBs : dtFs;
    const float* cumA = dir ? cumB : cumF;

    const int tid = threadIdx.x;
    {   // stage B, C (bf16), X (fp32), cum, dt
        int r = tid >> 2, q = tid & 3;
        const float* row;
        if (dir == 0) {
            int t = 64 * c + 1 + r;
            row = (t < 4) ? convFp + (size_t)(b * 4 + t) * CONVD : convFs + (size_t)(t - 4) * CONVD;
        } else {
            row = convBs + (size_t)(64 * c + r) * CONVD;
        }
#pragma unroll
        for (int i = 0; i < 8; ++i) {
            int c4 = q + 4 * i;
            float4 v = *(const float4*)&row[1024 + c4 * 4];
            ushort4 p = make_ushort4(f2bf(v.x), f2bf(v.y), f2bf(v.z), f2bf(v.w));
            *(ushort4*)&Bt[r * 136 + c4 * 4] = p;
        }
#pragma unroll
        for (int i = 0; i < 8; ++i) {
            int c4 = q + 4 * i;
            float4 v = *(const float4*)&row[1152 + c4 * 4];
            ushort4 p = make_ushort4(f2bf(v.x), f2bf(v.y), f2bf(v.z), f2bf(v.w));
            *(ushort4*)&Ct[r * 136 + c4 * 4] = p;
        }
#pragma unroll
        for (int i = 0; i < 4; ++i) {
            int c4 = q + 4 * i;
            float4 v = *(const float4*)&row[h * 64 + c4 * 4];
            *(float4*)&Xt[r * 68 + c4 * 4] = v;
        }
        if (tid < 64) {
            int j = 64 * c + tid;
            scum[tid] = cumA[h * 2048 + j];
            sdt[tid] = dtA[j * 16 + h];
        }
    }
    __syncthreads();

    const int tx = tid & 15, ty = tid >> 4;
    // phase 1: G = C . B^T  (t = ty+16i, s = tx+16j)
    float acc[4][4];
#pragma unroll
    for (int i = 0; i < 4; ++i)
#pragma unroll
        for (int j = 0; j < 4; ++j) acc[i][j] = 0.f;
    for (int k = 0; k < 128; k += 4) {
        float cf[4][4], bf[4][4];
#pragma unroll
        for (int i = 0; i < 4; ++i) {
            ushort4 v = *(ushort4*)&Ct[(ty + 16 * i) * 136 + k];
            cf[i][0] = bfu(v.x); cf[i][1] = bfu(v.y); cf[i][2] = bfu(v.z); cf[i][3] = bfu(v.w);
        }
#pragma unroll
        for (int j = 0; j < 4; ++j) {
            ushort4 v = *(ushort4*)&Bt[(tx + 16 * j) * 136 + k];
            bf[j][0] = bfu(v.x); bf[j][1] = bfu(v.y); bf[j][2] = bfu(v.z); bf[j][3] = bfu(v.w);
        }
#pragma unroll
        for (int i = 0; i < 4; ++i)
#pragma unroll
            for (int j = 0; j < 4; ++j)
                acc[i][j] += cf[i][0] * bf[j][0] + cf[i][1] * bf[j][1] +
                             cf[i][2] * bf[j][2] + cf[i][3] * bf[j][3];
    }
    __syncthreads();   // done reading Ct; Sm aliases it
    // mask + decay + dt scale, write S
#pragma unroll
    for (int i = 0; i < 4; ++i) {
        int t = ty + 16 * i;
#pragma unroll
        for (int j = 0; j < 4; ++j) {
            int s = tx + 16 * j;
            float v = (s <= t) ? __expf(scum[t] - scum[s]) * sdt[s] * acc[i][j] : 0.f;
            Sm[t * 68 + s] = v;
        }
    }
    __syncthreads();

    // phase 2+3: Yintra = S @ X ; U = B^T . (e*X)
    float4 accY[4];
    float4 accU[8];
#pragma unroll
    for (int i = 0; i < 4; ++i) accY[i] = make_float4(0.f, 0.f, 0.f, 0.f);
#pragma unroll
    for (int i = 0; i < 8; ++i) accU[i] = make_float4(0.f, 0.f, 0.f, 0.f);
    const float cend = scum[63];
    for (int s = 0; s < 64; ++s) {
        float4 xv = *(const float4*)&Xt[s * 68 + tx * 4];
        float es = __expf(cend - scum[s]) * sdt[s];
#pragma unroll
        for (int i = 0; i < 4; ++i) {
            float sv = Sm[(ty + 16 * i) * 68 + s];
            accY[i].x += sv * xv.x; accY[i].y += sv * xv.y;
            accY[i].z += sv * xv.z; accY[i].w += sv * xv.w;
        }
        float4 xe = make_float4(xv.x * es, xv.y * es, xv.z * es, xv.w * es);
#pragma unroll
        for (int i = 0; i < 8; ++i) {
            float bv = bfu(Bt[s * 136 + (ty + 16 * i)]);
            accU[i].x += bv * xe.x; accU[i].y += bv * xe.y;
            accU[i].z += bv * xe.z; accU[i].w += bv * xe.w;
        }
    }
#pragma unroll
    for (int i = 0; i < 4; ++i) {
        ushort4 p = make_ushort4(f2bf(accY[i].x), f2bf(accY[i].y), f2bf(accY[i].z), f2bf(accY[i].w));
        *(ushort4*)&Yout[(ty + 16 * i) * 64 + tx * 4] = p;
    }
#pragma unroll
    for (int i = 0; i < 8; ++i) {
        ushort4 p = make_ushort4(f2bf(accU[i].x), f2bf(accU[i].y), f2bf(accU[i].z), f2bf(accU[i].w));
        *(ushort4*)&Uout[(ty + 16 * i) * 64 + tx * 4] = p;
    }
}

// ---------------- chunk0 rank-1 inter coefficients ----------------

__global__ void cb0_kernel(const float* __restrict__ convFs, const float* __restrict__ convFp,
                           const float* __restrict__ dtFp, float* __restrict__ cb0) {
    int idx = blockIdx.x * 256 + threadIdx.x;   // 8192
    int b = idx >> 10, r = idx & 1023, h = r >> 6, tl = r & 63;
    int t = tl + 1;
    const float* crow = (t < 4) ? convFp + (size_t)(b * 4 + t) * CONVD : convFs + (size_t)(t - 4) * CONVD;
    const float* b0 = convFp + (size_t)(b * 4) * CONVD;
    float s = 0.f;
    for (int n = 0; n < 128; ++n) s += crow[1152 + n] * b0[1024 + n];
    cb0[(b * 16 + h) * 64 + tl] = s * dtFp[b * 16 + h];
}

// ---------------- M = D0*dt0*B0^T x0 + U0 ----------------

__global__ void m_kernel(const unsigned short* __restrict__ UF0, const float* __restrict__ convFp,
                         const float* __restrict__ dtFp, const float* __restrict__ cumF,
                         unsigned short* __restrict__ Mb) {
    int blk = blockIdx.x;   // 128: (b,h)
    int b = blk >> 4, h = blk & 15, tid = threadIdx.x;
    float D0 = __expf(cumF[h * 2048 + 63]);
    float dt0 = dtFp[b * 16 + h];
    const float* row0 = convFp + (size_t)(b * 4) * CONVD;
    const unsigned short* u = UF0 + (size_t)(b * 16 + h) * 8192;
    unsigned short* m = Mb + (size_t)(b * 16 + h) * 8192;
    for (int e4 = tid; e4 < 2048; e4 += 256) {
        int e = e4 * 4, n = e >> 6, p = e & 63;
        float Bn = D0 * dt0 * row0[1024 + n];
        float4 x4 = *(const float4*)&row0[h * 64 + p];
        ushort4 uv = *(const ushort4*)&u[e];
        ushort4 o = make_ushort4(f2bf(Bn * x4.x + bfu(uv.x)), f2bf(Bn * x4.y + bfu(uv.y)),
                                 f2bf(Bn * x4.z + bfu(uv.z)), f2bf(Bn * x4.w + bfu(uv.w)));
        *(ushort4*)&m[e] = o;
    }
}

// ---------------- shared chunk-state scan: T_c, psi_c ----------------

__global__ void tpsi_kernel(const unsigned short* __restrict__ UFs, const unsigned short* __restrict__ UB,
                            const float* __restrict__ cumF, const float* __restrict__ cumB,
                            unsigned short* __restrict__ Tst, float* __restrict__ psiF) {
    int blk = blockIdx.x;   // 32: dir*16+h
    int dir = blk >> 4, h = blk & 15;
    int tid = threadIdx.x;
    const unsigned short* U = dir ? UB : UFs;
    const float* cum = dir ? cumB : cumF;
    unsigned short* T = Tst + (size_t)(dir * 16 + h) * 32 * 8192;
    if (dir == 0 && tid == 0) {
        float ps = 1.f;
        for (int c = 1; c < 32; ++c) {
            psiF[h * 32 + c] = ps;
            ps *= __expf(cumF[h * 2048 + c * 64 + 63]);
        }
    }
    float4 st[8];
#pragma unroll
    for (int q = 0; q < 8; ++q) st[q] = make_float4(0.f, 0.f, 0.f, 0.f);
    int c0 = dir ? 0 : 1;
    for (int c = c0; c < 32; ++c) {
        float Dc = __expf(cum[h * 2048 + c * 64 + 63]);
#pragma unroll
        for (int q = 0; q < 8; ++q) {
            size_t e = 4 * tid + 1024 * q;
            ushort4 o = make_ushort4(f2bf(st[q].x), f2bf(st[q].y), f2bf(st[q].z), f2bf(st[q].w));
            *(ushort4*)&T[(size_t)c * 8192 + e] = o;
            ushort4 uv = *(const ushort4*)&U[((size_t)c * 16 + h) * 8192 + e];
            st[q].x = Dc * st[q].x + bfu(uv.x);
            st[q].y = Dc * st[q].y + bfu(uv.y);
            st[q].z = Dc * st[q].z + bfu(uv.z);
            st[q].w = Dc * st[q].w + bfu(uv.w);
        }
    }
}

// ---------------- gate kernel: Yinter GEMM + gating + partial RMS dot ----------------
// iid<4096: fwd (b,h,c). else bwd (h,c).

__global__ __launch_bounds__(256, 2) void gate_kernel(
    const float* __restrict__ convFs, const float* __restrict__ convFp,
    const float* __restrict__ convBs,
    const float* __restrict__ zxf, const float* __restrict__ zxb,
    const float* __restrict__ cumF, const float* __restrict__ cumB,
    const unsigned short* __restrict__ YiF0, const unsigned short* __restrict__ YiFs,
    const unsigned short* __restrict__ YiB,
    const unsigned short* __restrict__ Tst, const float* __restrict__ psiF,
    const unsigned short* __restrict__ Mb, const float* __restrict__ cb0,
    const float* __restrict__ fD, const float* __restrict__ bD,
    const float* __restrict__ wf2, const float* __restrict__ wb2,
    float* __restrict__ aF, float* __restrict__ aB) {
    __shared__ __align__(16) unsigned char smraw[17408 + 34816];
    unsigned short* Cs = (unsigned short*)smraw;               // 64 x 136
    unsigned short* Wm = (unsigned short*)(smraw + 17408);     // 128 x 136

    const int iid = blockIdx.x;
    int dir, b = 0, h, c;
    if (iid < 4096) { dir = 0; b = iid >> 9; int r = iid & 511; h = r >> 5; c = r & 31; }
    else            { int k = iid - 4096; dir = 1; h = k >> 5; c = k & 31; }
    const int tid = threadIdx.x, tx = tid & 15, ty = tid >> 4;
    const bool doGemm = !(dir == 0 && c == 0);

    if (doGemm) {
        int r = tid >> 2, q = tid & 3;
        const float* row;
        if (dir == 0) row = convFs + (size_t)(64 * c + 1 + r - 4) * CONVD;   // c>=1 -> t>=65
        else          row = convBs + (size_t)(64 * c + r) * CONVD;
#pragma unroll
        for (int i = 0; i < 8; ++i) {
            int c4 = q + 4 * i;
            float4 v = *(const float4*)&row[1152 + c4 * 4];
            ushort4 p = make_ushort4(f2bf(v.x), f2bf(v.y), f2bf(v.z), f2bf(v.w));
            *(ushort4*)&Cs[r * 136 + c4 * 4] = p;
        }
        const unsigned short* Tp = Tst + ((size_t)(dir * 16 + h) * 32 + c) * 8192;
        if (dir == 0) {
            float psi = psiF[h * 32 + c];
            const unsigned short* Mp = Mb + (size_t)(b * 16 + h) * 8192;
            for (int e = tid; e < 8192; e += 256) {
                int n = e >> 6, p = e & 63;
                Wm[n * 136 + p] = f2bf(bfu(Tp[e]) + psi * bfu(Mp[e]));
            }
        } else {
            for (int e = tid; e < 8192; e += 256) {
                int n = e >> 6, p = e & 63;
                Wm[n * 136 + p] = Tp[e];
            }
        }
    }
    __syncthreads();

    float4 accY[4];
#pragma unroll
    for (int i = 0; i < 4; ++i) accY[i] = make_float4(0.f, 0.f, 0.f, 0.f);
    if (doGemm) {
        for (int n = 0; n < 128; n += 4) {
            float wf[4][4];
#pragma unroll
            for (int d = 0; d < 4; ++d) {
                ushort4 v = *(ushort4*)&Wm[(n + d) * 136 + tx * 4];
                wf[d][0] = bfu(v.x); wf[d][1] = bfu(v.y); wf[d][2] = bfu(v.z); wf[d][3] = bfu(v.w);
            }
#pragma unroll
            for (int i = 0; i < 4; ++i) {
                ushort4 v = *(ushort4*)&Cs[(ty + 16 * i) * 136 + n];
                float c0 = bfu(v.x), c1 = bfu(v.y), c2 = bfu(v.z), c3 = bfu(v.w);
                accY[i].x += c0 * wf[0][0] + c1 * wf[1][0] + c2 * wf[2][0] + c3 * wf[3][0];
                accY[i].y += c0 * wf[0][1] + c1 * wf[1][1] + c2 * wf[2][1] + c3 * wf[3][1];
                accY[i].z += c0 * wf[0][2] + c1 * wf[1][2] + c2 * wf[2][2] + c3 * wf[3][2];
                accY[i].w += c0 * wf[0][3] + c1 * wf[1][3] + c2 * wf[2][3] + c3 * wf[3][3];
            }
        }
    }

    // gating + partial reduction
    const float Dh = (dir ? bD : fD)[h];
    const float* wvp = dir ? wb2 : wf2;
    float4 wreg = *(const float4*)&wvp[h * 64 + tx * 4];
    const float* cumA = dir ? cumB : cumF;
    float4 x0v = make_float4(0.f, 0.f, 0.f, 0.f);
    float cbv[4] = {0.f, 0.f, 0.f, 0.f};
    if (dir == 0 && c == 0) {
        x0v = *(const float4*)&convFp[(size_t)(b * 4) * CONVD + h * 64 + tx * 4];
#pragma unroll
        for (int i = 0; i < 4; ++i) cbv[i] = cb0[(b * 16 + h) * 64 + (ty + 16 * i)];
    }
#pragma unroll
    for (int i = 0; i < 4; ++i) {
        int tl = ty + 16 * i;
        int j = 64 * c + tl;
        float et = __expf(cumA[h * 2048 + j]);
        const unsigned short* Yi;
        const float *xrow, *zrow;
        if (dir == 0) {
            int t = j + 1;
            Yi = (c == 0) ? YiF0 + (size_t)(b * 16 + h) * 4096 : YiFs + (size_t)(c * 16 + h) * 4096;
            xrow = (t < 4) ? convFp + (size_t)(b * 4 + t) * CONVD : convFs + (size_t)(t - 4) * CONVD;
            zrow = zxf + (size_t)j * DPROJ;
        } else {
            Yi = YiB + (size_t)(c * 16 + h) * 4096;
            xrow = convBs + (size_t)j * CONVD;
            zrow = zxb + (size_t)(2047 - j) * DPROJ;
        }
        ushort4 yi4 = *(const ushort4*)&Yi[tl * 64 + tx * 4];
        float4 xx = *(const float4*)&xrow[h * 64 + tx * 4];
        float4 zz = *(const float4*)&zrow[h * 64 + tx * 4];
        float yv[4] = {bfu(yi4.x), bfu(yi4.y), bfu(yi4.z), bfu(yi4.w)};
        float xa[4] = {xx.x, xx.y, xx.z, xx.w};
        float za[4] = {zz.x, zz.y, zz.z, zz.w};
        float ya[4] = {accY[i].x, accY[i].y, accY[i].z, accY[i].w};
        float x0a[4] = {x0v.x, x0v.y, x0v.z, x0v.w};
        float wa[4] = {wreg.x, wreg.y, wreg.z, wreg.w};
        float a1 = 0.f, a2 = 0.f;
#pragma unroll
        for (int w = 0; w < 4; ++w) {
            float tot = yv[w] + et * (ya[w] + cbv[i] * x0a[w]) + Dh * xa[w];
            float g = tot * siluf(za[w]);
            a1 += g * wa[w];
            a2 += g * g;
        }
#pragma unroll
        for (int m = 1; m < 16; m <<= 1) {
            a1 += __shfl_xor(a1, m);
            a2 += __shfl_xor(a2, m);
        }
        if (tx == 0) {
            if (dir == 0) {
                size_t o = ((size_t)(b * 2048 + j) * 16 + h) * 2;
                aF[o] = a1; aF[o + 1] = a2;
            } else {
                int g = 2047 - j;
                size_t o = ((size_t)g * 16 + h) * 2;
                aB[o] = a1; aB[o + 1] = a2;
            }
        }
    }
}

// ---------------- final combine ----------------

__global__ void final_kernel(const float* __restrict__ aF, const float* __restrict__ aB,
                             const float* __restrict__ headB, float* __restrict__ out) {
    int idx = blockIdx.x * 256 + threadIdx.x;   // 16384
    int b = idx >> 11, g = idx & 2047;
    const float* pf = aF + ((size_t)(b * 2048 + g)) * 32;
    const float* pb = aB + (size_t)g * 32;
    float f1 = 0.f, f2 = 0.f, b1 = 0.f, b2 = 0.f;
#pragma unroll
    for (int h = 0; h < 16; ++h) {
        f1 += pf[2 * h]; f2 += pf[2 * h + 1];
        b1 += pb[2 * h]; b2 += pb[2 * h + 1];
    }
    out[idx] = f1 * rsqrtf(f2 * (1.f / 1024.f) + 1e-5f) +
               b1 * rsqrtf(b2 * (1.f / 1024.f) + 1e-5f) + headB[0];
}

// ---------------- launch ----------------

extern "C" void kernel_launch(void* const* d_in, const int* in_sizes, int n_in,
                              void* d_out, int out_size, void* d_ws, size_t ws_size,
                              hipStream_t stream) {
    const int*   pidx   = (const int*)  d_in[0];
    const int*   chridx = (const int*)  d_in[1];
    const float* locusF = (const float*)d_in[2];
    const float* pathF  = (const float*)d_in[3];
    const float* pertE  = (const float*)d_in[4];
    const float* gidE   = (const float*)d_in[5];
    const float* chrE   = (const float*)d_in[6];
    const float* locusW = (const float*)d_in[7];
    const float* locusB = (const float*)d_in[8];
    const float* condW  = (const float*)d_in[9];
    const float* condB  = (const float*)d_in[10];
    const float* inW    = (const float*)d_in[11];
    const float* inB    = (const float*)d_in[12];
    const float* headW  = (const float*)d_in[13];
    const float* headB  = (const float*)d_in[14];
    const float* fInW   = (const float*)d_in[15];
    const float* fCw    = (const float*)d_in[16];
    const float* fCb    = (const float*)d_in[17];
    const float* fDtB   = (const float*)d_in[18];
    const float* fAlog  = (const float*)d_in[19];
    const float* fDp    = (const float*)d_in[20];
    const float* fNw    = (const float*)d_in[21];
    const float* fOutW  = (const float*)d_in[22];
    const float* bInW   = (const float*)d_in[23];
    const float* bCw    = (const float*)d_in[24];
    const float* bCb    = (const float*)d_in[25];
    const float* bDtB   = (const float*)d_in[26];
    const float* bAlog  = (const float*)d_in[27];
    const float* bDp    = (const float*)d_in[28];
    const float* bNw    = (const float*)d_in[29];
    const float* bOutW  = (const float*)d_in[30];
    float* out = (float*)d_out;
    (void)in_sizes; (void)n_in; (void)out_size; (void)ws_size;

    char* base = (char*)d_ws;
    size_t off = 0;
    auto allocf = [&](size_t n) -> float* {
        char* r = base + off; off += ((n * 4 + 63) & ~(size_t)63); return (float*)r; };
    auto allocu = [&](size_t n) -> unsigned short* {
        char* r = base + off; off += ((n * 2 + 63) & ~(size_t)63); return (unsigned short*)r; };

    float* gf     = allocf(2048UL * 384);
    float* cond   = allocf(8UL * 384);
    float* cemb   = allocf(8UL * 128);
    float* ug     = allocf(2048UL * 512);
    float* uc     = allocf(8UL * 512);
    float* zxf    = allocf(2048UL * DPROJ);
    float* zxb    = allocf(2048UL * DPROJ);
    float* zxc    = allocf(8UL * DPROJ);
    float* convFs = allocf(2045UL * CONVD);
    float* convFp = allocf(8UL * 4 * CONVD);
    float* convBs = allocf(2048UL * CONVD);
    float* dtFs   = allocf(2048UL * 16);
    float* dtFp   = allocf(128);
    float* dtBs   = allocf(2048UL * 16);
    float* cumF   = allocf(16UL * 2048);
    float* cumB   = allocf(16UL * 2048);
    float* wf2    = allocf(1024);
    float* wb2    = allocf(1024);
    float* cb0    = allocf(8UL * 16 * 64);
    float* psiF   = allocf(16UL * 32);
    float* aF     = allocf(8UL * 2048 * 16 * 2);
    float* aB     = allocf(2048UL * 16 * 2);
    unsigned short* YiF0 = allocu(8UL * 16 * 4096);
    unsigned short* YiFs = allocu(32UL * 16 * 4096);
    unsigned short* YiB  = allocu(32UL * 16 * 4096);
    unsigned short* UF0  = allocu(8UL * 16 * 8192);
    unsigned short* UFs  = allocu(32UL * 16 * 8192);
    unsigned short* UB   = allocu(32UL * 16 * 8192);
    unsigned short* Mb   = allocu(8UL * 16 * 8192);
    unsigned short* Tst  = allocu(2UL * 16 * 32 * 8192);

    gather_kernel<<<4, 256, 0, stream>>>(pidx, pertE, cemb);
    wfold_kernel<<<8, 256, 0, stream>>>(headW, fOutW, fNw, bOutW, bNw, wf2, wb2);
    genefeat_kernel<<<3072, 256, 0, stream>>>(chridx, gidE, pathF, chrE, gf);
    gemm_kernel<<<dim3(1, 32), 256, 0, stream>>>(locusF, locusW, locusB, gf + 320, 2048, 64, 64, 384, 1);
    gemm_kernel<<<dim3(6, 1), 256, 0, stream>>>(cemb, condW, condB, cond, 8, 384, 128, 384, 0);
    gemm_kernel<<<dim3(8, 32), 256, 0, stream>>>(gf, inW, inB, ug, 2048, 512, 384, 512, 0);
    gemm_kernel<<<dim3(8, 1), 256, 0, stream>>>(cond, inW, inB, uc, 8, 512, 384, 512, 0);
    gemm_kernel<<<dim3(37, 32), 256, 0, stream>>>(ug, fInW, nullptr, zxf, 2048, DPROJ, 512, DPROJ, 0);
    gemm_kernel<<<dim3(37, 32), 256, 0, stream>>>(ug, bInW, nullptr, zxb, 2048, DPROJ, 512, DPROJ, 0);
    gemm_kernel<<<dim3(37, 1), 256, 0, stream>>>(uc, fInW, nullptr, zxc, 8, DPROJ, 512, DPROJ, 0);
    dt_kernel<<<128, 256, 0, stream>>>(zxf, fDtB, dtFs, 0);
    dt_kernel<<<128, 256, 0, stream>>>(zxb, bDtB, dtBs, 1);
    dtpb_kernel<<<1, 128, 0, stream>>>(zxc, fDtB, dtFp);
    cum_kernel<<<4, 256, 0, stream>>>(dtFs, dtBs, fAlog, bAlog, cumF, cumB);
    convFsh_kernel<<<(2045 * 1280 + 255) / 256, 256, 0, stream>>>(zxf, fCw, fCb, convFs);
    convFpb_kernel<<<160, 256, 0, stream>>>(zxf, zxc, fCw, fCb, convFp);
    convBsh_kernel<<<10240, 256, 0, stream>>>(zxb, bCw, bCb, convBs);
    intra_kernel<<<1136, 256, 0, stream>>>(convFs, convFp, convBs, dtFs, dtBs, cumF, cumB,
                                           YiF0, YiFs, YiB, UF0, UFs, UB);
    cb0_kernel<<<32, 256, 0, stream>>>(convFs, convFp, dtFp, cb0);
    m_kernel<<<128, 256, 0, stream>>>(UF0, convFp, dtFp, cumF, Mb);
    tpsi_kernel<<<32, 256, 0, stream>>>(UFs, UB, cumF, cumB, Tst, psiF);
    gate_kernel<<<4608, 256, 0, stream>>>(convFs, convFp, convBs, zxf, zxb, cumF, cumB,
                                          YiF0, YiFs, YiB, Tst, psiF, Mb, cb0,
                                          fDp, bDp, wf2, wb2, aF, aB);
    final_kernel<<<64, 256, 0, stream>>>(aF, aB, headB, out);
}

// Round 3
// 524.735 us; speedup vs baseline: 5.5001x; 1.2573x over previous
//
#include <hip/hip_runtime.h>
#include <hip/hip_bf16.h>
#include <math.h>

#define DPROJ 2320
#define CONVD 1280

typedef __attribute__((ext_vector_type(8))) short bf16x8;
typedef __attribute__((ext_vector_type(4))) float f32x4;

__device__ __forceinline__ float siluf(float x) { return x / (1.f + __expf(-x)); }
__device__ __forceinline__ float bfu(unsigned short s) { return __uint_as_float(((unsigned)s) << 16); }
__device__ __forceinline__ unsigned short f2bf(float f) {
    unsigned u = __float_as_uint(f);
    unsigned r = (u + 0x7FFFu + ((u >> 16) & 1u)) >> 16;
    return (unsigned short)r;
}

// ---------------- small prep kernels ----------------

__global__ void gather_kernel(const int* __restrict__ pidx, const float* __restrict__ pertE,
                              float* __restrict__ cemb) {
    int idx = blockIdx.x * 256 + threadIdx.x;   // 1024
    int b = idx >> 7, k = idx & 127;
    cemb[idx] = pertE[(size_t)pidx[b] * 128 + k];
}

__global__ void wfold_kernel(const float* __restrict__ headW,
                             const float* __restrict__ fOutW, const float* __restrict__ fNw,
                             const float* __restrict__ bOutW, const float* __restrict__ bNw,
                             float* __restrict__ wf2, float* __restrict__ wb2) {
    int idx = blockIdx.x * 256 + threadIdx.x;   // 2048
    int dir = idx >> 10, d = idx & 1023;
    const float* W  = dir ? bOutW : fOutW;
    const float* nw = dir ? bNw : fNw;
    float s = 0.f;
    for (int m = 0; m < 512; ++m) s += headW[m] * W[(size_t)m * 1024 + d];
    (dir ? wb2 : wf2)[d] = s * nw[d];
}

__global__ void genefeat_kernel(const int* __restrict__ chridx, const float* __restrict__ gid,
                                const float* __restrict__ path, const float* __restrict__ chrE,
                                float* __restrict__ gf) {
    int idx = blockIdx.x * 256 + threadIdx.x;   // 2048*384
    int g = idx / 384, j = idx % 384;
    float v;
    if (j < 128)      v = gid[(size_t)g * 128 + j];
    else if (j < 256) v = path[(size_t)g * 128 + (j - 128)];
    else if (j < 320) v = chrE[(size_t)chridx[g] * 64 + (j - 256)];
    else return;      // cols 320..383 written by the locus GEMM
    gf[idx] = v;
}

// ---------------- hi/lo bf16 split conversion: out[m][k]=hi, out[m][K+k]=lo ----------------

__global__ void tobf_kernel(const float* __restrict__ in, unsigned short* __restrict__ out,
                            int M, int K, int Mpad) {
    int idx = blockIdx.x * 256 + threadIdx.x;
    if (idx >= Mpad * K) return;
    int m = idx / K, k = idx % K;
    float v = (m < M) ? in[(size_t)m * K + k] : 0.f;
    unsigned short hi = f2bf(v);
    unsigned short lo = f2bf(v - bfu(hi));
    out[(size_t)m * 2 * K + k] = hi;
    out[(size_t)m * 2 * K + K + k] = lo;
}

// ---------------- MFMA GEMM: C[M x N] = A2[M x K2] . W2[Npad x K2]^T (+bias) ----------------
// M multiple of 128, Npad multiple of 128 (rows >= N zero-padded), K2 multiple of 32.

__global__ __launch_bounds__(256) void mfma_gemm_kernel(
    const unsigned short* __restrict__ A2, const unsigned short* __restrict__ W2,
    const float* __restrict__ bias, float* __restrict__ C,
    int N, int K2, int ldc) {
    __shared__ __align__(16) unsigned short Al[128 * 40];
    __shared__ __align__(16) unsigned short Bl[128 * 40];
    const int tid = threadIdx.x;
    const int bm = blockIdx.y * 128, bn = blockIdx.x * 128;
    const int lane = tid & 63, wave = tid >> 6;
    const int wm = (wave >> 1) * 64, wn = (wave & 1) * 64;
    f32x4 acc[4][4];
#pragma unroll
    for (int i = 0; i < 4; ++i)
#pragma unroll
        for (int j = 0; j < 4; ++j) acc[i][j] = (f32x4){0.f, 0.f, 0.f, 0.f};

    for (int k0 = 0; k0 < K2; k0 += 32) {
        __syncthreads();
#pragma unroll
        for (int s = 0; s < 2; ++s) {
            int ch = tid + 256 * s;
            int row = ch >> 2, q = ch & 3;
            uint4 va = *(const uint4*)&A2[(size_t)(bm + row) * K2 + k0 + q * 8];
            *(uint4*)&Al[row * 40 + q * 8] = va;
            uint4 vb = *(const uint4*)&W2[(size_t)(bn + row) * K2 + k0 + q * 8];
            *(uint4*)&Bl[row * 40 + q * 8] = vb;
        }
        __syncthreads();
        bf16x8 af[4], bfr[4];
#pragma unroll
        for (int i = 0; i < 4; ++i)
            af[i] = *(const bf16x8*)&Al[(wm + i * 16 + (lane & 15)) * 40 + (lane >> 4) * 8];
#pragma unroll
        for (int j = 0; j < 4; ++j)
            bfr[j] = *(const bf16x8*)&Bl[(wn + j * 16 + (lane & 15)) * 40 + (lane >> 4) * 8];
#pragma unroll
        for (int i = 0; i < 4; ++i)
#pragma unroll
            for (int j = 0; j < 4; ++j)
                acc[i][j] = __builtin_amdgcn_mfma_f32_16x16x32_bf16(af[i], bfr[j], acc[i][j], 0, 0, 0);
    }
#pragma unroll
    for (int i = 0; i < 4; ++i) {
        int m = bm + wm + i * 16 + (lane >> 4) * 4;
#pragma unroll
        for (int j = 0; j < 4; ++j) {
            int n = bn + wn + j * 16 + (lane & 15);
            if (n < N) {
                float bv = bias ? bias[n] : 0.f;
#pragma unroll
                for (int r = 0; r < 4; ++r)
                    C[(size_t)(m + r) * ldc + n] = acc[i][j][r] + bv;
            }
        }
    }
}

// ---------------- generic tiled fp32 GEMM (small shapes only) ----------------

__global__ __launch_bounds__(256) void gemm_kernel(
    const float* __restrict__ A, const float* __restrict__ W,
    const float* __restrict__ bias, float* __restrict__ C,
    int M, int N, int K, int ldc, int act) {
    __shared__ __align__(16) float As[16][68];
    __shared__ __align__(16) float Ws[16][68];
    const int tid = threadIdx.x;
    const int tx = tid & 15, ty = tid >> 4;
    const int bm = blockIdx.y * 64, bn = blockIdx.x * 64;
    const int lr = tid >> 2;
    const int lk = (tid & 3) * 4;
    float acc[4][4];
#pragma unroll
    for (int i = 0; i < 4; ++i)
#pragma unroll
        for (int j = 0; j < 4; ++j) acc[i][j] = 0.f;

    for (int k0 = 0; k0 < K; k0 += 16) {
        const int am = bm + lr;
        const int wn = bn + lr;
        float4 av = make_float4(0.f, 0.f, 0.f, 0.f), wv = make_float4(0.f, 0.f, 0.f, 0.f);
        if (am < M) av = *(const float4*)&A[(size_t)am * K + k0 + lk];
        if (wn < N) wv = *(const float4*)&W[(size_t)wn * K + k0 + lk];
        __syncthreads();
        As[lk + 0][lr] = av.x; As[lk + 1][lr] = av.y; As[lk + 2][lr] = av.z; As[lk + 3][lr] = av.w;
        Ws[lk + 0][lr] = wv.x; Ws[lk + 1][lr] = wv.y; Ws[lk + 2][lr] = wv.z; Ws[lk + 3][lr] = wv.w;
        __syncthreads();
#pragma unroll
        for (int kk = 0; kk < 16; ++kk) {
            float4 a = *(const float4*)&As[kk][ty * 4];
            float4 w = *(const float4*)&Ws[kk][tx * 4];
            float aa[4] = {a.x, a.y, a.z, a.w}, ww[4] = {w.x, w.y, w.z, w.w};
#pragma unroll
            for (int i = 0; i < 4; ++i)
#pragma unroll
                for (int j = 0; j < 4; ++j) acc[i][j] += aa[i] * ww[j];
        }
    }
#pragma unroll
    for (int i = 0; i < 4; ++i) {
        const int m = bm + ty * 4 + i;
        if (m >= M) continue;
#pragma unroll
        for (int j = 0; j < 4; ++j) {
            const int n = bn + tx * 4 + j;
            if (n >= N) continue;
            float v = acc[i][j] + (bias ? bias[n] : 0.f);
            if (act == 1) v = 0.5f * v * (1.f + erff(v * 0.70710678118654752f));
            C[(size_t)m * ldc + n] = v;
        }
    }
}

// ---------------- dt precompute ----------------

__global__ void dt_kernel(const float* __restrict__ zx, const float* __restrict__ dt_bias,
                          float* __restrict__ dt_o, int flip) {
    int idx = blockIdx.x * 256 + threadIdx.x;   // 32768
    int r = idx >> 4, h = idx & 15;
    int row = flip ? (2047 - r) : r;
    float raw = zx[(size_t)row * DPROJ + 2304 + h] + dt_bias[h];
    float dt = (raw > 20.f) ? raw : log1pf(expf(raw));
    dt_o[idx] = dt;
}

__global__ void dtpb_kernel(const float* __restrict__ zxc, const float* __restrict__ dt_bias,
                            float* __restrict__ dt_o) {
    int idx = threadIdx.x;   // 128
    int b = idx >> 4, h = idx & 15;
    float raw = zxc[(size_t)b * DPROJ + 2304 + h] + dt_bias[h];
    float dt = (raw > 20.f) ? raw : log1pf(expf(raw));
    dt_o[idx] = dt;
}

// chunk-local inclusive cumsum of ldA = -dt*exp(A_log)
__global__ void cum_kernel(const float* __restrict__ dtFs, const float* __restrict__ dtBs,
                           const float* __restrict__ fAlog, const float* __restrict__ bAlog,
                           float* __restrict__ cumF, float* __restrict__ cumB) {
    int id = blockIdx.x * 256 + threadIdx.x;   // 1024
    int dir = id >> 9, k = id & 511, h = k >> 5, c = k & 31;
    const float* dt = dir ? dtBs : dtFs;
    const float* Al = dir ? bAlog : fAlog;
    float* cum = dir ? cumB : cumF;
    float a = expf(Al[h]);
    float acc = 0.f;
    for (int s = 0; s < 64; ++s) {
        int j = c * 64 + s;
        acc += -dt[j * 16 + h] * a;
        cum[h * 2048 + j] = acc;
    }
}

// ---------------- causal depthwise conv (+SiLU) ----------------

__global__ void convFsh_kernel(const float* __restrict__ zxf, const float* __restrict__ cw,
                               const float* __restrict__ cb, float* __restrict__ outp) {
    int idx = blockIdx.x * 256 + threadIdx.x;
    if (idx >= 2045 * 1280) return;
    int t4 = idx / 1280, c = idx % 1280;
    float4 w4 = *(const float4*)&cw[c * 4];
    float acc = cb[c];
    acc += zxf[(size_t)(t4 + 0) * DPROJ + 1024 + c] * w4.x;
    acc += zxf[(size_t)(t4 + 1) * DPROJ + 1024 + c] * w4.y;
    acc += zxf[(size_t)(t4 + 2) * DPROJ + 1024 + c] * w4.z;
    acc += zxf[(size_t)(t4 + 3) * DPROJ + 1024 + c] * w4.w;
    outp[idx] = siluf(acc);
}

__global__ void convFpb_kernel(const float* __restrict__ zxf, const float* __restrict__ zxc,
                               const float* __restrict__ cw, const float* __restrict__ cb,
                               float* __restrict__ outp) {
    int idx = blockIdx.x * 256 + threadIdx.x;   // 8*4*1280
    int b = idx / 5120;
    int r = idx % 5120;
    int t = r / 1280, c = r % 1280;
    float4 w4 = *(const float4*)&cw[c * 4];
    float w[4] = {w4.x, w4.y, w4.z, w4.w};
    float acc = cb[c];
#pragma unroll
    for (int k = 0; k < 4; ++k) {
        int j = t - 3 + k;
        float x = 0.f;
        if (j == 0)      x = zxc[(size_t)b * DPROJ + 1024 + c];
        else if (j >= 1) x = zxf[(size_t)(j - 1) * DPROJ + 1024 + c];
        acc += x * w[k];
    }
    outp[idx] = siluf(acc);
}

__global__ void convBsh_kernel(const float* __restrict__ zxb, const float* __restrict__ cw,
                               const float* __restrict__ cb, float* __restrict__ outp) {
    int idx = blockIdx.x * 256 + threadIdx.x;   // 2048*1280
    int s = idx / 1280, c = idx % 1280;
    float4 w4 = *(const float4*)&cw[c * 4];
    float w[4] = {w4.x, w4.y, w4.z, w4.w};
    float acc = cb[c];
#pragma unroll
    for (int k = 0; k < 4; ++k) {
        int j = s - 3 + k;
        if (j >= 0) acc += zxb[(size_t)(2047 - j) * DPROJ + 1024 + c] * w[k];
    }
    outp[idx] = siluf(acc);
}

// ---------------- intra-chunk kernel ----------------

__global__ __launch_bounds__(256) void intra_kernel(
    const float* __restrict__ convFs, const float* __restrict__ convFp,
    const float* __restrict__ convBs,
    const float* __restrict__ dtFs, const float* __restrict__ dtBs,
    const float* __restrict__ cumF, const float* __restrict__ cumB,
    unsigned short* __restrict__ YiF0, unsigned short* __restrict__ YiFs,
    unsigned short* __restrict__ YiB,
    unsigned short* __restrict__ UF0, unsigned short* __restrict__ UFs,
    unsigned short* __restrict__ UB) {
    __shared__ __align__(16) unsigned char smraw[17408 * 3 + 512];
    unsigned short* Bt = (unsigned short*)smraw;              // 64 x 136 halves
    unsigned short* Ct = (unsigned short*)(smraw + 17408);    // 64 x 136 halves
    float* Sm = (float*)(smraw + 17408);                      // 64 x 68 (aliases Ct)
    float* Xt = (float*)(smraw + 2 * 17408);                  // 64 x 68
    float* scum = (float*)(smraw + 3 * 17408);                // 64
    float* sdt = scum + 64;                                   // 64

    const int iid = blockIdx.x;
    int dir, b = 0, h, c;
    unsigned short *Yout, *Uout;
    if (iid < 128)      { dir = 0; b = iid >> 4; h = iid & 15; c = 0;
                          Yout = YiF0 + (size_t)(b * 16 + h) * 4096; Uout = UF0 + (size_t)(b * 16 + h) * 8192; }
    else if (iid < 624) { int k = iid - 128; dir = 0; c = 1 + (k >> 4); h = k & 15;
                          Yout = YiFs + (size_t)(c * 16 + h) * 4096; Uout = UFs + (size_t)(c * 16 + h) * 8192; }
    else                { int k = iid - 624; dir = 1; c = k >> 4; h = k & 15;
                          Yout = YiB + (size_t)(c * 16 + h) * 4096;  Uout = UB + (size_t)(c * 16 + h) * 8192; }
    const float* dtA = dir ? dtBs : dtFs;
    const float* cumA = dir ? cumB : cumF;

    const int tid = threadIdx.x;
    {   // stage B, C (bf16), X (fp32), cum, dt
        int r = tid >> 2, q = tid & 3;
        const float* row;
        if (dir == 0) {
            int t = 64 * c + 1 + r;
            row = (t < 4) ? convFp + (size_t)(b * 4 + t) * CONVD : convFs + (size_t)(t - 4) * CONVD;
        } else {
            row = convBs + (size_t)(64 * c + r) * CONVD;
        }
#pragma unroll
        for (int i = 0; i < 8; ++i) {
            int c4 = q + 4 * i;
            float4 v = *(const float4*)&row[1024 + c4 * 4];
            ushort4 p = make_ushort4(f2bf(v.x), f2bf(v.y), f2bf(v.z), f2bf(v.w));
            *(ushort4*)&Bt[r * 136 + c4 * 4] = p;
        }
#pragma unroll
        for (int i = 0; i < 8; ++i) {
            int c4 = q + 4 * i;
            float4 v = *(const float4*)&row[1152 + c4 * 4];
            ushort4 p = make_ushort4(f2bf(v.x), f2bf(v.y), f2bf(v.z), f2bf(v.w));
            *(ushort4*)&Ct[r * 136 + c4 * 4] = p;
        }
#pragma unroll
        for (int i = 0; i < 4; ++i) {
            int c4 = q + 4 * i;
            float4 v = *(const float4*)&row[h * 64 + c4 * 4];
            *(float4*)&Xt[r * 68 + c4 * 4] = v;
        }
        if (tid < 64) {
            int j = 64 * c + tid;
            scum[tid] = cumA[h * 2048 + j];
            sdt[tid] = dtA[j * 16 + h];
        }
    }
    __syncthreads();

    const int tx = tid & 15, ty = tid >> 4;
    // phase 1: G = C . B^T
    float acc[4][4];
#pragma unroll
    for (int i = 0; i < 4; ++i)
#pragma unroll
        for (int j = 0; j < 4; ++j) acc[i][j] = 0.f;
    for (int k = 0; k < 128; k += 4) {
        float cf[4][4], bfv[4][4];
#pragma unroll
        for (int i = 0; i < 4; ++i) {
            ushort4 v = *(ushort4*)&Ct[(ty + 16 * i) * 136 + k];
            cf[i][0] = bfu(v.x); cf[i][1] = bfu(v.y); cf[i][2] = bfu(v.z); cf[i][3] = bfu(v.w);
        }
#pragma unroll
        for (int j = 0; j < 4; ++j) {
            ushort4 v = *(ushort4*)&Bt[(tx + 16 * j) * 136 + k];
            bfv[j][0] = bfu(v.x); bfv[j][1] = bfu(v.y); bfv[j][2] = bfu(v.z); bfv[j][3] = bfu(v.w);
        }
#pragma unroll
        for (int i = 0; i < 4; ++i)
#pragma unroll
            for (int j = 0; j < 4; ++j)
                acc[i][j] += cf[i][0] * bfv[j][0] + cf[i][1] * bfv[j][1] +
                             cf[i][2] * bfv[j][2] + cf[i][3] * bfv[j][3];
    }
    __syncthreads();   // done reading Ct; Sm aliases it
#pragma unroll
    for (int i = 0; i < 4; ++i) {
        int t = ty + 16 * i;
#pragma unroll
        for (int j = 0; j < 4; ++j) {
            int s = tx + 16 * j;
            float v = (s <= t) ? __expf(scum[t] - scum[s]) * sdt[s] * acc[i][j] : 0.f;
            Sm[t * 68 + s] = v;
        }
    }
    __syncthreads();

    // phase 2+3: Yintra = S @ X ; U = B^T . (e*X)
    float4 accY[4];
    float4 accU[8];
#pragma unroll
    for (int i = 0; i < 4; ++i) accY[i] = make_float4(0.f, 0.f, 0.f, 0.f);
#pragma unroll
    for (int i = 0; i < 8; ++i) accU[i] = make_float4(0.f, 0.f, 0.f, 0.f);
    const float cend = scum[63];
    for (int s = 0; s < 64; ++s) {
        float4 xv = *(const float4*)&Xt[s * 68 + tx * 4];
        float es = __expf(cend - scum[s]) * sdt[s];
#pragma unroll
        for (int i = 0; i < 4; ++i) {
            float sv = Sm[(ty + 16 * i) * 68 + s];
            accY[i].x += sv * xv.x; accY[i].y += sv * xv.y;
            accY[i].z += sv * xv.z; accY[i].w += sv * xv.w;
        }
        float4 xe = make_float4(xv.x * es, xv.y * es, xv.z * es, xv.w * es);
#pragma unroll
        for (int i = 0; i < 8; ++i) {
            float bv = bfu(Bt[s * 136 + (ty + 16 * i)]);
            accU[i].x += bv * xe.x; accU[i].y += bv * xe.y;
            accU[i].z += bv * xe.z; accU[i].w += bv * xe.w;
        }
    }
#pragma unroll
    for (int i = 0; i < 4; ++i) {
        ushort4 p = make_ushort4(f2bf(accY[i].x), f2bf(accY[i].y), f2bf(accY[i].z), f2bf(accY[i].w));
        *(ushort4*)&Yout[(ty + 16 * i) * 64 + tx * 4] = p;
    }
#pragma unroll
    for (int i = 0; i < 8; ++i) {
        ushort4 p = make_ushort4(f2bf(accU[i].x), f2bf(accU[i].y), f2bf(accU[i].z), f2bf(accU[i].w));
        *(ushort4*)&Uout[(ty + 16 * i) * 64 + tx * 4] = p;
    }
}

// ---------------- chunk0 rank-1 inter coefficients ----------------

__global__ void cb0_kernel(const float* __restrict__ convFs, const float* __restrict__ convFp,
                           const float* __restrict__ dtFp, float* __restrict__ cb0) {
    int idx = blockIdx.x * 256 + threadIdx.x;   // 8192
    int b = idx >> 10, r = idx & 1023, h = r >> 6, tl = r & 63;
    int t = tl + 1;
    const float* crow = (t < 4) ? convFp + (size_t)(b * 4 + t) * CONVD : convFs + (size_t)(t - 4) * CONVD;
    const float* b0 = convFp + (size_t)(b * 4) * CONVD;
    float s = 0.f;
    for (int n = 0; n < 128; ++n) s += crow[1152 + n] * b0[1024 + n];
    cb0[(b * 16 + h) * 64 + tl] = s * dtFp[b * 16 + h];
}

// ---------------- M = D0*dt0*B0^T x0 + U0 ----------------

__global__ void m_kernel(const unsigned short* __restrict__ UF0, const float* __restrict__ convFp,
                         const float* __restrict__ dtFp, const float* __restrict__ cumF,
                         unsigned short* __restrict__ Mb) {
    int blk = blockIdx.x;   // 128: (b,h)
    int b = blk >> 4, h = blk & 15, tid = threadIdx.x;
    float D0 = __expf(cumF[h * 2048 + 63]);
    float dt0 = dtFp[b * 16 + h];
    const float* row0 = convFp + (size_t)(b * 4) * CONVD;
    const unsigned short* u = UF0 + (size_t)(b * 16 + h) * 8192;
    unsigned short* m = Mb + (size_t)(b * 16 + h) * 8192;
    for (int e4 = tid; e4 < 2048; e4 += 256) {
        int e = e4 * 4, n = e >> 6, p = e & 63;
        float Bn = D0 * dt0 * row0[1024 + n];
        float4 x4 = *(const float4*)&row0[h * 64 + p];
        ushort4 uv = *(const ushort4*)&u[e];
        ushort4 o = make_ushort4(f2bf(Bn * x4.x + bfu(uv.x)), f2bf(Bn * x4.y + bfu(uv.y)),
                                 f2bf(Bn * x4.z + bfu(uv.z)), f2bf(Bn * x4.w + bfu(uv.w)));
        *(ushort4*)&m[e] = o;
    }
}

// ---------------- shared chunk-state scan: T_c, psi_c ----------------

__global__ void tpsi_kernel(const unsigned short* __restrict__ UFs, const unsigned short* __restrict__ UB,
                            const float* __restrict__ cumF, const float* __restrict__ cumB,
                            unsigned short* __restrict__ Tst, float* __restrict__ psiF) {
    int blk = blockIdx.x;   // 32: dir*16+h
    int dir = blk >> 4, h = blk & 15;
    int tid = threadIdx.x;
    const unsigned short* U = dir ? UB : UFs;
    const float* cum = dir ? cumB : cumF;
    unsigned short* T = Tst + (size_t)(dir * 16 + h) * 32 * 8192;
    if (dir == 0 && tid == 0) {
        float ps = 1.f;
        for (int c = 1; c < 32; ++c) {
            psiF[h * 32 + c] = ps;
            ps *= __expf(cumF[h * 2048 + c * 64 + 63]);
        }
    }
    float4 st[8];
#pragma unroll
    for (int q = 0; q < 8; ++q) st[q] = make_float4(0.f, 0.f, 0.f, 0.f);
    int c0 = dir ? 0 : 1;
    for (int c = c0; c < 32; ++c) {
        float Dc = __expf(cum[h * 2048 + c * 64 + 63]);
#pragma unroll
        for (int q = 0; q < 8; ++q) {
            size_t e = 4 * tid + 1024 * q;
            ushort4 o = make_ushort4(f2bf(st[q].x), f2bf(st[q].y), f2bf(st[q].z), f2bf(st[q].w));
            *(ushort4*)&T[(size_t)c * 8192 + e] = o;
            ushort4 uv = *(const ushort4*)&U[((size_t)c * 16 + h) * 8192 + e];
            st[q].x = Dc * st[q].x + bfu(uv.x);
            st[q].y = Dc * st[q].y + bfu(uv.y);
            st[q].z = Dc * st[q].z + bfu(uv.z);
            st[q].w = Dc * st[q].w + bfu(uv.w);
        }
    }
}

// ---------------- gate kernel: MFMA Yinter + gating + partial RMS dot ----------------
// iid<4096: fwd (b,h,c). else bwd (h,c).

__global__ __launch_bounds__(256, 2) void gate_kernel(
    const float* __restrict__ convFs, const float* __restrict__ convFp,
    const float* __restrict__ convBs,
    const float* __restrict__ zxf, const float* __restrict__ zxb,
    const float* __restrict__ cumF, const float* __restrict__ cumB,
    const unsigned short* __restrict__ YiF0, const unsigned short* __restrict__ YiFs,
    const unsigned short* __restrict__ YiB,
    const unsigned short* __restrict__ Tst, const float* __restrict__ psiF,
    const unsigned short* __restrict__ Mb, const float* __restrict__ cb0,
    const float* __restrict__ fD, const float* __restrict__ bD,
    const float* __restrict__ wf2, const float* __restrict__ wb2,
    float* __restrict__ aF, float* __restrict__ aB) {
    __shared__ __align__(16) unsigned char smraw[17408 * 3];
    unsigned short* Cs  = (unsigned short*)smraw;              // 64 x 136  [t][n]
    unsigned short* WmT = (unsigned short*)(smraw + 17408);    // 64 x 136  [p][n]
    float* Ysm = (float*)(smraw + 2 * 17408);                  // 64 x 68   [t][p]

    const int iid = blockIdx.x;
    int dir, b = 0, h, c;
    if (iid < 4096) { dir = 0; b = iid >> 9; int r = iid & 511; h = r >> 5; c = r & 31; }
    else            { int k = iid - 4096; dir = 1; h = k >> 5; c = k & 31; }
    const int tid = threadIdx.x, tx = tid & 15, ty = tid >> 4;
    const int lane = tid & 63, wave = tid >> 6;
    const bool doGemm = !(dir == 0 && c == 0);

    if (doGemm) {
        int r = tid >> 2, q = tid & 3;
        const float* row;
        if (dir == 0) row = convFs + (size_t)(64 * c + 1 + r - 4) * CONVD;   // c>=1 -> t>=65
        else          row = convBs + (size_t)(64 * c + r) * CONVD;
#pragma unroll
        for (int i = 0; i < 8; ++i) {
            int c4 = q + 4 * i;
            float4 v = *(const float4*)&row[1152 + c4 * 4];
            ushort4 p = make_ushort4(f2bf(v.x), f2bf(v.y), f2bf(v.z), f2bf(v.w));
            *(ushort4*)&Cs[r * 136 + c4 * 4] = p;
        }
        const unsigned short* Tp = Tst + ((size_t)(dir * 16 + h) * 32 + c) * 8192;
        if (dir == 0) {
            float psi = psiF[h * 32 + c];
            const unsigned short* Mp = Mb + (size_t)(b * 16 + h) * 8192;
            for (int e = tid; e < 8192; e += 256) {
                int n = e >> 6, p = e & 63;
                WmT[p * 136 + n] = f2bf(bfu(Tp[e]) + psi * bfu(Mp[e]));
            }
        } else {
            for (int e = tid; e < 8192; e += 256) {
                int n = e >> 6, p = e & 63;
                WmT[p * 136 + n] = Tp[e];
            }
        }
    }
    __syncthreads();

    if (doGemm) {
        const int wt = (wave >> 1) * 32, wp = (wave & 1) * 32;
        f32x4 acc2[2][2];
#pragma unroll
        for (int i = 0; i < 2; ++i)
#pragma unroll
            for (int j = 0; j < 2; ++j) acc2[i][j] = (f32x4){0.f, 0.f, 0.f, 0.f};
#pragma unroll
        for (int ks = 0; ks < 4; ++ks) {
            bf16x8 af[2], bfr[2];
#pragma unroll
            for (int i = 0; i < 2; ++i)
                af[i] = *(const bf16x8*)&Cs[(wt + i * 16 + (lane & 15)) * 136 + ks * 32 + (lane >> 4) * 8];
#pragma unroll
            for (int j = 0; j < 2; ++j)
                bfr[j] = *(const bf16x8*)&WmT[(wp + j * 16 + (lane & 15)) * 136 + ks * 32 + (lane >> 4) * 8];
#pragma unroll
            for (int i = 0; i < 2; ++i)
#pragma unroll
                for (int j = 0; j < 2; ++j)
                    acc2[i][j] = __builtin_amdgcn_mfma_f32_16x16x32_bf16(af[i], bfr[j], acc2[i][j], 0, 0, 0);
        }
#pragma unroll
        for (int i = 0; i < 2; ++i)
#pragma unroll
            for (int j = 0; j < 2; ++j)
#pragma unroll
                for (int r = 0; r < 4; ++r)
                    Ysm[(wt + i * 16 + (lane >> 4) * 4 + r) * 68 + wp + j * 16 + (lane & 15)] = acc2[i][j][r];
    }
    __syncthreads();

    // gating + partial reduction
    const float Dh = (dir ? bD : fD)[h];
    const float* wvp = dir ? wb2 : wf2;
    float4 wreg = *(const float4*)&wvp[h * 64 + tx * 4];
    const float* cumA = dir ? cumB : cumF;
    float4 x0v = make_float4(0.f, 0.f, 0.f, 0.f);
    float cbv[4] = {0.f, 0.f, 0.f, 0.f};
    if (dir == 0 && c == 0) {
        x0v = *(const float4*)&convFp[(size_t)(b * 4) * CONVD + h * 64 + tx * 4];
#pragma unroll
        for (int i = 0; i < 4; ++i) cbv[i] = cb0[(b * 16 + h) * 64 + (ty + 16 * i)];
    }
#pragma unroll
    for (int i = 0; i < 4; ++i) {
        int tl = ty + 16 * i;
        int j = 64 * c + tl;
        float et = __expf(cumA[h * 2048 + j]);
        const unsigned short* Yi;
        const float *xrow, *zrow;
        if (dir == 0) {
            int t = j + 1;
            Yi = (c == 0) ? YiF0 + (size_t)(b * 16 + h) * 4096 : YiFs + (size_t)(c * 16 + h) * 4096;
            xrow = (t < 4) ? convFp + (size_t)(b * 4 + t) * CONVD : convFs + (size_t)(t - 4) * CONVD;
            zrow = zxf + (size_t)j * DPROJ;
        } else {
            Yi = YiB + (size_t)(c * 16 + h) * 4096;
            xrow = convBs + (size_t)j * CONVD;
            zrow = zxb + (size_t)(2047 - j) * DPROJ;
        }
        ushort4 yi4 = *(const ushort4*)&Yi[tl * 64 + tx * 4];
        float4 xx = *(const float4*)&xrow[h * 64 + tx * 4];
        float4 zz = *(const float4*)&zrow[h * 64 + tx * 4];
        float ya[4] = {0.f, 0.f, 0.f, 0.f};
        if (doGemm) {
            float4 y4 = *(const float4*)&Ysm[tl * 68 + tx * 4];
            ya[0] = y4.x; ya[1] = y4.y; ya[2] = y4.z; ya[3] = y4.w;
        }
        float yv[4] = {bfu(yi4.x), bfu(yi4.y), bfu(yi4.z), bfu(yi4.w)};
        float xa[4] = {xx.x, xx.y, xx.z, xx.w};
        float za[4] = {zz.x, zz.y, zz.z, zz.w};
        float x0a[4] = {x0v.x, x0v.y, x0v.z, x0v.w};
        float wa[4] = {wreg.x, wreg.y, wreg.z, wreg.w};
        float a1 = 0.f, a2 = 0.f;
#pragma unroll
        for (int w = 0; w < 4; ++w) {
            float tot = yv[w] + et * (ya[w] + cbv[i] * x0a[w]) + Dh * xa[w];
            float g = tot * siluf(za[w]);
            a1 += g * wa[w];
            a2 += g * g;
        }
#pragma unroll
        for (int m = 1; m < 16; m <<= 1) {
            a1 += __shfl_xor(a1, m);
            a2 += __shfl_xor(a2, m);
        }
        if (tx == 0) {
            if (dir == 0) {
                size_t o = ((size_t)(b * 2048 + j) * 16 + h) * 2;
                aF[o] = a1; aF[o + 1] = a2;
            } else {
                int g = 2047 - j;
                size_t o = ((size_t)g * 16 + h) * 2;
                aB[o] = a1; aB[o + 1] = a2;
            }
        }
    }
}

// ---------------- final combine ----------------

__global__ void final_kernel(const float* __restrict__ aF, const float* __restrict__ aB,
                             const float* __restrict__ headB, float* __restrict__ out) {
    int idx = blockIdx.x * 256 + threadIdx.x;   // 16384
    int b = idx >> 11, g = idx & 2047;
    const float* pf = aF + ((size_t)(b * 2048 + g)) * 32;
    const float* pb = aB + (size_t)g * 32;
    float f1 = 0.f, f2 = 0.f, b1 = 0.f, b2 = 0.f;
#pragma unroll
    for (int h = 0; h < 16; ++h) {
        f1 += pf[2 * h]; f2 += pf[2 * h + 1];
        b1 += pb[2 * h]; b2 += pb[2 * h + 1];
    }
    out[idx] = f1 * rsqrtf(f2 * (1.f / 1024.f) + 1e-5f) +
               b1 * rsqrtf(b2 * (1.f / 1024.f) + 1e-5f) + headB[0];
}

// ---------------- launch ----------------

extern "C" void kernel_launch(void* const* d_in, const int* in_sizes, int n_in,
                              void* d_out, int out_size, void* d_ws, size_t ws_size,
                              hipStream_t stream) {
    const int*   pidx   = (const int*)  d_in[0];
    const int*   chridx = (const int*)  d_in[1];
    const float* locusF = (const float*)d_in[2];
    const float* pathF  = (const float*)d_in[3];
    const float* pertE  = (const float*)d_in[4];
    const float* gidE   = (const float*)d_in[5];
    const float* chrE   = (const float*)d_in[6];
    const float* locusW = (const float*)d_in[7];
    const float* locusB = (const float*)d_in[8];
    const float* condW  = (const float*)d_in[9];
    const float* condB  = (const float*)d_in[10];
    const float* inW    = (const float*)d_in[11];
    const float* inB    = (const float*)d_in[12];
    const float* headW  = (const float*)d_in[13];
    const float* headB  = (const float*)d_in[14];
    const float* fInW   = (const float*)d_in[15];
    const float* fCw    = (const float*)d_in[16];
    const float* fCb    = (const float*)d_in[17];
    const float* fDtB   = (const float*)d_in[18];
    const float* fAlog  = (const float*)d_in[19];
    const float* fDp    = (const float*)d_in[20];
    const float* fNw    = (const float*)d_in[21];
    const float* fOutW  = (const float*)d_in[22];
    const float* bInW   = (const float*)d_in[23];
    const float* bCw    = (const float*)d_in[24];
    const float* bCb    = (const float*)d_in[25];
    const float* bDtB   = (const float*)d_in[26];
    const float* bAlog  = (const float*)d_in[27];
    const float* bDp    = (const float*)d_in[28];
    const float* bNw    = (const float*)d_in[29];
    const float* bOutW  = (const float*)d_in[30];
    float* out = (float*)d_out;
    (void)in_sizes; (void)n_in; (void)out_size; (void)ws_size;

    char* base = (char*)d_ws;
    size_t off = 0;
    auto allocf = [&](size_t n) -> float* {
        char* r = base + off; off += ((n * 4 + 63) & ~(size_t)63); return (float*)r; };
    auto allocu = [&](size_t n) -> unsigned short* {
        char* r = base + off; off += ((n * 2 + 63) & ~(size_t)63); return (unsigned short*)r; };

    float* gf     = allocf(2048UL * 384);
    float* cond   = allocf(8UL * 384);
    float* cemb   = allocf(8UL * 128);
    float* ug     = allocf(2048UL * 512);
    float* uc     = allocf(8UL * 512);
    float* zxf    = allocf(2048UL * DPROJ);
    float* zxb    = allocf(2048UL * DPROJ);
    float* zxc    = allocf(8UL * DPROJ);
    float* convFs = allocf(2045UL * CONVD);
    float* convFp = allocf(8UL * 4 * CONVD);
    float* convBs = allocf(2048UL * CONVD);
    float* dtFs   = allocf(2048UL * 16);
    float* dtFp   = allocf(128);
    float* dtBs   = allocf(2048UL * 16);
    float* cumF   = allocf(16UL * 2048);
    float* cumB   = allocf(16UL * 2048);
    float* wf2    = allocf(1024);
    float* wb2    = allocf(1024);
    float* cb0    = allocf(8UL * 16 * 64);
    float* psiF   = allocf(16UL * 32);
    float* aF     = allocf(8UL * 2048 * 16 * 2);
    float* aB     = allocf(2048UL * 16 * 2);
    unsigned short* YiF0 = allocu(8UL * 16 * 4096);
    unsigned short* YiFs = allocu(32UL * 16 * 4096);
    unsigned short* YiB  = allocu(32UL * 16 * 4096);
    unsigned short* UF0  = allocu(8UL * 16 * 8192);
    unsigned short* UFs  = allocu(32UL * 16 * 8192);
    unsigned short* UB   = allocu(32UL * 16 * 8192);
    unsigned short* Mb   = allocu(8UL * 16 * 8192);
    unsigned short* Tst  = allocu(2UL * 16 * 32 * 8192);
    unsigned short* gf2   = allocu(2048UL * 768);
    unsigned short* inW2  = allocu(512UL * 768);
    unsigned short* ug2   = allocu(2048UL * 1024);
    unsigned short* fInW2 = allocu(2432UL * 1024);
    unsigned short* bInW2 = allocu(2432UL * 1024);

    gather_kernel<<<4, 256, 0, stream>>>(pidx, pertE, cemb);
    wfold_kernel<<<8, 256, 0, stream>>>(headW, fOutW, fNw, bOutW, bNw, wf2, wb2);
    genefeat_kernel<<<3072, 256, 0, stream>>>(chridx, gidE, pathF, chrE, gf);
    gemm_kernel<<<dim3(1, 32), 256, 0, stream>>>(locusF, locusW, locusB, gf + 320, 2048, 64, 64, 384, 1);
    gemm_kernel<<<dim3(6, 1), 256, 0, stream>>>(cemb, condW, condB, cond, 8, 384, 128, 384, 0);

    // weight conversions (independent of data path)
    tobf_kernel<<<(512 * 384 + 255) / 256, 256, 0, stream>>>(inW, inW2, 512, 384, 512);
    tobf_kernel<<<(2432 * 512 + 255) / 256, 256, 0, stream>>>(fInW, fInW2, 2320, 512, 2432);
    tobf_kernel<<<(2432 * 512 + 255) / 256, 256, 0, stream>>>(bInW, bInW2, 2320, 512, 2432);

    // ug = gf @ inW^T  (MFMA, hi/lo split)
    tobf_kernel<<<(2048 * 384 + 255) / 256, 256, 0, stream>>>(gf, gf2, 2048, 384, 2048);
    mfma_gemm_kernel<<<dim3(4, 16), 256, 0, stream>>>(gf2, inW2, inB, ug, 512, 768, 512);
    gemm_kernel<<<dim3(8, 1), 256, 0, stream>>>(cond, inW, inB, uc, 8, 512, 384, 512, 0);

    // zxf/zxb = ug @ {f,b}InW^T  (MFMA, hi/lo split)
    tobf_kernel<<<(2048 * 512 + 255) / 256, 256, 0, stream>>>(ug, ug2, 2048, 512, 2048);
    mfma_gemm_kernel<<<dim3(19, 16), 256, 0, stream>>>(ug2, fInW2, nullptr, zxf, 2320, 1024, 2320);
    mfma_gemm_kernel<<<dim3(19, 16), 256, 0, stream>>>(ug2, bInW2, nullptr, zxb, 2320, 1024, 2320);
    gemm_kernel<<<dim3(37, 1), 256, 0, stream>>>(uc, fInW, nullptr, zxc, 8, DPROJ, 512, DPROJ, 0);

    dt_kernel<<<128, 256, 0, stream>>>(zxf, fDtB, dtFs, 0);
    dt_kernel<<<128, 256, 0, stream>>>(zxb, bDtB, dtBs, 1);
    dtpb_kernel<<<1, 128, 0, stream>>>(zxc, fDtB, dtFp);
    cum_kernel<<<4, 256, 0, stream>>>(dtFs, dtBs, fAlog, bAlog, cumF, cumB);
    convFsh_kernel<<<(2045 * 1280 + 255) / 256, 256, 0, stream>>>(zxf, fCw, fCb, convFs);
    convFpb_kernel<<<160, 256, 0, stream>>>(zxf, zxc, fCw, fCb, convFp);
    convBsh_kernel<<<10240, 256, 0, stream>>>(zxb, bCw, bCb, convBs);
    intra_kernel<<<1136, 256, 0, stream>>>(convFs, convFp, convBs, dtFs, dtBs, cumF, cumB,
                                           YiF0, YiFs, YiB, UF0, UFs, UB);
    cb0_kernel<<<32, 256, 0, stream>>>(convFs, convFp, dtFp, cb0);
    m_kernel<<<128, 256, 0, stream>>>(UF0, convFp, dtFp, cumF, Mb);
    tpsi_kernel<<<32, 256, 0, stream>>>(UFs, UB, cumF, cumB, Tst, psiF);
    gate_kernel<<<4608, 256, 0, stream>>>(convFs, convFp, convBs, zxf, zxb, cumF, cumB,
                                          YiF0, YiFs, YiB, Tst, psiF, Mb, cb0,
                                          fDp, bDp, wf2, wb2, aF, aB);
    final_kernel<<<64, 256, 0, stream>>>(aF, aB, headB, out);
}

// Round 4
// 491.465 us; speedup vs baseline: 5.8725x; 1.0677x over previous
//
#include <hip/hip_runtime.h>
#include <hip/hip_bf16.h>
#include <math.h>

#define DPROJ 2320
#define CONVD 1280

typedef __attribute__((ext_vector_type(8))) short bf16x8;
typedef __attribute__((ext_vector_type(4))) float f32x4;

__device__ __forceinline__ float siluf(float x) { return x / (1.f + __expf(-x)); }
__device__ __forceinline__ float bfu(unsigned short s) { return __uint_as_float(((unsigned)s) << 16); }
__device__ __forceinline__ unsigned short f2bf(float f) {
    unsigned u = __float_as_uint(f);
    unsigned r = (u + 0x7FFFu + ((u >> 16) & 1u)) >> 16;
    return (unsigned short)r;
}

// ---------------- small prep kernels ----------------

__global__ void gather_kernel(const int* __restrict__ pidx, const float* __restrict__ pertE,
                              float* __restrict__ cemb) {
    int idx = blockIdx.x * 256 + threadIdx.x;   // 1024
    int b = idx >> 7, k = idx & 127;
    cemb[idx] = pertE[(size_t)pidx[b] * 128 + k];
}

__global__ void wfold_kernel(const float* __restrict__ headW,
                             const float* __restrict__ fOutW, const float* __restrict__ fNw,
                             const float* __restrict__ bOutW, const float* __restrict__ bNw,
                             float* __restrict__ wf2, float* __restrict__ wb2) {
    __shared__ float red[256];
    int blk = blockIdx.x;   // 32: dir*16 + dchunk
    int dir = blk >> 4, dc = blk & 15;
    int tid = threadIdx.x;
    int d = dc * 64 + (tid & 63), seg = tid >> 6;
    const float* W = dir ? bOutW : fOutW;
    float s = 0.f;
    for (int m = seg * 128; m < seg * 128 + 128; ++m) s += headW[m] * W[(size_t)m * 1024 + d];
    red[tid] = s;
    __syncthreads();
    if (tid < 64) {
        float tot = red[tid] + red[tid + 64] + red[tid + 128] + red[tid + 192];
        const float* nw = dir ? bNw : fNw;
        (dir ? wb2 : wf2)[d] = tot * nw[d];
    }
}

__global__ void genefeat_kernel(const int* __restrict__ chridx, const float* __restrict__ gid,
                                const float* __restrict__ path, const float* __restrict__ chrE,
                                float* __restrict__ gf) {
    int idx = blockIdx.x * 256 + threadIdx.x;   // 2048*384
    int g = idx / 384, j = idx % 384;
    float v;
    if (j < 128)      v = gid[(size_t)g * 128 + j];
    else if (j < 256) v = path[(size_t)g * 128 + (j - 128)];
    else if (j < 320) v = chrE[(size_t)chridx[g] * 64 + (j - 256)];
    else return;      // cols 320..383 written by the locus GEMM
    gf[idx] = v;
}

// ---------------- hi/lo bf16 split conversion: out[m][k]=hi, out[m][K+k]=lo ----------------

__global__ void tobf_kernel(const float* __restrict__ in, unsigned short* __restrict__ out,
                            int M, int K, int Mpad) {
    int idx = blockIdx.x * 256 + threadIdx.x;
    if (idx >= Mpad * K) return;
    int m = idx / K, k = idx % K;
    float v = (m < M) ? in[(size_t)m * K + k] : 0.f;
    unsigned short hi = f2bf(v);
    unsigned short lo = f2bf(v - bfu(hi));
    out[(size_t)m * 2 * K + k] = hi;
    out[(size_t)m * 2 * K + K + k] = lo;
}

// ---------------- MFMA GEMM: C[M x N] = A2[M x K2] . W2[Npad x K2]^T (+bias) ----------------

__global__ __launch_bounds__(256) void mfma_gemm_kernel(
    const unsigned short* __restrict__ A2, const unsigned short* __restrict__ W2,
    const float* __restrict__ bias, float* __restrict__ C,
    int N, int K2, int ldc) {
    __shared__ __align__(16) unsigned short Al[128 * 40];
    __shared__ __align__(16) unsigned short Bl[128 * 40];
    const int tid = threadIdx.x;
    const int bm = blockIdx.y * 128, bn = blockIdx.x * 128;
    const int lane = tid & 63, wave = tid >> 6;
    const int wm = (wave >> 1) * 64, wn = (wave & 1) * 64;
    f32x4 acc[4][4];
#pragma unroll
    for (int i = 0; i < 4; ++i)
#pragma unroll
        for (int j = 0; j < 4; ++j) acc[i][j] = (f32x4){0.f, 0.f, 0.f, 0.f};

    for (int k0 = 0; k0 < K2; k0 += 32) {
        __syncthreads();
#pragma unroll
        for (int s = 0; s < 2; ++s) {
            int ch = tid + 256 * s;
            int row = ch >> 2, q = ch & 3;
            uint4 va = *(const uint4*)&A2[(size_t)(bm + row) * K2 + k0 + q * 8];
            *(uint4*)&Al[row * 40 + q * 8] = va;
            uint4 vb = *(const uint4*)&W2[(size_t)(bn + row) * K2 + k0 + q * 8];
            *(uint4*)&Bl[row * 40 + q * 8] = vb;
        }
        __syncthreads();
        bf16x8 af[4], bfr[4];
#pragma unroll
        for (int i = 0; i < 4; ++i)
            af[i] = *(const bf16x8*)&Al[(wm + i * 16 + (lane & 15)) * 40 + (lane >> 4) * 8];
#pragma unroll
        for (int j = 0; j < 4; ++j)
            bfr[j] = *(const bf16x8*)&Bl[(wn + j * 16 + (lane & 15)) * 40 + (lane >> 4) * 8];
#pragma unroll
        for (int i = 0; i < 4; ++i)
#pragma unroll
            for (int j = 0; j < 4; ++j)
                acc[i][j] = __builtin_amdgcn_mfma_f32_16x16x32_bf16(af[i], bfr[j], acc[i][j], 0, 0, 0);
    }
#pragma unroll
    for (int i = 0; i < 4; ++i) {
        int m = bm + wm + i * 16 + (lane >> 4) * 4;
#pragma unroll
        for (int j = 0; j < 4; ++j) {
            int n = bn + wn + j * 16 + (lane & 15);
            if (n < N) {
                float bv = bias ? bias[n] : 0.f;
#pragma unroll
                for (int r = 0; r < 4; ++r)
                    C[(size_t)(m + r) * ldc + n] = acc[i][j][r] + bv;
            }
        }
    }
}

// ---------------- generic tiled fp32 GEMM (small shapes only) ----------------

__global__ __launch_bounds__(256) void gemm_kernel(
    const float* __restrict__ A, const float* __restrict__ W,
    const float* __restrict__ bias, float* __restrict__ C,
    int M, int N, int K, int ldc, int act) {
    __shared__ __align__(16) float As[16][68];
    __shared__ __align__(16) float Ws[16][68];
    const int tid = threadIdx.x;
    const int tx = tid & 15, ty = tid >> 4;
    const int bm = blockIdx.y * 64, bn = blockIdx.x * 64;
    const int lr = tid >> 2;
    const int lk = (tid & 3) * 4;
    float acc[4][4];
#pragma unroll
    for (int i = 0; i < 4; ++i)
#pragma unroll
        for (int j = 0; j < 4; ++j) acc[i][j] = 0.f;

    for (int k0 = 0; k0 < K; k0 += 16) {
        const int am = bm + lr;
        const int wn = bn + lr;
        float4 av = make_float4(0.f, 0.f, 0.f, 0.f), wv = make_float4(0.f, 0.f, 0.f, 0.f);
        if (am < M) av = *(const float4*)&A[(size_t)am * K + k0 + lk];
        if (wn < N) wv = *(const float4*)&W[(size_t)wn * K + k0 + lk];
        __syncthreads();
        As[lk + 0][lr] = av.x; As[lk + 1][lr] = av.y; As[lk + 2][lr] = av.z; As[lk + 3][lr] = av.w;
        Ws[lk + 0][lr] = wv.x; Ws[lk + 1][lr] = wv.y; Ws[lk + 2][lr] = wv.z; Ws[lk + 3][lr] = wv.w;
        __syncthreads();
#pragma unroll
        for (int kk = 0; kk < 16; ++kk) {
            float4 a = *(const float4*)&As[kk][ty * 4];
            float4 w = *(const float4*)&Ws[kk][tx * 4];
            float aa[4] = {a.x, a.y, a.z, a.w}, ww[4] = {w.x, w.y, w.z, w.w};
#pragma unroll
            for (int i = 0; i < 4; ++i)
#pragma unroll
                for (int j = 0; j < 4; ++j) acc[i][j] += aa[i] * ww[j];
        }
    }
#pragma unroll
    for (int i = 0; i < 4; ++i) {
        const int m = bm + ty * 4 + i;
        if (m >= M) continue;
#pragma unroll
        for (int j = 0; j < 4; ++j) {
            const int n = bn + tx * 4 + j;
            if (n >= N) continue;
            float v = acc[i][j] + (bias ? bias[n] : 0.f);
            if (act == 1) v = 0.5f * v * (1.f + erff(v * 0.70710678118654752f));
            C[(size_t)m * ldc + n] = v;
        }
    }
}

// ---------------- dt precompute ----------------

__global__ void dt_kernel(const float* __restrict__ zx, const float* __restrict__ dt_bias,
                          float* __restrict__ dt_o, int flip) {
    int idx = blockIdx.x * 256 + threadIdx.x;   // 32768
    int r = idx >> 4, h = idx & 15;
    int row = flip ? (2047 - r) : r;
    float raw = zx[(size_t)row * DPROJ + 2304 + h] + dt_bias[h];
    float dt = (raw > 20.f) ? raw : log1pf(expf(raw));
    dt_o[idx] = dt;
}

__global__ void dtpb_kernel(const float* __restrict__ zxc, const float* __restrict__ dt_bias,
                            float* __restrict__ dt_o) {
    int idx = threadIdx.x;   // 128
    int b = idx >> 4, h = idx & 15;
    float raw = zxc[(size_t)b * DPROJ + 2304 + h] + dt_bias[h];
    float dt = (raw > 20.f) ? raw : log1pf(expf(raw));
    dt_o[idx] = dt;
}

// chunk-local inclusive cumsum of ldA = -dt*exp(A_log)
__global__ void cum_kernel(const float* __restrict__ dtFs, const float* __restrict__ dtBs,
                           const float* __restrict__ fAlog, const float* __restrict__ bAlog,
                           float* __restrict__ cumF, float* __restrict__ cumB) {
    int id = blockIdx.x * 256 + threadIdx.x;   // 1024
    int dir = id >> 9, k = id & 511, h = k >> 5, c = k & 31;
    const float* dt = dir ? dtBs : dtFs;
    const float* Al = dir ? bAlog : fAlog;
    float* cum = dir ? cumB : cumF;
    float a = expf(Al[h]);
    float acc = 0.f;
    for (int s = 0; s < 64; ++s) {
        int j = c * 64 + s;
        acc += -dt[j * 16 + h] * a;
        cum[h * 2048 + j] = acc;
    }
}

// ---------------- causal depthwise conv (+SiLU) ----------------

__global__ void convFsh_kernel(const float* __restrict__ zxf, const float* __restrict__ cw,
                               const float* __restrict__ cb, float* __restrict__ outp) {
    int idx = blockIdx.x * 256 + threadIdx.x;
    if (idx >= 2045 * 1280) return;
    int t4 = idx / 1280, c = idx % 1280;
    float4 w4 = *(const float4*)&cw[c * 4];
    float acc = cb[c];
    acc += zxf[(size_t)(t4 + 0) * DPROJ + 1024 + c] * w4.x;
    acc += zxf[(size_t)(t4 + 1) * DPROJ + 1024 + c] * w4.y;
    acc += zxf[(size_t)(t4 + 2) * DPROJ + 1024 + c] * w4.z;
    acc += zxf[(size_t)(t4 + 3) * DPROJ + 1024 + c] * w4.w;
    outp[idx] = siluf(acc);
}

__global__ void convFpb_kernel(const float* __restrict__ zxf, const float* __restrict__ zxc,
                               const float* __restrict__ cw, const float* __restrict__ cb,
                               float* __restrict__ outp) {
    int idx = blockIdx.x * 256 + threadIdx.x;   // 8*4*1280
    int b = idx / 5120;
    int r = idx % 5120;
    int t = r / 1280, c = r % 1280;
    float4 w4 = *(const float4*)&cw[c * 4];
    float w[4] = {w4.x, w4.y, w4.z, w4.w};
    float acc = cb[c];
#pragma unroll
    for (int k = 0; k < 4; ++k) {
        int j = t - 3 + k;
        float x = 0.f;
        if (j == 0)      x = zxc[(size_t)b * DPROJ + 1024 + c];
        else if (j >= 1) x = zxf[(size_t)(j - 1) * DPROJ + 1024 + c];
        acc += x * w[k];
    }
    outp[idx] = siluf(acc);
}

__global__ void convBsh_kernel(const float* __restrict__ zxb, const float* __restrict__ cw,
                               const float* __restrict__ cb, float* __restrict__ outp) {
    int idx = blockIdx.x * 256 + threadIdx.x;   // 2048*1280
    int s = idx / 1280, c = idx % 1280;
    float4 w4 = *(const float4*)&cw[c * 4];
    float w[4] = {w4.x, w4.y, w4.z, w4.w};
    float acc = cb[c];
#pragma unroll
    for (int k = 0; k < 4; ++k) {
        int j = s - 3 + k;
        if (j >= 0) acc += zxb[(size_t)(2047 - j) * DPROJ + 1024 + c] * w[k];
    }
    outp[idx] = siluf(acc);
}

// ---------------- intra-chunk kernel (MFMA) ----------------
// Phase 1: G = C.B^T (64x64x128) -> mask/decay -> S (bf16, LDS)
// Phase 2: Yintra = S@X (64x64x64)
// Phase 3: U = B^T.(e*X) (128x64x64)

__global__ __launch_bounds__(256) void intra_kernel(
    const float* __restrict__ convFs, const float* __restrict__ convFp,
    const float* __restrict__ convBs,
    const float* __restrict__ dtFs, const float* __restrict__ dtBs,
    const float* __restrict__ cumF, const float* __restrict__ cumB,
    unsigned short* __restrict__ YiF0, unsigned short* __restrict__ YiFs,
    unsigned short* __restrict__ YiB,
    unsigned short* __restrict__ UF0, unsigned short* __restrict__ UFs,
    unsigned short* __restrict__ UB) {
    __shared__ __align__(16) unsigned char smraw[63232];
    unsigned short* Bt = (unsigned short*)smraw;                    // 64 x 136  [s][n]
    unsigned short* Ct = (unsigned short*)(smraw + 17408);          // 64 x 136  [t][n]
    unsigned short* Sm = (unsigned short*)(smraw + 17408);          // 64 x 72   [t][s] (alias Ct)
    unsigned short* BT = (unsigned short*)(smraw + 34816);          // 128 x 72  [n][s]
    unsigned short* XT = (unsigned short*)(smraw + 53248);          // 64 x 72   [p][s]
    float* scum = (float*)(smraw + 62464);                          // 64
    float* sdt  = scum + 64;                                        // 64
    float* se   = scum + 128;                                       // 64

    const int iid = blockIdx.x;
    int dir, b = 0, h, c;
    unsigned short *Yout, *Uout;
    if (iid < 128)      { dir = 0; b = iid >> 4; h = iid & 15; c = 0;
                          Yout = YiF0 + (size_t)(b * 16 + h) * 4096; Uout = UF0 + (size_t)(b * 16 + h) * 8192; }
    else if (iid < 624) { int k = iid - 128; dir = 0; c = 1 + (k >> 4); h = k & 15;
                          Yout = YiFs + (size_t)(c * 16 + h) * 4096; Uout = UFs + (size_t)(c * 16 + h) * 8192; }
    else                { int k = iid - 624; dir = 1; c = k >> 4; h = k & 15;
                          Yout = YiB + (size_t)(c * 16 + h) * 4096;  Uout = UB + (size_t)(c * 16 + h) * 8192; }
    const float* dtA = dir ? dtBs : dtFs;
    const float* cumA = dir ? cumB : cumF;

    const int tid = threadIdx.x;
    const int lane = tid & 63, wave = tid >> 6;
    const int quad = lane >> 4, l15 = lane & 15;

    {   // stage B [s][n] + B^T [n][s], C [t][n], X^T [p][s] (all bf16), cum, dt
        int r = tid >> 2, q = tid & 3;
        const float* row;
        if (dir == 0) {
            int t = 64 * c + 1 + r;
            row = (t < 4) ? convFp + (size_t)(b * 4 + t) * CONVD : convFs + (size_t)(t - 4) * CONVD;
        } else {
            row = convBs + (size_t)(64 * c + r) * CONVD;
        }
#pragma unroll
        for (int i = 0; i < 8; ++i) {
            int n0 = (q + 4 * i) * 4;
            float4 v = *(const float4*)&row[1024 + n0];
            ushort4 p = make_ushort4(f2bf(v.x), f2bf(v.y), f2bf(v.z), f2bf(v.w));
            *(ushort4*)&Bt[r * 136 + n0] = p;
            BT[(n0 + 0) * 72 + r] = p.x;
            BT[(n0 + 1) * 72 + r] = p.y;
            BT[(n0 + 2) * 72 + r] = p.z;
            BT[(n0 + 3) * 72 + r] = p.w;
        }
#pragma unroll
        for (int i = 0; i < 8; ++i) {
            int n0 = (q + 4 * i) * 4;
            float4 v = *(const float4*)&row[1152 + n0];
            ushort4 p = make_ushort4(f2bf(v.x), f2bf(v.y), f2bf(v.z), f2bf(v.w));
            *(ushort4*)&Ct[r * 136 + n0] = p;
        }
#pragma unroll
        for (int i = 0; i < 4; ++i) {
            int p0 = (q + 4 * i) * 4;
            float4 v = *(const float4*)&row[h * 64 + p0];
            XT[(p0 + 0) * 72 + r] = f2bf(v.x);
            XT[(p0 + 1) * 72 + r] = f2bf(v.y);
            XT[(p0 + 2) * 72 + r] = f2bf(v.z);
            XT[(p0 + 3) * 72 + r] = f2bf(v.w);
        }
        if (tid < 64) {
            int j = 64 * c + tid;
            scum[tid] = cumA[h * 2048 + j];
            sdt[tid] = dtA[j * 16 + h];
        }
    }
    __syncthreads();
    if (tid < 64) se[tid] = __expf(scum[63] - scum[tid]) * sdt[tid];

    // phase 1: G = C . B^T
    const int tm = (wave >> 1) * 32, sn = (wave & 1) * 32;
    f32x4 acc1[2][2];
#pragma unroll
    for (int i = 0; i < 2; ++i)
#pragma unroll
        for (int j = 0; j < 2; ++j) acc1[i][j] = (f32x4){0.f, 0.f, 0.f, 0.f};
#pragma unroll
    for (int ks = 0; ks < 4; ++ks) {
        bf16x8 af[2], bfr[2];
#pragma unroll
        for (int i = 0; i < 2; ++i)
            af[i] = *(const bf16x8*)&Ct[(tm + i * 16 + l15) * 136 + ks * 32 + quad * 8];
#pragma unroll
        for (int j = 0; j < 2; ++j)
            bfr[j] = *(const bf16x8*)&Bt[(sn + j * 16 + l15) * 136 + ks * 32 + quad * 8];
#pragma unroll
        for (int i = 0; i < 2; ++i)
#pragma unroll
            for (int j = 0; j < 2; ++j)
                acc1[i][j] = __builtin_amdgcn_mfma_f32_16x16x32_bf16(af[i], bfr[j], acc1[i][j], 0, 0, 0);
    }
    __syncthreads();   // all Ct reads done; Sm aliases Ct

    // mask + decay + dt scale -> S (bf16)
#pragma unroll
    for (int j = 0; j < 2; ++j) {
        int s = sn + j * 16 + l15;
        float cs = scum[s], ds = sdt[s];
#pragma unroll
        for (int i = 0; i < 2; ++i) {
#pragma unroll
            for (int r = 0; r < 4; ++r) {
                int t = tm + i * 16 + quad * 4 + r;
                float v = (s <= t) ? __expf(scum[t] - cs) * ds * acc1[i][j][r] : 0.f;
                Sm[t * 72 + s] = f2bf(v);
            }
        }
    }
    __syncthreads();

    // phase 2: Yintra = S @ X   (B-operand = X^T)
    const int pn = (wave & 1) * 32;
    f32x4 acc2[2][2];
#pragma unroll
    for (int i = 0; i < 2; ++i)
#pragma unroll
        for (int j = 0; j < 2; ++j) acc2[i][j] = (f32x4){0.f, 0.f, 0.f, 0.f};
#pragma unroll
    for (int ks = 0; ks < 2; ++ks) {
        bf16x8 af[2], bfr[2];
#pragma unroll
        for (int i = 0; i < 2; ++i)
            af[i] = *(const bf16x8*)&Sm[(tm + i * 16 + l15) * 72 + ks * 32 + quad * 8];
#pragma unroll
        for (int j = 0; j < 2; ++j)
            bfr[j] = *(const bf16x8*)&XT[(pn + j * 16 + l15) * 72 + ks * 32 + quad * 8];
#pragma unroll
        for (int i = 0; i < 2; ++i)
#pragma unroll
            for (int j = 0; j < 2; ++j)
                acc2[i][j] = __builtin_amdgcn_mfma_f32_16x16x32_bf16(af[i], bfr[j], acc2[i][j], 0, 0, 0);
    }
#pragma unroll
    for (int i = 0; i < 2; ++i)
#pragma unroll
        for (int j = 0; j < 2; ++j)
#pragma unroll
            for (int r = 0; r < 4; ++r) {
                int t = tm + i * 16 + quad * 4 + r;
                int p = pn + j * 16 + l15;
                Yout[t * 64 + p] = f2bf(acc2[i][j][r]);
            }

    // phase 3: U = B^T . (e*X)   (A = BT rows n, B-operand = (eX)^T)
    const int nm = wave * 32;
    f32x4 acc3[2][4];
#pragma unroll
    for (int i = 0; i < 2; ++i)
#pragma unroll
        for (int j = 0; j < 4; ++j) acc3[i][j] = (f32x4){0.f, 0.f, 0.f, 0.f};
#pragma unroll
    for (int ks = 0; ks < 2; ++ks) {
        float ev[8];
#pragma unroll
        for (int jj = 0; jj < 8; ++jj) ev[jj] = se[ks * 32 + quad * 8 + jj];
        bf16x8 bfx[4];
#pragma unroll
        for (int j = 0; j < 4; ++j) {
            bf16x8 xs = *(const bf16x8*)&XT[(j * 16 + l15) * 72 + ks * 32 + quad * 8];
#pragma unroll
            for (int jj = 0; jj < 8; ++jj)
                bfx[j][jj] = (short)f2bf(bfu((unsigned short)xs[jj]) * ev[jj]);
        }
        bf16x8 af[2];
#pragma unroll
        for (int i = 0; i < 2; ++i)
            af[i] = *(const bf16x8*)&BT[(nm + i * 16 + l15) * 72 + ks * 32 + quad * 8];
#pragma unroll
        for (int i = 0; i < 2; ++i)
#pragma unroll
            for (int j = 0; j < 4; ++j)
                acc3[i][j] = __builtin_amdgcn_mfma_f32_16x16x32_bf16(af[i], bfx[j], acc3[i][j], 0, 0, 0);
    }
#pragma unroll
    for (int i = 0; i < 2; ++i)
#pragma unroll
        for (int j = 0; j < 4; ++j)
#pragma unroll
            for (int r = 0; r < 4; ++r) {
                int n = nm + i * 16 + quad * 4 + r;
                int p = j * 16 + l15;
                Uout[n * 64 + p] = f2bf(acc3[i][j][r]);
            }
}

// ---------------- chunk0 rank-1 inter coefficients ----------------

__global__ void cb0_kernel(const float* __restrict__ convFs, const float* __restrict__ convFp,
                           const float* __restrict__ dtFp, float* __restrict__ cb0) {
    int idx = blockIdx.x * 256 + threadIdx.x;   // 8192
    int b = idx >> 10, r = idx & 1023, h = r >> 6, tl = r & 63;
    int t = tl + 1;
    const float* crow = (t < 4) ? convFp + (size_t)(b * 4 + t) * CONVD : convFs + (size_t)(t - 4) * CONVD;
    const float* b0 = convFp + (size_t)(b * 4) * CONVD;
    float s = 0.f;
    for (int n = 0; n < 128; ++n) s += crow[1152 + n] * b0[1024 + n];
    cb0[(b * 16 + h) * 64 + tl] = s * dtFp[b * 16 + h];
}

// ---------------- M = D0*dt0*B0^T x0 + U0 ----------------

__global__ void m_kernel(const unsigned short* __restrict__ UF0, const float* __restrict__ convFp,
                         const float* __restrict__ dtFp, const float* __restrict__ cumF,
                         unsigned short* __restrict__ Mb) {
    int blk = blockIdx.x;   // 128: (b,h)
    int b = blk >> 4, h = blk & 15, tid = threadIdx.x;
    float D0 = __expf(cumF[h * 2048 + 63]);
    float dt0 = dtFp[b * 16 + h];
    const float* row0 = convFp + (size_t)(b * 4) * CONVD;
    const unsigned short* u = UF0 + (size_t)(b * 16 + h) * 8192;
    unsigned short* m = Mb + (size_t)(b * 16 + h) * 8192;
    for (int e4 = tid; e4 < 2048; e4 += 256) {
        int e = e4 * 4, n = e >> 6, p = e & 63;
        float Bn = D0 * dt0 * row0[1024 + n];
        float4 x4 = *(const float4*)&row0[h * 64 + p];
        ushort4 uv = *(const ushort4*)&u[e];
        ushort4 o = make_ushort4(f2bf(Bn * x4.x + bfu(uv.x)), f2bf(Bn * x4.y + bfu(uv.y)),
                                 f2bf(Bn * x4.z + bfu(uv.z)), f2bf(Bn * x4.w + bfu(uv.w)));
        *(ushort4*)&m[e] = o;
    }
}

// ---------------- shared chunk-state scan: T_c, psi_c (256 blocks, prefetch) ----------------

__global__ void tpsi_kernel(const unsigned short* __restrict__ UFs, const unsigned short* __restrict__ UB,
                            const float* __restrict__ cumF, const float* __restrict__ cumB,
                            unsigned short* __restrict__ Tst, float* __restrict__ psiF) {
    int blk = blockIdx.x;   // 256: dir*128 + h*8 + q8
    int dir = blk >> 7, h = (blk >> 3) & 15, q8 = blk & 7;
    int tid = threadIdx.x;
    const unsigned short* U = dir ? UB : UFs;
    const float* cum = dir ? cumB : cumF;
    unsigned short* T = Tst + (size_t)(dir * 16 + h) * 32 * 8192;
    if (dir == 0 && q8 == 0 && tid == 0) {
        float ps = 1.f;
        for (int c = 1; c < 32; ++c) {
            psiF[h * 32 + c] = ps;
            ps *= __expf(cumF[h * 2048 + c * 64 + 63]);
        }
    }
    const size_t e = (size_t)q8 * 1024 + 4 * tid;
    float4 st = make_float4(0.f, 0.f, 0.f, 0.f);
    const int c0 = dir ? 0 : 1;
    ushort4 u = *(const ushort4*)&U[((size_t)c0 * 16 + h) * 8192 + e];
    for (int c = c0; c < 32; ++c) {
        ushort4 un = make_ushort4(0, 0, 0, 0);
        if (c + 1 < 32) un = *(const ushort4*)&U[((size_t)(c + 1) * 16 + h) * 8192 + e];
        float Dc = __expf(cum[h * 2048 + c * 64 + 63]);
        ushort4 o = make_ushort4(f2bf(st.x), f2bf(st.y), f2bf(st.z), f2bf(st.w));
        *(ushort4*)&T[(size_t)c * 8192 + e] = o;
        st.x = Dc * st.x + bfu(u.x);
        st.y = Dc * st.y + bfu(u.y);
        st.z = Dc * st.z + bfu(u.z);
        st.w = Dc * st.w + bfu(u.w);
        u = un;
    }
}

// ---------------- gate kernel: MFMA Yinter + gating + partial RMS dot ----------------

__global__ __launch_bounds__(256, 2) void gate_kernel(
    const float* __restrict__ convFs, const float* __restrict__ convFp,
    const float* __restrict__ convBs,
    const float* __restrict__ zxf, const float* __restrict__ zxb,
    const float* __restrict__ cumF, const float* __restrict__ cumB,
    const unsigned short* __restrict__ YiF0, const unsigned short* __restrict__ YiFs,
    const unsigned short* __restrict__ YiB,
    const unsigned short* __restrict__ Tst, const float* __restrict__ psiF,
    const unsigned short* __restrict__ Mb, const float* __restrict__ cb0,
    const float* __restrict__ fD, const float* __restrict__ bD,
    const float* __restrict__ wf2, const float* __restrict__ wb2,
    float* __restrict__ aF, float* __restrict__ aB) {
    __shared__ __align__(16) unsigned char smraw[17408 * 3];
    unsigned short* Cs  = (unsigned short*)smraw;              // 64 x 136  [t][n]
    unsigned short* WmT = (unsigned short*)(smraw + 17408);    // 64 x 136  [p][n]
    float* Ysm = (float*)(smraw + 2 * 17408);                  // 64 x 68   [t][p]

    const int iid = blockIdx.x;
    int dir, b = 0, h, c;
    if (iid < 4096) { dir = 0; b = iid >> 9; int r = iid & 511; h = r >> 5; c = r & 31; }
    else            { int k = iid - 4096; dir = 1; h = k >> 5; c = k & 31; }
    const int tid = threadIdx.x, tx = tid & 15, ty = tid >> 4;
    const int lane = tid & 63, wave = tid >> 6;
    const bool doGemm = !(dir == 0 && c == 0);

    if (doGemm) {
        int r = tid >> 2, q = tid & 3;
        const float* row;
        if (dir == 0) row = convFs + (size_t)(64 * c + 1 + r - 4) * CONVD;   // c>=1 -> t>=65
        else          row = convBs + (size_t)(64 * c + r) * CONVD;
#pragma unroll
        for (int i = 0; i < 8; ++i) {
            int c4 = q + 4 * i;
            float4 v = *(const float4*)&row[1152 + c4 * 4];
            ushort4 p = make_ushort4(f2bf(v.x), f2bf(v.y), f2bf(v.z), f2bf(v.w));
            *(ushort4*)&Cs[r * 136 + c4 * 4] = p;
        }
        const unsigned short* Tp = Tst + ((size_t)(dir * 16 + h) * 32 + c) * 8192;
        if (dir == 0) {
            float psi = psiF[h * 32 + c];
            const unsigned short* Mp = Mb + (size_t)(b * 16 + h) * 8192;
            for (int e = tid; e < 8192; e += 256) {
                int n = e >> 6, p = e & 63;
                WmT[p * 136 + n] = f2bf(bfu(Tp[e]) + psi * bfu(Mp[e]));
            }
        } else {
            for (int e = tid; e < 8192; e += 256) {
                int n = e >> 6, p = e & 63;
                WmT[p * 136 + n] = Tp[e];
            }
        }
    }
    __syncthreads();

    if (doGemm) {
        const int wt = (wave >> 1) * 32, wp = (wave & 1) * 32;
        f32x4 acc2[2][2];
#pragma unroll
        for (int i = 0; i < 2; ++i)
#pragma unroll
            for (int j = 0; j < 2; ++j) acc2[i][j] = (f32x4){0.f, 0.f, 0.f, 0.f};
#pragma unroll
        for (int ks = 0; ks < 4; ++ks) {
            bf16x8 af[2], bfr[2];
#pragma unroll
            for (int i = 0; i < 2; ++i)
                af[i] = *(const bf16x8*)&Cs[(wt + i * 16 + (lane & 15)) * 136 + ks * 32 + (lane >> 4) * 8];
#pragma unroll
            for (int j = 0; j < 2; ++j)
                bfr[j] = *(const bf16x8*)&WmT[(wp + j * 16 + (lane & 15)) * 136 + ks * 32 + (lane >> 4) * 8];
#pragma unroll
            for (int i = 0; i < 2; ++i)
#pragma unroll
                for (int j = 0; j < 2; ++j)
                    acc2[i][j] = __builtin_amdgcn_mfma_f32_16x16x32_bf16(af[i], bfr[j], acc2[i][j], 0, 0, 0);
        }
#pragma unroll
        for (int i = 0; i < 2; ++i)
#pragma unroll
            for (int j = 0; j < 2; ++j)
#pragma unroll
                for (int r = 0; r < 4; ++r)
                    Ysm[(wt + i * 16 + (lane >> 4) * 4 + r) * 68 + wp + j * 16 + (lane & 15)] = acc2[i][j][r];
    }
    __syncthreads();

    // gating + partial reduction
    const float Dh = (dir ? bD : fD)[h];
    const float* wvp = dir ? wb2 : wf2;
    float4 wreg = *(const float4*)&wvp[h * 64 + tx * 4];
    const float* cumA = dir ? cumB : cumF;
    float4 x0v = make_float4(0.f, 0.f, 0.f, 0.f);
    float cbv[4] = {0.f, 0.f, 0.f, 0.f};
    if (dir == 0 && c == 0) {
        x0v = *(const float4*)&convFp[(size_t)(b * 4) * CONVD + h * 64 + tx * 4];
#pragma unroll
        for (int i = 0; i < 4; ++i) cbv[i] = cb0[(b * 16 + h) * 64 + (ty + 16 * i)];
    }
#pragma unroll
    for (int i = 0; i < 4; ++i) {
        int tl = ty + 16 * i;
        int j = 64 * c + tl;
        float et = __expf(cumA[h * 2048 + j]);
        const unsigned short* Yi;
        const float *xrow, *zrow;
        if (dir == 0) {
            int t = j + 1;
            Yi = (c == 0) ? YiF0 + (size_t)(b * 16 + h) * 4096 : YiFs + (size_t)(c * 16 + h) * 4096;
            xrow = (t < 4) ? convFp + (size_t)(b * 4 + t) * CONVD : convFs + (size_t)(t - 4) * CONVD;
            zrow = zxf + (size_t)j * DPROJ;
        } else {
            Yi = YiB + (size_t)(c * 16 + h) * 4096;
            xrow = convBs + (size_t)j * CONVD;
            zrow = zxb + (size_t)(2047 - j) * DPROJ;
        }
        ushort4 yi4 = *(const ushort4*)&Yi[tl * 64 + tx * 4];
        float4 xx = *(const float4*)&xrow[h * 64 + tx * 4];
        float4 zz = *(const float4*)&zrow[h * 64 + tx * 4];
        float ya[4] = {0.f, 0.f, 0.f, 0.f};
        if (doGemm) {
            float4 y4 = *(const float4*)&Ysm[tl * 68 + tx * 4];
            ya[0] = y4.x; ya[1] = y4.y; ya[2] = y4.z; ya[3] = y4.w;
        }
        float yv[4] = {bfu(yi4.x), bfu(yi4.y), bfu(yi4.z), bfu(yi4.w)};
        float xa[4] = {xx.x, xx.y, xx.z, xx.w};
        float za[4] = {zz.x, zz.y, zz.z, zz.w};
        float x0a[4] = {x0v.x, x0v.y, x0v.z, x0v.w};
        float wa[4] = {wreg.x, wreg.y, wreg.z, wreg.w};
        float a1 = 0.f, a2 = 0.f;
#pragma unroll
        for (int w = 0; w < 4; ++w) {
            float tot = yv[w] + et * (ya[w] + cbv[i] * x0a[w]) + Dh * xa[w];
            float g = tot * siluf(za[w]);
            a1 += g * wa[w];
            a2 += g * g;
        }
#pragma unroll
        for (int m = 1; m < 16; m <<= 1) {
            a1 += __shfl_xor(a1, m);
            a2 += __shfl_xor(a2, m);
        }
        if (tx == 0) {
            if (dir == 0) {
                size_t o = ((size_t)(b * 2048 + j) * 16 + h) * 2;
                aF[o] = a1; aF[o + 1] = a2;
            } else {
                int g = 2047 - j;
                size_t o = ((size_t)g * 16 + h) * 2;
                aB[o] = a1; aB[o + 1] = a2;
            }
        }
    }
}

// ---------------- final combine ----------------

__global__ void final_kernel(const float* __restrict__ aF, const float* __restrict__ aB,
                             const float* __restrict__ headB, float* __restrict__ out) {
    int idx = blockIdx.x * 256 + threadIdx.x;   // 16384
    int b = idx >> 11, g = idx & 2047;
    const float* pf = aF + ((size_t)(b * 2048 + g)) * 32;
    const float* pb = aB + (size_t)g * 32;
    float f1 = 0.f, f2 = 0.f, b1 = 0.f, b2 = 0.f;
#pragma unroll
    for (int h = 0; h < 16; ++h) {
        f1 += pf[2 * h]; f2 += pf[2 * h + 1];
        b1 += pb[2 * h]; b2 += pb[2 * h + 1];
    }
    out[idx] = f1 * rsqrtf(f2 * (1.f / 1024.f) + 1e-5f) +
               b1 * rsqrtf(b2 * (1.f / 1024.f) + 1e-5f) + headB[0];
}

// ---------------- launch ----------------

extern "C" void kernel_launch(void* const* d_in, const int* in_sizes, int n_in,
                              void* d_out, int out_size, void* d_ws, size_t ws_size,
                              hipStream_t stream) {
    const int*   pidx   = (const int*)  d_in[0];
    const int*   chridx = (const int*)  d_in[1];
    const float* locusF = (const float*)d_in[2];
    const float* pathF  = (const float*)d_in[3];
    const float* pertE  = (const float*)d_in[4];
    const float* gidE   = (const float*)d_in[5];
    const float* chrE   = (const float*)d_in[6];
    const float* locusW = (const float*)d_in[7];
    const float* locusB = (const float*)d_in[8];
    const float* condW  = (const float*)d_in[9];
    const float* condB  = (const float*)d_in[10];
    const float* inW    = (const float*)d_in[11];
    const float* inB    = (const float*)d_in[12];
    const float* headW  = (const float*)d_in[13];
    const float* headB  = (const float*)d_in[14];
    const float* fInW   = (const float*)d_in[15];
    const float* fCw    = (const float*)d_in[16];
    const float* fCb    = (const float*)d_in[17];
    const float* fDtB   = (const float*)d_in[18];
    const float* fAlog  = (const float*)d_in[19];
    const float* fDp    = (const float*)d_in[20];
    const float* fNw    = (const float*)d_in[21];
    const float* fOutW  = (const float*)d_in[22];
    const float* bInW   = (const float*)d_in[23];
    const float* bCw    = (const float*)d_in[24];
    const float* bCb    = (const float*)d_in[25];
    const float* bDtB   = (const float*)d_in[26];
    const float* bAlog  = (const float*)d_in[27];
    const float* bDp    = (const float*)d_in[28];
    const float* bNw    = (const float*)d_in[29];
    const float* bOutW  = (const float*)d_in[30];
    float* out = (float*)d_out;
    (void)in_sizes; (void)n_in; (void)out_size; (void)ws_size;

    char* base = (char*)d_ws;
    size_t off = 0;
    auto allocf = [&](size_t n) -> float* {
        char* r = base + off; off += ((n * 4 + 63) & ~(size_t)63); return (float*)r; };
    auto allocu = [&](size_t n) -> unsigned short* {
        char* r = base + off; off += ((n * 2 + 63) & ~(size_t)63); return (unsigned short*)r; };

    float* gf     = allocf(2048UL * 384);
    float* cond   = allocf(8UL * 384);
    float* cemb   = allocf(8UL * 128);
    float* ug     = allocf(2048UL * 512);
    float* uc     = allocf(8UL * 512);
    float* zxf    = allocf(2048UL * DPROJ);
    float* zxb    = allocf(2048UL * DPROJ);
    float* zxc    = allocf(8UL * DPROJ);
    float* convFs = allocf(2045UL * CONVD);
    float* convFp = allocf(8UL * 4 * CONVD);
    float* convBs = allocf(2048UL * CONVD);
    float* dtFs   = allocf(2048UL * 16);
    float* dtFp   = allocf(128);
    float* dtBs   = allocf(2048UL * 16);
    float* cumF   = allocf(16UL * 2048);
    float* cumB   = allocf(16UL * 2048);
    float* wf2    = allocf(1024);
    float* wb2    = allocf(1024);
    float* cb0    = allocf(8UL * 16 * 64);
    float* psiF   = allocf(16UL * 32);
    float* aF     = allocf(8UL * 2048 * 16 * 2);
    float* aB     = allocf(2048UL * 16 * 2);
    unsigned short* YiF0 = allocu(8UL * 16 * 4096);
    unsigned short* YiFs = allocu(32UL * 16 * 4096);
    unsigned short* YiB  = allocu(32UL * 16 * 4096);
    unsigned short* UF0  = allocu(8UL * 16 * 8192);
    unsigned short* UFs  = allocu(32UL * 16 * 8192);
    unsigned short* UB   = allocu(32UL * 16 * 8192);
    unsigned short* Mb   = allocu(8UL * 16 * 8192);
    unsigned short* Tst  = allocu(2UL * 16 * 32 * 8192);
    unsigned short* gf2   = allocu(2048UL * 768);
    unsigned short* inW2  = allocu(512UL * 768);
    unsigned short* ug2   = allocu(2048UL * 1024);
    unsigned short* fInW2 = allocu(2432UL * 1024);
    unsigned short* bInW2 = allocu(2432UL * 1024);

    gather_kernel<<<4, 256, 0, stream>>>(pidx, pertE, cemb);
    wfold_kernel<<<32, 256, 0, stream>>>(headW, fOutW, fNw, bOutW, bNw, wf2, wb2);
    genefeat_kernel<<<3072, 256, 0, stream>>>(chridx, gidE, pathF, chrE, gf);
    gemm_kernel<<<dim3(1, 32), 256, 0, stream>>>(locusF, locusW, locusB, gf + 320, 2048, 64, 64, 384, 1);
    gemm_kernel<<<dim3(6, 1), 256, 0, stream>>>(cemb, condW, condB, cond, 8, 384, 128, 384, 0);

    // weight conversions (independent of data path)
    tobf_kernel<<<(512 * 384 + 255) / 256, 256, 0, stream>>>(inW, inW2, 512, 384, 512);
    tobf_kernel<<<(2432 * 512 + 255) / 256, 256, 0, stream>>>(fInW, fInW2, 2320, 512, 2432);
    tobf_kernel<<<(2432 * 512 + 255) / 256, 256, 0, stream>>>(bInW, bInW2, 2320, 512, 2432);

    // ug = gf @ inW^T  (MFMA, hi/lo split)
    tobf_kernel<<<(2048 * 384 + 255) / 256, 256, 0, stream>>>(gf, gf2, 2048, 384, 2048);
    mfma_gemm_kernel<<<dim3(4, 16), 256, 0, stream>>>(gf2, inW2, inB, ug, 512, 768, 512);
    gemm_kernel<<<dim3(8, 1), 256, 0, stream>>>(cond, inW, inB, uc, 8, 512, 384, 512, 0);

    // zxf/zxb = ug @ {f,b}InW^T  (MFMA, hi/lo split)
    tobf_kernel<<<(2048 * 512 + 255) / 256, 256, 0, stream>>>(ug, ug2, 2048, 512, 2048);
    mfma_gemm_kernel<<<dim3(19, 16), 256, 0, stream>>>(ug2, fInW2, nullptr, zxf, 2320, 1024, 2320);
    mfma_gemm_kernel<<<dim3(19, 16), 256, 0, stream>>>(ug2, bInW2, nullptr, zxb, 2320, 1024, 2320);
    gemm_kernel<<<dim3(37, 1), 256, 0, stream>>>(uc, fInW, nullptr, zxc, 8, DPROJ, 512, DPROJ, 0);

    dt_kernel<<<128, 256, 0, stream>>>(zxf, fDtB, dtFs, 0);
    dt_kernel<<<128, 256, 0, stream>>>(zxb, bDtB, dtBs, 1);
    dtpb_kernel<<<1, 128, 0, stream>>>(zxc, fDtB, dtFp);
    cum_kernel<<<4, 256, 0, stream>>>(dtFs, dtBs, fAlog, bAlog, cumF, cumB);
    convFsh_kernel<<<(2045 * 1280 + 255) / 256, 256, 0, stream>>>(zxf, fCw, fCb, convFs);
    convFpb_kernel<<<160, 256, 0, stream>>>(zxf, zxc, fCw, fCb, convFp);
    convBsh_kernel<<<10240, 256, 0, stream>>>(zxb, bCw, bCb, convBs);
    intra_kernel<<<1136, 256, 0, stream>>>(convFs, convFp, convBs, dtFs, dtBs, cumF, cumB,
                                           YiF0, YiFs, YiB, UF0, UFs, UB);
    cb0_kernel<<<32, 256, 0, stream>>>(convFs, convFp, dtFp, cb0);
    m_kernel<<<128, 256, 0, stream>>>(UF0, convFp, dtFp, cumF, Mb);
    tpsi_kernel<<<256, 256, 0, stream>>>(UFs, UB, cumF, cumB, Tst, psiF);
    gate_kernel<<<4608, 256, 0, stream>>>(convFs, convFp, convBs, zxf, zxb, cumF, cumB,
                                          YiF0, YiFs, YiB, Tst, psiF, Mb, cb0,
                                          fDp, bDp, wf2, wb2, aF, aB);
    final_kernel<<<64, 256, 0, stream>>>(aF, aB, headB, out);
}

// Round 5
// 461.067 us; speedup vs baseline: 6.2596x; 1.0659x over previous
//
#include <hip/hip_runtime.h>
#include <hip/hip_bf16.h>
#include <math.h>

#define DPROJ 2320
#define CONVD 1280

typedef __attribute__((ext_vector_type(8))) short bf16x8;
typedef __attribute__((ext_vector_type(4))) float f32x4;

__device__ __forceinline__ float siluf(float x) { return x / (1.f + __expf(-x)); }
__device__ __forceinline__ float bfu(unsigned short s) { return __uint_as_float(((unsigned)s) << 16); }
__device__ __forceinline__ unsigned short f2bf(float f) {
    unsigned u = __float_as_uint(f);
    unsigned r = (u + 0x7FFFu + ((u >> 16) & 1u)) >> 16;
    return (unsigned short)r;
}

// ---------------- small prep kernels ----------------

__global__ void gather_kernel(const int* __restrict__ pidx, const float* __restrict__ pertE,
                              float* __restrict__ cemb) {
    int idx = blockIdx.x * 256 + threadIdx.x;   // 1024
    int b = idx >> 7, k = idx & 127;
    cemb[idx] = pertE[(size_t)pidx[b] * 128 + k];
}

__global__ void wfold_kernel(const float* __restrict__ headW,
                             const float* __restrict__ fOutW, const float* __restrict__ fNw,
                             const float* __restrict__ bOutW, const float* __restrict__ bNw,
                             float* __restrict__ wf2, float* __restrict__ wb2) {
    __shared__ float red[256];
    int blk = blockIdx.x;   // 32: dir*16 + dchunk
    int dir = blk >> 4, dc = blk & 15;
    int tid = threadIdx.x;
    int d = dc * 64 + (tid & 63), seg = tid >> 6;
    const float* W = dir ? bOutW : fOutW;
    float s = 0.f;
    for (int m = seg * 128; m < seg * 128 + 128; ++m) s += headW[m] * W[(size_t)m * 1024 + d];
    red[tid] = s;
    __syncthreads();
    if (tid < 64) {
        float tot = red[tid] + red[tid + 64] + red[tid + 128] + red[tid + 192];
        const float* nw = dir ? bNw : fNw;
        (dir ? wb2 : wf2)[d] = tot * nw[d];
    }
}

__global__ void genefeat_kernel(const int* __restrict__ chridx, const float* __restrict__ gid,
                                const float* __restrict__ path, const float* __restrict__ chrE,
                                float* __restrict__ gf) {
    int idx = blockIdx.x * 256 + threadIdx.x;   // 2048*384
    int g = idx / 384, j = idx % 384;
    float v;
    if (j < 128)      v = gid[(size_t)g * 128 + j];
    else if (j < 256) v = path[(size_t)g * 128 + (j - 128)];
    else if (j < 320) v = chrE[(size_t)chridx[g] * 64 + (j - 256)];
    else return;      // cols 320..383 written by the locus GEMM
    gf[idx] = v;
}

// ---------------- bf16 cast: out[m][k] = bf16(in[m][k]) ----------------

__global__ void tobf_kernel(const float* __restrict__ in, unsigned short* __restrict__ out,
                            int M, int K, int Mpad) {
    int idx = blockIdx.x * 256 + threadIdx.x;
    if (idx >= Mpad * K) return;
    int m = idx / K, k = idx % K;
    float v = (m < M) ? in[(size_t)m * K + k] : 0.f;
    out[idx] = f2bf(v);
}

// ---------------- MFMA GEMM: C[M x N] = A2[M x K2] . W2[Npad x K2]^T (+bias) ----------------

__global__ __launch_bounds__(256) void mfma_gemm_kernel(
    const unsigned short* __restrict__ A2, const unsigned short* __restrict__ W2,
    const float* __restrict__ bias, float* __restrict__ C,
    int N, int K2, int ldc) {
    __shared__ __align__(16) unsigned short Al[128 * 40];
    __shared__ __align__(16) unsigned short Bl[128 * 40];
    const int tid = threadIdx.x;
    const int bm = blockIdx.y * 128, bn = blockIdx.x * 128;
    const int lane = tid & 63, wave = tid >> 6;
    const int wm = (wave >> 1) * 64, wn = (wave & 1) * 64;
    f32x4 acc[4][4];
#pragma unroll
    for (int i = 0; i < 4; ++i)
#pragma unroll
        for (int j = 0; j < 4; ++j) acc[i][j] = (f32x4){0.f, 0.f, 0.f, 0.f};

    for (int k0 = 0; k0 < K2; k0 += 32) {
        __syncthreads();
#pragma unroll
        for (int s = 0; s < 2; ++s) {
            int ch = tid + 256 * s;
            int row = ch >> 2, q = ch & 3;
            uint4 va = *(const uint4*)&A2[(size_t)(bm + row) * K2 + k0 + q * 8];
            *(uint4*)&Al[row * 40 + q * 8] = va;
            uint4 vb = *(const uint4*)&W2[(size_t)(bn + row) * K2 + k0 + q * 8];
            *(uint4*)&Bl[row * 40 + q * 8] = vb;
        }
        __syncthreads();
        bf16x8 af[4], bfr[4];
#pragma unroll
        for (int i = 0; i < 4; ++i)
            af[i] = *(const bf16x8*)&Al[(wm + i * 16 + (lane & 15)) * 40 + (lane >> 4) * 8];
#pragma unroll
        for (int j = 0; j < 4; ++j)
            bfr[j] = *(const bf16x8*)&Bl[(wn + j * 16 + (lane & 15)) * 40 + (lane >> 4) * 8];
#pragma unroll
        for (int i = 0; i < 4; ++i)
#pragma unroll
            for (int j = 0; j < 4; ++j)
                acc[i][j] = __builtin_amdgcn_mfma_f32_16x16x32_bf16(af[i], bfr[j], acc[i][j], 0, 0, 0);
    }
#pragma unroll
    for (int i = 0; i < 4; ++i) {
        int m = bm + wm + i * 16 + (lane >> 4) * 4;
#pragma unroll
        for (int j = 0; j < 4; ++j) {
            int n = bn + wn + j * 16 + (lane & 15);
            if (n < N) {
                float bv = bias ? bias[n] : 0.f;
#pragma unroll
                for (int r = 0; r < 4; ++r)
                    C[(size_t)(m + r) * ldc + n] = acc[i][j][r] + bv;
            }
        }
    }
}

// ---------------- generic tiled fp32 GEMM (small shapes only) ----------------

__global__ __launch_bounds__(256) void gemm_kernel(
    const float* __restrict__ A, const float* __restrict__ W,
    const float* __restrict__ bias, float* __restrict__ C,
    int M, int N, int K, int ldc, int act) {
    __shared__ __align__(16) float As[16][68];
    __shared__ __align__(16) float Ws[16][68];
    const int tid = threadIdx.x;
    const int tx = tid & 15, ty = tid >> 4;
    const int bm = blockIdx.y * 64, bn = blockIdx.x * 64;
    const int lr = tid >> 2;
    const int lk = (tid & 3) * 4;
    float acc[4][4];
#pragma unroll
    for (int i = 0; i < 4; ++i)
#pragma unroll
        for (int j = 0; j < 4; ++j) acc[i][j] = 0.f;

    for (int k0 = 0; k0 < K; k0 += 16) {
        const int am = bm + lr;
        const int wn = bn + lr;
        float4 av = make_float4(0.f, 0.f, 0.f, 0.f), wv = make_float4(0.f, 0.f, 0.f, 0.f);
        if (am < M) av = *(const float4*)&A[(size_t)am * K + k0 + lk];
        if (wn < N) wv = *(const float4*)&W[(size_t)wn * K + k0 + lk];
        __syncthreads();
        As[lk + 0][lr] = av.x; As[lk + 1][lr] = av.y; As[lk + 2][lr] = av.z; As[lk + 3][lr] = av.w;
        Ws[lk + 0][lr] = wv.x; Ws[lk + 1][lr] = wv.y; Ws[lk + 2][lr] = wv.z; Ws[lk + 3][lr] = wv.w;
        __syncthreads();
#pragma unroll
        for (int kk = 0; kk < 16; ++kk) {
            float4 a = *(const float4*)&As[kk][ty * 4];
            float4 w = *(const float4*)&Ws[kk][tx * 4];
            float aa[4] = {a.x, a.y, a.z, a.w}, ww[4] = {w.x, w.y, w.z, w.w};
#pragma unroll
            for (int i = 0; i < 4; ++i)
#pragma unroll
                for (int j = 0; j < 4; ++j) acc[i][j] += aa[i] * ww[j];
        }
    }
#pragma unroll
    for (int i = 0; i < 4; ++i) {
        const int m = bm + ty * 4 + i;
        if (m >= M) continue;
#pragma unroll
        for (int j = 0; j < 4; ++j) {
            const int n = bn + tx * 4 + j;
            if (n >= N) continue;
            float v = acc[i][j] + (bias ? bias[n] : 0.f);
            if (act == 1) v = 0.5f * v * (1.f + erff(v * 0.70710678118654752f));
            C[(size_t)m * ldc + n] = v;
        }
    }
}

// ---------------- dt precompute ----------------

__global__ void dt_kernel(const float* __restrict__ zx, const float* __restrict__ dt_bias,
                          float* __restrict__ dt_o, int flip) {
    int idx = blockIdx.x * 256 + threadIdx.x;   // 32768
    int r = idx >> 4, h = idx & 15;
    int row = flip ? (2047 - r) : r;
    float raw = zx[(size_t)row * DPROJ + 2304 + h] + dt_bias[h];
    float dt = (raw > 20.f) ? raw : log1pf(expf(raw));
    dt_o[idx] = dt;
}

__global__ void dtpb_kernel(const float* __restrict__ zxc, const float* __restrict__ dt_bias,
                            float* __restrict__ dt_o) {
    int idx = threadIdx.x;   // 128
    int b = idx >> 4, h = idx & 15;
    float raw = zxc[(size_t)b * DPROJ + 2304 + h] + dt_bias[h];
    float dt = (raw > 20.f) ? raw : log1pf(expf(raw));
    dt_o[idx] = dt;
}

// chunk-local inclusive cumsum of ldA = -dt*exp(A_log)
__global__ void cum_kernel(const float* __restrict__ dtFs, const float* __restrict__ dtBs,
                           const float* __restrict__ fAlog, const float* __restrict__ bAlog,
                           float* __restrict__ cumF, float* __restrict__ cumB) {
    int id = blockIdx.x * 256 + threadIdx.x;   // 1024
    int dir = id >> 9, k = id & 511, h = k >> 5, c = k & 31;
    const float* dt = dir ? dtBs : dtFs;
    const float* Al = dir ? bAlog : fAlog;
    float* cum = dir ? cumB : cumF;
    float a = expf(Al[h]);
    float acc = 0.f;
    for (int s = 0; s < 64; ++s) {
        int j = c * 64 + s;
        acc += -dt[j * 16 + h] * a;
        cum[h * 2048 + j] = acc;
    }
}

// ---------------- causal depthwise conv (+SiLU), with bf16 B/C side-copies ----------------

__global__ void convFsh_kernel(const float* __restrict__ zxf, const float* __restrict__ cw,
                               const float* __restrict__ cb, float* __restrict__ outp,
                               unsigned short* __restrict__ bc16) {
    int idx = blockIdx.x * 256 + threadIdx.x;
    if (idx >= 2045 * 1280) return;
    int t4 = idx / 1280, c = idx % 1280;
    float4 w4 = *(const float4*)&cw[c * 4];
    float acc = cb[c];
    acc += zxf[(size_t)(t4 + 0) * DPROJ + 1024 + c] * w4.x;
    acc += zxf[(size_t)(t4 + 1) * DPROJ + 1024 + c] * w4.y;
    acc += zxf[(size_t)(t4 + 2) * DPROJ + 1024 + c] * w4.z;
    acc += zxf[(size_t)(t4 + 3) * DPROJ + 1024 + c] * w4.w;
    float r = siluf(acc);
    outp[idx] = r;
    if (c >= 1024) bc16[(size_t)t4 * 256 + (c - 1024)] = f2bf(r);
}

__global__ void convFpb_kernel(const float* __restrict__ zxf, const float* __restrict__ zxc,
                               const float* __restrict__ cw, const float* __restrict__ cb,
                               float* __restrict__ outp, unsigned short* __restrict__ bc16) {
    int idx = blockIdx.x * 256 + threadIdx.x;   // 8*4*1280
    int b = idx / 5120;
    int r = idx % 5120;
    int t = r / 1280, c = r % 1280;
    float4 w4 = *(const float4*)&cw[c * 4];
    float w[4] = {w4.x, w4.y, w4.z, w4.w};
    float acc = cb[c];
#pragma unroll
    for (int k = 0; k < 4; ++k) {
        int j = t - 3 + k;
        float x = 0.f;
        if (j == 0)      x = zxc[(size_t)b * DPROJ + 1024 + c];
        else if (j >= 1) x = zxf[(size_t)(j - 1) * DPROJ + 1024 + c];
        acc += x * w[k];
    }
    float rr = siluf(acc);
    outp[idx] = rr;
    if (c >= 1024) bc16[(size_t)(b * 4 + t) * 256 + (c - 1024)] = f2bf(rr);
}

__global__ void convBsh_kernel(const float* __restrict__ zxb, const float* __restrict__ cw,
                               const float* __restrict__ cb, float* __restrict__ outp,
                               unsigned short* __restrict__ bc16) {
    int idx = blockIdx.x * 256 + threadIdx.x;   // 2048*1280
    int s = idx / 1280, c = idx % 1280;
    float4 w4 = *(const float4*)&cw[c * 4];
    float w[4] = {w4.x, w4.y, w4.z, w4.w};
    float acc = cb[c];
#pragma unroll
    for (int k = 0; k < 4; ++k) {
        int j = s - 3 + k;
        if (j >= 0) acc += zxb[(size_t)(2047 - j) * DPROJ + 1024 + c] * w[k];
    }
    float r = siluf(acc);
    outp[idx] = r;
    if (c >= 1024) bc16[(size_t)s * 256 + (c - 1024)] = f2bf(r);
}

// ---------------- intra-chunk kernel (MFMA) ----------------
// Phase 1: G = C.B^T -> mask/decay -> S (bf16, LDS)
// Phase 2 (swapped): Y^T-regs = X^T x S -> vectorized Yi[t][p] writes
// Phase 3: U = B^T.(e*X) -> vectorized U[p][n] writes

__global__ __launch_bounds__(256) void intra_kernel(
    const unsigned short* __restrict__ bcF, const unsigned short* __restrict__ bcFp,
    const unsigned short* __restrict__ bcB,
    const float* __restrict__ convFs, const float* __restrict__ convFp,
    const float* __restrict__ convBs,
    const float* __restrict__ dtFs, const float* __restrict__ dtBs,
    const float* __restrict__ cumF, const float* __restrict__ cumB,
    unsigned short* __restrict__ YiF0, unsigned short* __restrict__ YiFs,
    unsigned short* __restrict__ YiB,
    unsigned short* __restrict__ UF0, unsigned short* __restrict__ UFs,
    unsigned short* __restrict__ UB) {
    __shared__ __align__(16) unsigned char smraw[63232];
    unsigned short* Bt = (unsigned short*)smraw;                    // 64 x 136  [s][n]
    unsigned short* Ct = (unsigned short*)(smraw + 17408);          // 64 x 136  [t][n]
    unsigned short* Sm = (unsigned short*)(smraw + 17408);          // 64 x 72   [t][s] (alias Ct)
    unsigned short* BT = (unsigned short*)(smraw + 34816);          // 128 x 72  [n][s]
    unsigned short* XT = (unsigned short*)(smraw + 53248);          // 64 x 72   [p][s]
    float* scum = (float*)(smraw + 62464);                          // 64
    float* sdt  = scum + 64;                                        // 64
    float* se   = scum + 128;                                       // 64

    const int iid = blockIdx.x;
    int dir, b = 0, h, c;
    unsigned short *Yout, *Uout;
    if (iid < 128)      { dir = 0; b = iid >> 4; h = iid & 15; c = 0;
                          Yout = YiF0 + (size_t)(b * 16 + h) * 4096; Uout = UF0 + (size_t)(b * 16 + h) * 8192; }
    else if (iid < 624) { int k = iid - 128; dir = 0; c = 1 + (k >> 4); h = k & 15;
                          Yout = YiFs + (size_t)(c * 16 + h) * 4096; Uout = UFs + (size_t)(c * 16 + h) * 8192; }
    else                { int k = iid - 624; dir = 1; c = k >> 4; h = k & 15;
                          Yout = YiB + (size_t)(c * 16 + h) * 4096;  Uout = UB + (size_t)(c * 16 + h) * 8192; }
    const float* dtA = dir ? dtBs : dtFs;
    const float* cumA = dir ? cumB : cumF;

    const int tid = threadIdx.x;
    const int lane = tid & 63, wave = tid >> 6;
    const int quad = lane >> 4, l15 = lane & 15;

    {   // stage B [s][n] + B^T [n][s], C [t][n] (bf16 source), X^T [p][s], cum, dt
        int r = tid >> 2, q = tid & 3;
        const unsigned short* bsrc;
        const float* xrow;
        if (dir == 0) {
            int t = 64 * c + 1 + r;
            if (t < 4) { bsrc = bcFp + (size_t)(b * 4 + t) * 256; xrow = convFp + (size_t)(b * 4 + t) * CONVD; }
            else       { bsrc = bcF + (size_t)(t - 4) * 256;      xrow = convFs + (size_t)(t - 4) * CONVD; }
        } else {
            int s = 64 * c + r;
            bsrc = bcB + (size_t)s * 256;
            xrow = convBs + (size_t)s * CONVD;
        }
#pragma unroll
        for (int i = 0; i < 4; ++i) {
            int n0 = q * 32 + i * 8;
            uint4 v = *(const uint4*)&bsrc[n0];
            *(uint4*)&Bt[r * 136 + n0] = v;
            const unsigned short* pv = (const unsigned short*)&v;
#pragma unroll
            for (int jj = 0; jj < 8; ++jj) BT[(n0 + jj) * 72 + r] = pv[jj];
        }
#pragma unroll
        for (int i = 0; i < 4; ++i) {
            int n0 = q * 32 + i * 8;
            uint4 v = *(const uint4*)&bsrc[128 + n0];
            *(uint4*)&Ct[r * 136 + n0] = v;
        }
#pragma unroll
        for (int i = 0; i < 4; ++i) {
            int p0 = (q + 4 * i) * 4;
            float4 v = *(const float4*)&xrow[h * 64 + p0];
            XT[(p0 + 0) * 72 + r] = f2bf(v.x);
            XT[(p0 + 1) * 72 + r] = f2bf(v.y);
            XT[(p0 + 2) * 72 + r] = f2bf(v.z);
            XT[(p0 + 3) * 72 + r] = f2bf(v.w);
        }
        if (tid < 64) {
            int j = 64 * c + tid;
            scum[tid] = cumA[h * 2048 + j];
            sdt[tid] = dtA[j * 16 + h];
        }
    }
    __syncthreads();
    if (tid < 64) se[tid] = __expf(scum[63] - scum[tid]) * sdt[tid];

    // phase 1: G = C . B^T
    const int tm = (wave >> 1) * 32, sn = (wave & 1) * 32;
    f32x4 acc1[2][2];
#pragma unroll
    for (int i = 0; i < 2; ++i)
#pragma unroll
        for (int j = 0; j < 2; ++j) acc1[i][j] = (f32x4){0.f, 0.f, 0.f, 0.f};
#pragma unroll
    for (int ks = 0; ks < 4; ++ks) {
        bf16x8 af[2], bfr[2];
#pragma unroll
        for (int i = 0; i < 2; ++i)
            af[i] = *(const bf16x8*)&Ct[(tm + i * 16 + l15) * 136 + ks * 32 + quad * 8];
#pragma unroll
        for (int j = 0; j < 2; ++j)
            bfr[j] = *(const bf16x8*)&Bt[(sn + j * 16 + l15) * 136 + ks * 32 + quad * 8];
#pragma unroll
        for (int i = 0; i < 2; ++i)
#pragma unroll
            for (int j = 0; j < 2; ++j)
                acc1[i][j] = __builtin_amdgcn_mfma_f32_16x16x32_bf16(af[i], bfr[j], acc1[i][j], 0, 0, 0);
    }
    __syncthreads();   // all Ct reads done; Sm aliases Ct

    // mask + decay + dt scale -> S (bf16)
#pragma unroll
    for (int j = 0; j < 2; ++j) {
        int s = sn + j * 16 + l15;
        float cs = scum[s], ds = sdt[s];
#pragma unroll
        for (int i = 0; i < 2; ++i) {
#pragma unroll
            for (int r = 0; r < 4; ++r) {
                int t = tm + i * 16 + quad * 4 + r;
                float v = (s <= t) ? __expf(scum[t] - cs) * ds * acc1[i][j][r] : 0.f;
                Sm[t * 72 + s] = f2bf(v);
            }
        }
    }
    __syncthreads();

    // phase 2 (swapped): A = X^T rows p, B = Sm rows t -> D[p][t]
    const int pm = (wave >> 1) * 32, tn = (wave & 1) * 32;
    f32x4 acc2[2][2];
#pragma unroll
    for (int i = 0; i < 2; ++i)
#pragma unroll
        for (int j = 0; j < 2; ++j) acc2[i][j] = (f32x4){0.f, 0.f, 0.f, 0.f};
#pragma unroll
    for (int ks = 0; ks < 2; ++ks) {
        bf16x8 af[2], bfr[2];
#pragma unroll
        for (int i = 0; i < 2; ++i)
            af[i] = *(const bf16x8*)&XT[(pm + i * 16 + l15) * 72 + ks * 32 + quad * 8];
#pragma unroll
        for (int j = 0; j < 2; ++j)
            bfr[j] = *(const bf16x8*)&Sm[(tn + j * 16 + l15) * 72 + ks * 32 + quad * 8];
#pragma unroll
        for (int i = 0; i < 2; ++i)
#pragma unroll
            for (int j = 0; j < 2; ++j)
                acc2[i][j] = __builtin_amdgcn_mfma_f32_16x16x32_bf16(af[i], bfr[j], acc2[i][j], 0, 0, 0);
    }
#pragma unroll
    for (int i = 0; i < 2; ++i)
#pragma unroll
        for (int j = 0; j < 2; ++j) {
            int t = tn + j * 16 + l15;
            int p0 = pm + i * 16 + quad * 4;
            ushort4 o = make_ushort4(f2bf(acc2[i][j][0]), f2bf(acc2[i][j][1]),
                                     f2bf(acc2[i][j][2]), f2bf(acc2[i][j][3]));
            *(ushort4*)&Yout[t * 64 + p0] = o;
        }

    // phase 3: U = B^T . (e*X): D[n][p] -> write U[p][n] vectorized over n
    const int nm = wave * 32;
    f32x4 acc3[2][4];
#pragma unroll
    for (int i = 0; i < 2; ++i)
#pragma unroll
        for (int j = 0; j < 4; ++j) acc3[i][j] = (f32x4){0.f, 0.f, 0.f, 0.f};
#pragma unroll
    for (int ks = 0; ks < 2; ++ks) {
        float ev[8];
#pragma unroll
        for (int jj = 0; jj < 8; ++jj) ev[jj] = se[ks * 32 + quad * 8 + jj];
        bf16x8 bfx[4];
#pragma unroll
        for (int j = 0; j < 4; ++j) {
            bf16x8 xs = *(const bf16x8*)&XT[(j * 16 + l15) * 72 + ks * 32 + quad * 8];
#pragma unroll
            for (int jj = 0; jj < 8; ++jj)
                bfx[j][jj] = (short)f2bf(bfu((unsigned short)xs[jj]) * ev[jj]);
        }
        bf16x8 af[2];
#pragma unroll
        for (int i = 0; i < 2; ++i)
            af[i] = *(const bf16x8*)&BT[(nm + i * 16 + l15) * 72 + ks * 32 + quad * 8];
#pragma unroll
        for (int i = 0; i < 2; ++i)
#pragma unroll
            for (int j = 0; j < 4; ++j)
                acc3[i][j] = __builtin_amdgcn_mfma_f32_16x16x32_bf16(af[i], bfx[j], acc3[i][j], 0, 0, 0);
    }
#pragma unroll
    for (int i = 0; i < 2; ++i)
#pragma unroll
        for (int j = 0; j < 4; ++j) {
            int p = j * 16 + l15;
            int n0 = nm + i * 16 + quad * 4;
            ushort4 o = make_ushort4(f2bf(acc3[i][j][0]), f2bf(acc3[i][j][1]),
                                     f2bf(acc3[i][j][2]), f2bf(acc3[i][j][3]));
            *(ushort4*)&Uout[p * 128 + n0] = o;
        }
}

// ---------------- chunk0 rank-1 inter coefficients ----------------

__global__ void cb0_kernel(const float* __restrict__ convFs, const float* __restrict__ convFp,
                           const float* __restrict__ dtFp, float* __restrict__ cb0) {
    int idx = blockIdx.x * 256 + threadIdx.x;   // 8192
    int b = idx >> 10, r = idx & 1023, h = r >> 6, tl = r & 63;
    int t = tl + 1;
    const float* crow = (t < 4) ? convFp + (size_t)(b * 4 + t) * CONVD : convFs + (size_t)(t - 4) * CONVD;
    const float* b0 = convFp + (size_t)(b * 4) * CONVD;
    float s = 0.f;
    for (int n = 0; n < 128; ++n) s += crow[1152 + n] * b0[1024 + n];
    cb0[(b * 16 + h) * 64 + tl] = s * dtFp[b * 16 + h];
}

// ---------------- M[p][n] = D0*dt0*x0[p]*B0[n] + U0[p][n] ----------------

__global__ void m_kernel(const unsigned short* __restrict__ UF0, const float* __restrict__ convFp,
                         const float* __restrict__ dtFp, const float* __restrict__ cumF,
                         unsigned short* __restrict__ Mb) {
    int blk = blockIdx.x;   // 128: (b,h)
    int b = blk >> 4, h = blk & 15, tid = threadIdx.x;
    float D0 = __expf(cumF[h * 2048 + 63]);
    float dt0 = dtFp[b * 16 + h];
    const float* row0 = convFp + (size_t)(b * 4) * CONVD;
    const unsigned short* u = UF0 + (size_t)(b * 16 + h) * 8192;
    unsigned short* m = Mb + (size_t)(b * 16 + h) * 8192;
    for (int e4 = tid; e4 < 2048; e4 += 256) {
        int e = e4 * 4, p = e >> 7, n0 = e & 127;
        float s = D0 * dt0 * row0[h * 64 + p];
        float4 B4 = *(const float4*)&row0[1024 + n0];
        ushort4 uv = *(const ushort4*)&u[e];
        ushort4 o = make_ushort4(f2bf(s * B4.x + bfu(uv.x)), f2bf(s * B4.y + bfu(uv.y)),
                                 f2bf(s * B4.z + bfu(uv.z)), f2bf(s * B4.w + bfu(uv.w)));
        *(ushort4*)&m[e] = o;
    }
}

// ---------------- shared chunk-state scan: T_c, psi_c (flat over [p][n]) ----------------

__global__ void tpsi_kernel(const unsigned short* __restrict__ UFs, const unsigned short* __restrict__ UB,
                            const float* __restrict__ cumF, const float* __restrict__ cumB,
                            unsigned short* __restrict__ Tst, float* __restrict__ psiF) {
    int blk = blockIdx.x;   // 256: dir*128 + h*8 + q8
    int dir = blk >> 7, h = (blk >> 3) & 15, q8 = blk & 7;
    int tid = threadIdx.x;
    const unsigned short* U = dir ? UB : UFs;
    const float* cum = dir ? cumB : cumF;
    unsigned short* T = Tst + (size_t)(dir * 16 + h) * 32 * 8192;
    if (dir == 0 && q8 == 0 && tid == 0) {
        float ps = 1.f;
        for (int c = 1; c < 32; ++c) {
            psiF[h * 32 + c] = ps;
            ps *= __expf(cumF[h * 2048 + c * 64 + 63]);
        }
    }
    const size_t e = (size_t)q8 * 1024 + 4 * tid;
    float4 st = make_float4(0.f, 0.f, 0.f, 0.f);
    const int c0 = dir ? 0 : 1;
    ushort4 u = *(const ushort4*)&U[((size_t)c0 * 16 + h) * 8192 + e];
    for (int c = c0; c < 32; ++c) {
        ushort4 un = make_ushort4(0, 0, 0, 0);
        if (c + 1 < 32) un = *(const ushort4*)&U[((size_t)(c + 1) * 16 + h) * 8192 + e];
        float Dc = __expf(cum[h * 2048 + c * 64 + 63]);
        ushort4 o = make_ushort4(f2bf(st.x), f2bf(st.y), f2bf(st.z), f2bf(st.w));
        *(ushort4*)&T[(size_t)c * 8192 + e] = o;
        st.x = Dc * st.x + bfu(u.x);
        st.y = Dc * st.y + bfu(u.y);
        st.z = Dc * st.z + bfu(u.z);
        st.w = Dc * st.w + bfu(u.w);
        u = un;
    }
}

// ---------------- gate kernel: direct-global MFMA fragments + gating + partial RMS dot ----------------

__global__ __launch_bounds__(256, 4) void gate_kernel(
    const unsigned short* __restrict__ bcF, const unsigned short* __restrict__ bcB,
    const float* __restrict__ convFs, const float* __restrict__ convFp,
    const float* __restrict__ convBs,
    const float* __restrict__ zxf, const float* __restrict__ zxb,
    const float* __restrict__ cumF, const float* __restrict__ cumB,
    const unsigned short* __restrict__ YiF0, const unsigned short* __restrict__ YiFs,
    const unsigned short* __restrict__ YiB,
    const unsigned short* __restrict__ Tst, const float* __restrict__ psiF,
    const unsigned short* __restrict__ Mb, const float* __restrict__ cb0,
    const float* __restrict__ fD, const float* __restrict__ bD,
    const float* __restrict__ wf2, const float* __restrict__ wb2,
    float* __restrict__ aF, float* __restrict__ aB) {
    __shared__ __align__(16) float Ysm[64 * 68];

    const int iid = blockIdx.x;
    int dir, b = 0, h, c;
    if (iid < 4096) { dir = 0; b = iid >> 9; int r = iid & 511; h = r >> 5; c = r & 31; }
    else            { int k = iid - 4096; dir = 1; h = k >> 5; c = k & 31; }
    const int tid = threadIdx.x, tx = tid & 15, ty = tid >> 4;
    const int lane = tid & 63, wave = tid >> 6;
    const int quad = lane >> 4, l15 = lane & 15;
    const bool doGemm = !(dir == 0 && c == 0);

    if (doGemm) {
        const int wt = (wave >> 1) * 32, wp = (wave & 1) * 32;
        const unsigned short* Cbase = (dir == 0)
            ? bcF + ((size_t)(64 * c - 3)) * 256 + 128
            : bcB + ((size_t)(64 * c)) * 256 + 128;
        const unsigned short* Tp = Tst + ((size_t)(dir * 16 + h) * 32 + c) * 8192;
        const unsigned short* Mp = Mb + (size_t)(b * 16 + h) * 8192;
        const float psi = (dir == 0) ? psiF[h * 32 + c] : 0.f;
        f32x4 acc[2][2];
#pragma unroll
        for (int i = 0; i < 2; ++i)
#pragma unroll
            for (int j = 0; j < 2; ++j) acc[i][j] = (f32x4){0.f, 0.f, 0.f, 0.f};
#pragma unroll
        for (int ks = 0; ks < 4; ++ks) {
            bf16x8 af[2], bw[2];
#pragma unroll
            for (int i = 0; i < 2; ++i)
                af[i] = *(const bf16x8*)&Cbase[(size_t)(wt + i * 16 + l15) * 256 + ks * 32 + quad * 8];
#pragma unroll
            for (int j = 0; j < 2; ++j) {
                int p = wp + j * 16 + l15;
                bf16x8 tv = *(const bf16x8*)&Tp[p * 128 + ks * 32 + quad * 8];
                if (dir == 0) {
                    bf16x8 mv = *(const bf16x8*)&Mp[p * 128 + ks * 32 + quad * 8];
#pragma unroll
                    for (int jj = 0; jj < 8; ++jj)
                        bw[j][jj] = (short)f2bf(bfu((unsigned short)tv[jj]) + psi * bfu((unsigned short)mv[jj]));
                } else {
                    bw[j] = tv;
                }
            }
#pragma unroll
            for (int i = 0; i < 2; ++i)
#pragma unroll
                for (int j = 0; j < 2; ++j)
                    acc[i][j] = __builtin_amdgcn_mfma_f32_16x16x32_bf16(af[i], bw[j], acc[i][j], 0, 0, 0);
        }
#pragma unroll
        for (int i = 0; i < 2; ++i)
#pragma unroll
            for (int j = 0; j < 2; ++j)
#pragma unroll
                for (int r = 0; r < 4; ++r)
                    Ysm[(wt + i * 16 + quad * 4 + r) * 68 + wp + j * 16 + l15] = acc[i][j][r];
    }
    __syncthreads();

    // gating + partial reduction
    const float Dh = (dir ? bD : fD)[h];
    const float* wvp = dir ? wb2 : wf2;
    float4 wreg = *(const float4*)&wvp[h * 64 + tx * 4];
    const float* cumA = dir ? cumB : cumF;
    float4 x0v = make_float4(0.f, 0.f, 0.f, 0.f);
    float cbv[4] = {0.f, 0.f, 0.f, 0.f};
    if (dir == 0 && c == 0) {
        x0v = *(const float4*)&convFp[(size_t)(b * 4) * CONVD + h * 64 + tx * 4];
#pragma unroll
        for (int i = 0; i < 4; ++i) cbv[i] = cb0[(b * 16 + h) * 64 + (ty + 16 * i)];
    }
#pragma unroll
    for (int i = 0; i < 4; ++i) {
        int tl = ty + 16 * i;
        int j = 64 * c + tl;
        float et = __expf(cumA[h * 2048 + j]);
        const unsigned short* Yi;
        const float *xrow, *zrow;
        if (dir == 0) {
            int t = j + 1;
            Yi = (c == 0) ? YiF0 + (size_t)(b * 16 + h) * 4096 : YiFs + (size_t)(c * 16 + h) * 4096;
            xrow = (t < 4) ? convFp + (size_t)(b * 4 + t) * CONVD : convFs + (size_t)(t - 4) * CONVD;
            zrow = zxf + (size_t)j * DPROJ;
        } else {
            Yi = YiB + (size_t)(c * 16 + h) * 4096;
            xrow = convBs + (size_t)j * CONVD;
            zrow = zxb + (size_t)(2047 - j) * DPROJ;
        }
        ushort4 yi4 = *(const ushort4*)&Yi[tl * 64 + tx * 4];
        float4 xx = *(const float4*)&xrow[h * 64 + tx * 4];
        float4 zz = *(const float4*)&zrow[h * 64 + tx * 4];
        float ya[4] = {0.f, 0.f, 0.f, 0.f};
        if (doGemm) {
            float4 y4 = *(const float4*)&Ysm[tl * 68 + tx * 4];
            ya[0] = y4.x; ya[1] = y4.y; ya[2] = y4.z; ya[3] = y4.w;
        }
        float yv[4] = {bfu(yi4.x), bfu(yi4.y), bfu(yi4.z), bfu(yi4.w)};
        float xa[4] = {xx.x, xx.y, xx.z, xx.w};
        float za[4] = {zz.x, zz.y, zz.z, zz.w};
        float x0a[4] = {x0v.x, x0v.y, x0v.z, x0v.w};
        float wa[4] = {wreg.x, wreg.y, wreg.z, wreg.w};
        float a1 = 0.f, a2 = 0.f;
#pragma unroll
        for (int w = 0; w < 4; ++w) {
            float tot = yv[w] + et * (ya[w] + cbv[i] * x0a[w]) + Dh * xa[w];
            float g = tot * siluf(za[w]);
            a1 += g * wa[w];
            a2 += g * g;
        }
#pragma unroll
        for (int m = 1; m < 16; m <<= 1) {
            a1 += __shfl_xor(a1, m);
            a2 += __shfl_xor(a2, m);
        }
        if (tx == 0) {
            if (dir == 0) {
                size_t o = ((size_t)(b * 2048 + j) * 16 + h) * 2;
                aF[o] = a1; aF[o + 1] = a2;
            } else {
                int g = 2047 - j;
                size_t o = ((size_t)g * 16 + h) * 2;
                aB[o] = a1; aB[o + 1] = a2;
            }
        }
    }
}

// ---------------- final combine ----------------

__global__ void final_kernel(const float* __restrict__ aF, const float* __restrict__ aB,
                             const float* __restrict__ headB, float* __restrict__ out) {
    int idx = blockIdx.x * 256 + threadIdx.x;   // 16384
    int b = idx >> 11, g = idx & 2047;
    const float* pf = aF + ((size_t)(b * 2048 + g)) * 32;
    const float* pb = aB + (size_t)g * 32;
    float f1 = 0.f, f2 = 0.f, b1 = 0.f, b2 = 0.f;
#pragma unroll
    for (int h = 0; h < 16; ++h) {
        f1 += pf[2 * h]; f2 += pf[2 * h + 1];
        b1 += pb[2 * h]; b2 += pb[2 * h + 1];
    }
    out[idx] = f1 * rsqrtf(f2 * (1.f / 1024.f) + 1e-5f) +
               b1 * rsqrtf(b2 * (1.f / 1024.f) + 1e-5f) + headB[0];
}

// ---------------- launch ----------------

extern "C" void kernel_launch(void* const* d_in, const int* in_sizes, int n_in,
                              void* d_out, int out_size, void* d_ws, size_t ws_size,
                              hipStream_t stream) {
    const int*   pidx   = (const int*)  d_in[0];
    const int*   chridx = (const int*)  d_in[1];
    const float* locusF = (const float*)d_in[2];
    const float* pathF  = (const float*)d_in[3];
    const float* pertE  = (const float*)d_in[4];
    const float* gidE   = (const float*)d_in[5];
    const float* chrE   = (const float*)d_in[6];
    const float* locusW = (const float*)d_in[7];
    const float* locusB = (const float*)d_in[8];
    const float* condW  = (const float*)d_in[9];
    const float* condB  = (const float*)d_in[10];
    const float* inW    = (const float*)d_in[11];
    const float* inB    = (const float*)d_in[12];
    const float* headW  = (const float*)d_in[13];
    const float* headB  = (const float*)d_in[14];
    const float* fInW   = (const float*)d_in[15];
    const float* fCw    = (const float*)d_in[16];
    const float* fCb    = (const float*)d_in[17];
    const float* fDtB   = (const float*)d_in[18];
    const float* fAlog  = (const float*)d_in[19];
    const float* fDp    = (const float*)d_in[20];
    const float* fNw    = (const float*)d_in[21];
    const float* fOutW  = (const float*)d_in[22];
    const float* bInW   = (const float*)d_in[23];
    const float* bCw    = (const float*)d_in[24];
    const float* bCb    = (const float*)d_in[25];
    const float* bDtB   = (const float*)d_in[26];
    const float* bAlog  = (const float*)d_in[27];
    const float* bDp    = (const float*)d_in[28];
    const float* bNw    = (const float*)d_in[29];
    const float* bOutW  = (const float*)d_in[30];
    float* out = (float*)d_out;
    (void)in_sizes; (void)n_in; (void)out_size; (void)ws_size;

    char* base = (char*)d_ws;
    size_t off = 0;
    auto allocf = [&](size_t n) -> float* {
        char* r = base + off; off += ((n * 4 + 63) & ~(size_t)63); return (float*)r; };
    auto allocu = [&](size_t n) -> unsigned short* {
        char* r = base + off; off += ((n * 2 + 63) & ~(size_t)63); return (unsigned short*)r; };

    float* gf     = allocf(2048UL * 384);
    float* cond   = allocf(8UL * 384);
    float* cemb   = allocf(8UL * 128);
    float* ug     = allocf(2048UL * 512);
    float* uc     = allocf(8UL * 512);
    float* zxf    = allocf(2048UL * DPROJ);
    float* zxb    = allocf(2048UL * DPROJ);
    float* zxc    = allocf(8UL * DPROJ);
    float* convFs = allocf(2045UL * CONVD);
    float* convFp = allocf(8UL * 4 * CONVD);
    float* convBs = allocf(2048UL * CONVD);
    float* dtFs   = allocf(2048UL * 16);
    float* dtFp   = allocf(128);
    float* dtBs   = allocf(2048UL * 16);
    float* cumF   = allocf(16UL * 2048);
    float* cumB   = allocf(16UL * 2048);
    float* wf2    = allocf(1024);
    float* wb2    = allocf(1024);
    float* cb0    = allocf(8UL * 16 * 64);
    float* psiF   = allocf(16UL * 32);
    float* aF     = allocf(8UL * 2048 * 16 * 2);
    float* aB     = allocf(2048UL * 16 * 2);
    unsigned short* YiF0 = allocu(8UL * 16 * 4096);
    unsigned short* YiFs = allocu(32UL * 16 * 4096);
    unsigned short* YiB  = allocu(32UL * 16 * 4096);
    unsigned short* UF0  = allocu(8UL * 16 * 8192);
    unsigned short* UFs  = allocu(32UL * 16 * 8192);
    unsigned short* UB   = allocu(32UL * 16 * 8192);
    unsigned short* Mb   = allocu(8UL * 16 * 8192);
    unsigned short* Tst  = allocu(2UL * 16 * 32 * 8192);
    unsigned short* bcF  = allocu(2045UL * 256);
    unsigned short* bcFp = allocu(32UL * 256);
    unsigned short* bcB  = allocu(2048UL * 256);
    unsigned short* gf2   = allocu(2048UL * 384);
    unsigned short* inW2  = allocu(512UL * 384);
    unsigned short* ug2   = allocu(2048UL * 512);
    unsigned short* fInW2 = allocu(2432UL * 512);
    unsigned short* bInW2 = allocu(2432UL * 512);

    gather_kernel<<<4, 256, 0, stream>>>(pidx, pertE, cemb);
    wfold_kernel<<<32, 256, 0, stream>>>(headW, fOutW, fNw, bOutW, bNw, wf2, wb2);
    genefeat_kernel<<<3072, 256, 0, stream>>>(chridx, gidE, pathF, chrE, gf);
    gemm_kernel<<<dim3(1, 32), 256, 0, stream>>>(locusF, locusW, locusB, gf + 320, 2048, 64, 64, 384, 1);
    gemm_kernel<<<dim3(6, 1), 256, 0, stream>>>(cemb, condW, condB, cond, 8, 384, 128, 384, 0);

    // weight conversions (bf16, no lo-split)
    tobf_kernel<<<(512 * 384 + 255) / 256, 256, 0, stream>>>(inW, inW2, 512, 384, 512);
    tobf_kernel<<<(2432 * 512 + 255) / 256, 256, 0, stream>>>(fInW, fInW2, 2320, 512, 2432);
    tobf_kernel<<<(2432 * 512 + 255) / 256, 256, 0, stream>>>(bInW, bInW2, 2320, 512, 2432);

    // ug = gf @ inW^T
    tobf_kernel<<<(2048 * 384 + 255) / 256, 256, 0, stream>>>(gf, gf2, 2048, 384, 2048);
    mfma_gemm_kernel<<<dim3(4, 16), 256, 0, stream>>>(gf2, inW2, inB, ug, 512, 384, 512);
    gemm_kernel<<<dim3(8, 1), 256, 0, stream>>>(cond, inW, inB, uc, 8, 512, 384, 512, 0);

    // zxf/zxb = ug @ {f,b}InW^T
    tobf_kernel<<<(2048 * 512 + 255) / 256, 256, 0, stream>>>(ug, ug2, 2048, 512, 2048);
    mfma_gemm_kernel<<<dim3(19, 16), 256, 0, stream>>>(ug2, fInW2, nullptr, zxf, 2320, 512, 2320);
    mfma_gemm_kernel<<<dim3(19, 16), 256, 0, stream>>>(ug2, bInW2, nullptr, zxb, 2320, 512, 2320);
    gemm_kernel<<<dim3(37, 1), 256, 0, stream>>>(uc, fInW, nullptr, zxc, 8, DPROJ, 512, DPROJ, 0);

    dt_kernel<<<128, 256, 0, stream>>>(zxf, fDtB, dtFs, 0);
    dt_kernel<<<128, 256, 0, stream>>>(zxb, bDtB, dtBs, 1);
    dtpb_kernel<<<1, 128, 0, stream>>>(zxc, fDtB, dtFp);
    cum_kernel<<<4, 256, 0, stream>>>(dtFs, dtBs, fAlog, bAlog, cumF, cumB);
    convFsh_kernel<<<(2045 * 1280 + 255) / 256, 256, 0, stream>>>(zxf, fCw, fCb, convFs, bcF);
    convFpb_kernel<<<160, 256, 0, stream>>>(zxf, zxc, fCw, fCb, convFp, bcFp);
    convBsh_kernel<<<10240, 256, 0, stream>>>(zxb, bCw, bCb, convBs, bcB);
    intra_kernel<<<1136, 256, 0, stream>>>(bcF, bcFp, bcB, convFs, convFp, convBs,
                                           dtFs, dtBs, cumF, cumB,
                                           YiF0, YiFs, YiB, UF0, UFs, UB);
    cb0_kernel<<<32, 256, 0, stream>>>(convFs, convFp, dtFp, cb0);
    m_kernel<<<128, 256, 0, stream>>>(UF0, convFp, dtFp, cumF, Mb);
    tpsi_kernel<<<256, 256, 0, stream>>>(UFs, UB, cumF, cumB, Tst, psiF);
    gate_kernel<<<4608, 256, 0, stream>>>(bcF, bcB, convFs, convFp, convBs, zxf, zxb, cumF, cumB,
                                          YiF0, YiFs, YiB, Tst, psiF, Mb, cb0,
                                          fDp, bDp, wf2, wb2, aF, aB);
    final_kernel<<<64, 256, 0, stream>>>(aF, aB, headB, out);
}

// Round 6
// 445.430 us; speedup vs baseline: 6.4794x; 1.0351x over previous
//
#include <hip/hip_runtime.h>
#include <hip/hip_bf16.h>
#include <hip/hip_fp16.h>
#include <math.h>

#define DPROJ 2320
#define CONVD 1280

typedef __attribute__((ext_vector_type(8))) short bf16x8;
typedef __attribute__((ext_vector_type(4))) float f32x4;

__device__ __forceinline__ float siluf(float x) { return x / (1.f + __expf(-x)); }
__device__ __forceinline__ float bfu(unsigned short s) { return __uint_as_float(((unsigned)s) << 16); }
__device__ __forceinline__ unsigned short f2bf(float f) {
    unsigned u = __float_as_uint(f);
    unsigned r = (u + 0x7FFFu + ((u >> 16) & 1u)) >> 16;
    return (unsigned short)r;
}
__device__ __forceinline__ unsigned short f2h(float f) {
    __half h = __float2half(f);
    return *(unsigned short*)&h;
}
__device__ __forceinline__ float h2f(unsigned short s) {
    __half h = *(__half*)&s;
    return __half2float(h);
}

// ---------------- fused gather + genefeat ----------------

__global__ void gg_kernel(const int* __restrict__ chridx, const float* __restrict__ gid,
                          const float* __restrict__ path, const float* __restrict__ chrE,
                          const int* __restrict__ pidx, const float* __restrict__ pertE,
                          float* __restrict__ gf, float* __restrict__ cemb) {
    int blk = blockIdx.x, tid = threadIdx.x;
    if (blk < 3072) {
        int idx = blk * 256 + tid;   // 2048*384
        int g = idx / 384, j = idx % 384;
        float v;
        if (j < 128)      v = gid[(size_t)g * 128 + j];
        else if (j < 256) v = path[(size_t)g * 128 + (j - 128)];
        else if (j < 320) v = chrE[(size_t)chridx[g] * 64 + (j - 256)];
        else return;
        gf[idx] = v;
    } else {
        int idx = (blk - 3072) * 256 + tid;   // 1024
        int b = idx >> 7, k = idx & 127;
        cemb[idx] = pertE[(size_t)pidx[b] * 128 + k];
    }
}

__global__ void wfold_kernel(const float* __restrict__ headW,
                             const float* __restrict__ fOutW, const float* __restrict__ fNw,
                             const float* __restrict__ bOutW, const float* __restrict__ bNw,
                             float* __restrict__ wf2, float* __restrict__ wb2) {
    __shared__ float red[256];
    int blk = blockIdx.x;   // 32
    int dir = blk >> 4, dc = blk & 15;
    int tid = threadIdx.x;
    int d = dc * 64 + (tid & 63), seg = tid >> 6;
    const float* W = dir ? bOutW : fOutW;
    float s = 0.f;
    for (int m = seg * 128; m < seg * 128 + 128; ++m) s += headW[m] * W[(size_t)m * 1024 + d];
    red[tid] = s;
    __syncthreads();
    if (tid < 64) {
        float tot = red[tid] + red[tid + 64] + red[tid + 128] + red[tid + 192];
        const float* nw = dir ? bNw : fNw;
        (dir ? wb2 : wf2)[d] = tot * nw[d];
    }
}

// ---------------- fused bf16 conversions (weights + gf) ----------------

__global__ void tobf4_kernel(const float* __restrict__ inW, const float* __restrict__ fInW,
                             const float* __restrict__ bInW, const float* __restrict__ gf,
                             unsigned short* __restrict__ inW2, unsigned short* __restrict__ fInW2,
                             unsigned short* __restrict__ bInW2, unsigned short* __restrict__ gf2) {
    size_t idx = (size_t)blockIdx.x * 256 + threadIdx.x;
    const size_t A = 512UL * 384, B5 = 2432UL * 512;
    if (idx < A) {
        inW2[idx] = f2bf(inW[idx]);
    } else if (idx < A + B5) {
        size_t k = idx - A; int m = k / 512, kk = k % 512;
        fInW2[k] = f2bf(m < 2320 ? fInW[(size_t)m * 512 + kk] : 0.f);
    } else if (idx < A + 2 * B5) {
        size_t k = idx - A - B5; int m = k / 512, kk = k % 512;
        bInW2[k] = f2bf(m < 2320 ? bInW[(size_t)m * 512 + kk] : 0.f);
    } else {
        size_t k = idx - A - 2 * B5;   // 2048*384
        gf2[k] = f2bf(gf[k]);
    }
}

__global__ void tobf_kernel(const float* __restrict__ in, unsigned short* __restrict__ out,
                            int M, int K, int Mpad) {
    int idx = blockIdx.x * 256 + threadIdx.x;
    if (idx >= Mpad * K) return;
    int m = idx / K, k = idx % K;
    float v = (m < M) ? in[(size_t)m * K + k] : 0.f;
    out[idx] = f2bf(v);
}

// ---------------- MFMA GEMM: C[M x N] = A2[M x K2] . W2[Npad x K2]^T (+bias) ----------------

__global__ __launch_bounds__(256) void mfma_gemm_kernel(
    const unsigned short* __restrict__ A2, const unsigned short* __restrict__ W2,
    const float* __restrict__ bias, float* __restrict__ C,
    int N, int K2, int ldc) {
    __shared__ __align__(16) unsigned short Al[128 * 40];
    __shared__ __align__(16) unsigned short Bl[128 * 40];
    const int tid = threadIdx.x;
    const int bm = blockIdx.y * 128, bn = blockIdx.x * 128;
    const int lane = tid & 63, wave = tid >> 6;
    const int wm = (wave >> 1) * 64, wn = (wave & 1) * 64;
    f32x4 acc[4][4];
#pragma unroll
    for (int i = 0; i < 4; ++i)
#pragma unroll
        for (int j = 0; j < 4; ++j) acc[i][j] = (f32x4){0.f, 0.f, 0.f, 0.f};

    for (int k0 = 0; k0 < K2; k0 += 32) {
        __syncthreads();
#pragma unroll
        for (int s = 0; s < 2; ++s) {
            int ch = tid + 256 * s;
            int row = ch >> 2, q = ch & 3;
            uint4 va = *(const uint4*)&A2[(size_t)(bm + row) * K2 + k0 + q * 8];
            *(uint4*)&Al[row * 40 + q * 8] = va;
            uint4 vb = *(const uint4*)&W2[(size_t)(bn + row) * K2 + k0 + q * 8];
            *(uint4*)&Bl[row * 40 + q * 8] = vb;
        }
        __syncthreads();
        bf16x8 af[4], bfr[4];
#pragma unroll
        for (int i = 0; i < 4; ++i)
            af[i] = *(const bf16x8*)&Al[(wm + i * 16 + (lane & 15)) * 40 + (lane >> 4) * 8];
#pragma unroll
        for (int j = 0; j < 4; ++j)
            bfr[j] = *(const bf16x8*)&Bl[(wn + j * 16 + (lane & 15)) * 40 + (lane >> 4) * 8];
#pragma unroll
        for (int i = 0; i < 4; ++i)
#pragma unroll
            for (int j = 0; j < 4; ++j)
                acc[i][j] = __builtin_amdgcn_mfma_f32_16x16x32_bf16(af[i], bfr[j], acc[i][j], 0, 0, 0);
    }
#pragma unroll
    for (int i = 0; i < 4; ++i) {
        int m = bm + wm + i * 16 + (lane >> 4) * 4;
#pragma unroll
        for (int j = 0; j < 4; ++j) {
            int n = bn + wn + j * 16 + (lane & 15);
            if (n < N) {
                float bv = bias ? bias[n] : 0.f;
#pragma unroll
                for (int r = 0; r < 4; ++r)
                    C[(size_t)(m + r) * ldc + n] = acc[i][j][r] + bv;
            }
        }
    }
}

// ---------------- generic tiled fp32 GEMM (small shapes only) ----------------

__global__ __launch_bounds__(256) void gemm_kernel(
    const float* __restrict__ A, const float* __restrict__ W,
    const float* __restrict__ bias, float* __restrict__ C,
    int M, int N, int K, int ldc, int act) {
    __shared__ __align__(16) float As[16][68];
    __shared__ __align__(16) float Ws[16][68];
    const int tid = threadIdx.x;
    const int tx = tid & 15, ty = tid >> 4;
    const int bm = blockIdx.y * 64, bn = blockIdx.x * 64;
    const int lr = tid >> 2;
    const int lk = (tid & 3) * 4;
    float acc[4][4];
#pragma unroll
    for (int i = 0; i < 4; ++i)
#pragma unroll
        for (int j = 0; j < 4; ++j) acc[i][j] = 0.f;

    for (int k0 = 0; k0 < K; k0 += 16) {
        const int am = bm + lr;
        const int wn = bn + lr;
        float4 av = make_float4(0.f, 0.f, 0.f, 0.f), wv = make_float4(0.f, 0.f, 0.f, 0.f);
        if (am < M) av = *(const float4*)&A[(size_t)am * K + k0 + lk];
        if (wn < N) wv = *(const float4*)&W[(size_t)wn * K + k0 + lk];
        __syncthreads();
        As[lk + 0][lr] = av.x; As[lk + 1][lr] = av.y; As[lk + 2][lr] = av.z; As[lk + 3][lr] = av.w;
        Ws[lk + 0][lr] = wv.x; Ws[lk + 1][lr] = wv.y; Ws[lk + 2][lr] = wv.z; Ws[lk + 3][lr] = wv.w;
        __syncthreads();
#pragma unroll
        for (int kk = 0; kk < 16; ++kk) {
            float4 a = *(const float4*)&As[kk][ty * 4];
            float4 w = *(const float4*)&Ws[kk][tx * 4];
            float aa[4] = {a.x, a.y, a.z, a.w}, ww[4] = {w.x, w.y, w.z, w.w};
#pragma unroll
            for (int i = 0; i < 4; ++i)
#pragma unroll
                for (int j = 0; j < 4; ++j) acc[i][j] += aa[i] * ww[j];
        }
    }
#pragma unroll
    for (int i = 0; i < 4; ++i) {
        const int m = bm + ty * 4 + i;
        if (m >= M) continue;
#pragma unroll
        for (int j = 0; j < 4; ++j) {
            const int n = bn + tx * 4 + j;
            if (n >= N) continue;
            float v = acc[i][j] + (bias ? bias[n] : 0.f);
            if (act == 1) v = 0.5f * v * (1.f + erff(v * 0.70710678118654752f));
            C[(size_t)m * ldc + n] = v;
        }
    }
}

// ---------------- fused elementwise: silu(z) fp16 copies + dt (fwd/bwd/per-batch) ----------------

__global__ void elem_kernel(const float* __restrict__ zxf, const float* __restrict__ zxb,
                            const float* __restrict__ zxc,
                            const float* __restrict__ fDtB, const float* __restrict__ bDtB,
                            unsigned short* __restrict__ szF, unsigned short* __restrict__ szB,
                            float* __restrict__ dtFs, float* __restrict__ dtBs,
                            float* __restrict__ dtFp) {
    size_t idx = (size_t)blockIdx.x * 256 + threadIdx.x;
    const size_t SZ = 2048UL * 1024;
    if (idx < SZ) {
        size_t j = idx >> 10, d = idx & 1023;
        szF[idx] = f2h(siluf(zxf[j * DPROJ + d]));
    } else if (idx < 2 * SZ) {
        size_t k = idx - SZ;
        size_t j = k >> 10, d = k & 1023;
        szB[k] = f2h(siluf(zxb[j * DPROJ + d]));
    } else if (idx < 2 * SZ + 32768) {
        int k = (int)(idx - 2 * SZ);
        int r = k >> 4, hh = k & 15;
        float raw = zxf[(size_t)r * DPROJ + 2304 + hh] + fDtB[hh];
        dtFs[k] = (raw > 20.f) ? raw : log1pf(expf(raw));
    } else if (idx < 2 * SZ + 65536) {
        int k = (int)(idx - 2 * SZ - 32768);
        int r = k >> 4, hh = k & 15;
        float raw = zxb[(size_t)(2047 - r) * DPROJ + 2304 + hh] + bDtB[hh];
        dtBs[k] = (raw > 20.f) ? raw : log1pf(expf(raw));
    } else if (idx < 2 * SZ + 65536 + 128) {
        int k = (int)(idx - 2 * SZ - 65536);
        int b = k >> 4, hh = k & 15;
        float raw = zxc[(size_t)b * DPROJ + 2304 + hh] + fDtB[hh];
        dtFp[k] = (raw > 20.f) ? raw : log1pf(expf(raw));
    }
}

// chunk-local inclusive cumsum of ldA = -dt*exp(A_log)
__global__ void cum_kernel(const float* __restrict__ dtFs, const float* __restrict__ dtBs,
                           const float* __restrict__ fAlog, const float* __restrict__ bAlog,
                           float* __restrict__ cumF, float* __restrict__ cumB) {
    int id = blockIdx.x * 256 + threadIdx.x;   // 1024
    int dir = id >> 9, k = id & 511, h = k >> 5, c = k & 31;
    const float* dt = dir ? dtBs : dtFs;
    const float* Al = dir ? bAlog : fAlog;
    float* cum = dir ? cumB : cumF;
    float a = expf(Al[h]);
    float acc = 0.f;
    for (int s = 0; s < 64; ++s) {
        int j = c * 64 + s;
        acc += -dt[j * 16 + h] * a;
        cum[h * 2048 + j] = acc;
    }
}

// ---------------- causal depthwise conv (+SiLU), with bf16 B/C and fp16 x side-copies ----------------

__global__ void convFsh_kernel(const float* __restrict__ zxf, const float* __restrict__ cw,
                               const float* __restrict__ cb, float* __restrict__ outp,
                               unsigned short* __restrict__ bc16, unsigned short* __restrict__ x16) {
    int idx = blockIdx.x * 256 + threadIdx.x;
    if (idx >= 2045 * 1280) return;
    int t4 = idx / 1280, c = idx % 1280;
    float4 w4 = *(const float4*)&cw[c * 4];
    float acc = cb[c];
    acc += zxf[(size_t)(t4 + 0) * DPROJ + 1024 + c] * w4.x;
    acc += zxf[(size_t)(t4 + 1) * DPROJ + 1024 + c] * w4.y;
    acc += zxf[(size_t)(t4 + 2) * DPROJ + 1024 + c] * w4.z;
    acc += zxf[(size_t)(t4 + 3) * DPROJ + 1024 + c] * w4.w;
    float r = siluf(acc);
    outp[idx] = r;
    if (c >= 1024) bc16[(size_t)t4 * 256 + (c - 1024)] = f2bf(r);
    else           x16[(size_t)t4 * 1024 + c] = f2h(r);
}

__global__ void convFpb_kernel(const float* __restrict__ zxf, const float* __restrict__ zxc,
                               const float* __restrict__ cw, const float* __restrict__ cb,
                               float* __restrict__ outp, unsigned short* __restrict__ bc16,
                               unsigned short* __restrict__ x16) {
    int idx = blockIdx.x * 256 + threadIdx.x;   // 8*4*1280
    int b = idx / 5120;
    int r = idx % 5120;
    int t = r / 1280, c = r % 1280;
    float4 w4 = *(const float4*)&cw[c * 4];
    float w[4] = {w4.x, w4.y, w4.z, w4.w};
    float acc = cb[c];
#pragma unroll
    for (int k = 0; k < 4; ++k) {
        int j = t - 3 + k;
        float x = 0.f;
        if (j == 0)      x = zxc[(size_t)b * DPROJ + 1024 + c];
        else if (j >= 1) x = zxf[(size_t)(j - 1) * DPROJ + 1024 + c];
        acc += x * w[k];
    }
    float rr = siluf(acc);
    outp[idx] = rr;
    if (c >= 1024) bc16[(size_t)(b * 4 + t) * 256 + (c - 1024)] = f2bf(rr);
    else           x16[(size_t)(b * 4 + t) * 1024 + c] = f2h(rr);
}

__global__ void convBsh_kernel(const float* __restrict__ zxb, const float* __restrict__ cw,
                               const float* __restrict__ cb, float* __restrict__ outp,
                               unsigned short* __restrict__ bc16, unsigned short* __restrict__ x16) {
    int idx = blockIdx.x * 256 + threadIdx.x;   // 2048*1280
    int s = idx / 1280, c = idx % 1280;
    float4 w4 = *(const float4*)&cw[c * 4];
    float w[4] = {w4.x, w4.y, w4.z, w4.w};
    float acc = cb[c];
#pragma unroll
    for (int k = 0; k < 4; ++k) {
        int j = s - 3 + k;
        if (j >= 0) acc += zxb[(size_t)(2047 - j) * DPROJ + 1024 + c] * w[k];
    }
    float r = siluf(acc);
    outp[idx] = r;
    if (c >= 1024) bc16[(size_t)s * 256 + (c - 1024)] = f2bf(r);
    else           x16[(size_t)s * 1024 + c] = f2h(r);
}

// ---------------- intra-chunk kernel (MFMA) ----------------

__global__ __launch_bounds__(256) void intra_kernel(
    const unsigned short* __restrict__ bcF, const unsigned short* __restrict__ bcFp,
    const unsigned short* __restrict__ bcB,
    const float* __restrict__ convFs, const float* __restrict__ convFp,
    const float* __restrict__ convBs,
    const float* __restrict__ dtFs, const float* __restrict__ dtBs,
    const float* __restrict__ cumF, const float* __restrict__ cumB,
    unsigned short* __restrict__ YiF0, unsigned short* __restrict__ YiFs,
    unsigned short* __restrict__ YiB,
    unsigned short* __restrict__ UF0, unsigned short* __restrict__ UFs,
    unsigned short* __restrict__ UB) {
    __shared__ __align__(16) unsigned char smraw[63232];
    unsigned short* Bt = (unsigned short*)smraw;                    // 64 x 136  [s][n]
    unsigned short* Ct = (unsigned short*)(smraw + 17408);          // 64 x 136  [t][n]
    unsigned short* Sm = (unsigned short*)(smraw + 17408);          // 64 x 72   [t][s] (alias Ct)
    unsigned short* BT = (unsigned short*)(smraw + 34816);          // 128 x 72  [n][s]
    unsigned short* XT = (unsigned short*)(smraw + 53248);          // 64 x 72   [p][s]
    float* scum = (float*)(smraw + 62464);                          // 64
    float* sdt  = scum + 64;                                        // 64
    float* se   = scum + 128;                                       // 64

    const int iid = blockIdx.x;
    int dir, b = 0, h, c;
    unsigned short *Yout, *Uout;
    if (iid < 128)      { dir = 0; b = iid >> 4; h = iid & 15; c = 0;
                          Yout = YiF0 + (size_t)(b * 16 + h) * 4096; Uout = UF0 + (size_t)(b * 16 + h) * 8192; }
    else if (iid < 624) { int k = iid - 128; dir = 0; c = 1 + (k >> 4); h = k & 15;
                          Yout = YiFs + (size_t)(c * 16 + h) * 4096; Uout = UFs + (size_t)(c * 16 + h) * 8192; }
    else                { int k = iid - 624; dir = 1; c = k >> 4; h = k & 15;
                          Yout = YiB + (size_t)(c * 16 + h) * 4096;  Uout = UB + (size_t)(c * 16 + h) * 8192; }
    const float* dtA = dir ? dtBs : dtFs;
    const float* cumA = dir ? cumB : cumF;

    const int tid = threadIdx.x;
    const int lane = tid & 63, wave = tid >> 6;
    const int quad = lane >> 4, l15 = lane & 15;

    {
        int r = tid >> 2, q = tid & 3;
        const unsigned short* bsrc;
        const float* xrow;
        if (dir == 0) {
            int t = 64 * c + 1 + r;
            if (t < 4) { bsrc = bcFp + (size_t)(b * 4 + t) * 256; xrow = convFp + (size_t)(b * 4 + t) * CONVD; }
            else       { bsrc = bcF + (size_t)(t - 4) * 256;      xrow = convFs + (size_t)(t - 4) * CONVD; }
        } else {
            int s = 64 * c + r;
            bsrc = bcB + (size_t)s * 256;
            xrow = convBs + (size_t)s * CONVD;
        }
#pragma unroll
        for (int i = 0; i < 4; ++i) {
            int n0 = q * 32 + i * 8;
            uint4 v = *(const uint4*)&bsrc[n0];
            *(uint4*)&Bt[r * 136 + n0] = v;
            const unsigned short* pv = (const unsigned short*)&v;
#pragma unroll
            for (int jj = 0; jj < 8; ++jj) BT[(n0 + jj) * 72 + r] = pv[jj];
        }
#pragma unroll
        for (int i = 0; i < 4; ++i) {
            int n0 = q * 32 + i * 8;
            uint4 v = *(const uint4*)&bsrc[128 + n0];
            *(uint4*)&Ct[r * 136 + n0] = v;
        }
#pragma unroll
        for (int i = 0; i < 4; ++i) {
            int p0 = (q + 4 * i) * 4;
            float4 v = *(const float4*)&xrow[h * 64 + p0];
            XT[(p0 + 0) * 72 + r] = f2bf(v.x);
            XT[(p0 + 1) * 72 + r] = f2bf(v.y);
            XT[(p0 + 2) * 72 + r] = f2bf(v.z);
            XT[(p0 + 3) * 72 + r] = f2bf(v.w);
        }
        if (tid < 64) {
            int j = 64 * c + tid;
            scum[tid] = cumA[h * 2048 + j];
            sdt[tid] = dtA[j * 16 + h];
        }
    }
    __syncthreads();
    if (tid < 64) se[tid] = __expf(scum[63] - scum[tid]) * sdt[tid];

    // phase 1: G = C . B^T
    const int tm = (wave >> 1) * 32, sn = (wave & 1) * 32;
    f32x4 acc1[2][2];
#pragma unroll
    for (int i = 0; i < 2; ++i)
#pragma unroll
        for (int j = 0; j < 2; ++j) acc1[i][j] = (f32x4){0.f, 0.f, 0.f, 0.f};
#pragma unroll
    for (int ks = 0; ks < 4; ++ks) {
        bf16x8 af[2], bfr[2];
#pragma unroll
        for (int i = 0; i < 2; ++i)
            af[i] = *(const bf16x8*)&Ct[(tm + i * 16 + l15) * 136 + ks * 32 + quad * 8];
#pragma unroll
        for (int j = 0; j < 2; ++j)
            bfr[j] = *(const bf16x8*)&Bt[(sn + j * 16 + l15) * 136 + ks * 32 + quad * 8];
#pragma unroll
        for (int i = 0; i < 2; ++i)
#pragma unroll
            for (int j = 0; j < 2; ++j)
                acc1[i][j] = __builtin_amdgcn_mfma_f32_16x16x32_bf16(af[i], bfr[j], acc1[i][j], 0, 0, 0);
    }
    __syncthreads();

#pragma unroll
    for (int j = 0; j < 2; ++j) {
        int s = sn + j * 16 + l15;
        float cs = scum[s], ds = sdt[s];
#pragma unroll
        for (int i = 0; i < 2; ++i) {
#pragma unroll
            for (int r = 0; r < 4; ++r) {
                int t = tm + i * 16 + quad * 4 + r;
                float v = (s <= t) ? __expf(scum[t] - cs) * ds * acc1[i][j][r] : 0.f;
                Sm[t * 72 + s] = f2bf(v);
            }
        }
    }
    __syncthreads();

    // phase 2 (swapped): A = X^T rows p, B = Sm rows t -> D[p][t]
    const int pm = (wave >> 1) * 32, tn = (wave & 1) * 32;
    f32x4 acc2[2][2];
#pragma unroll
    for (int i = 0; i < 2; ++i)
#pragma unroll
        for (int j = 0; j < 2; ++j) acc2[i][j] = (f32x4){0.f, 0.f, 0.f, 0.f};
#pragma unroll
    for (int ks = 0; ks < 2; ++ks) {
        bf16x8 af[2], bfr[2];
#pragma unroll
        for (int i = 0; i < 2; ++i)
            af[i] = *(const bf16x8*)&XT[(pm + i * 16 + l15) * 72 + ks * 32 + quad * 8];
#pragma unroll
        for (int j = 0; j < 2; ++j)
            bfr[j] = *(const bf16x8*)&Sm[(tn + j * 16 + l15) * 72 + ks * 32 + quad * 8];
#pragma unroll
        for (int i = 0; i < 2; ++i)
#pragma unroll
            for (int j = 0; j < 2; ++j)
                acc2[i][j] = __builtin_amdgcn_mfma_f32_16x16x32_bf16(af[i], bfr[j], acc2[i][j], 0, 0, 0);
    }
#pragma unroll
    for (int i = 0; i < 2; ++i)
#pragma unroll
        for (int j = 0; j < 2; ++j) {
            int t = tn + j * 16 + l15;
            int p0 = pm + i * 16 + quad * 4;
            ushort4 o = make_ushort4(f2bf(acc2[i][j][0]), f2bf(acc2[i][j][1]),
                                     f2bf(acc2[i][j][2]), f2bf(acc2[i][j][3]));
            *(ushort4*)&Yout[t * 64 + p0] = o;
        }

    // phase 3: U = B^T . (e*X) -> write U[p][n]
    const int nm = wave * 32;
    f32x4 acc3[2][4];
#pragma unroll
    for (int i = 0; i < 2; ++i)
#pragma unroll
        for (int j = 0; j < 4; ++j) acc3[i][j] = (f32x4){0.f, 0.f, 0.f, 0.f};
#pragma unroll
    for (int ks = 0; ks < 2; ++ks) {
        float ev[8];
#pragma unroll
        for (int jj = 0; jj < 8; ++jj) ev[jj] = se[ks * 32 + quad * 8 + jj];
        bf16x8 bfx[4];
#pragma unroll
        for (int j = 0; j < 4; ++j) {
            bf16x8 xs = *(const bf16x8*)&XT[(j * 16 + l15) * 72 + ks * 32 + quad * 8];
#pragma unroll
            for (int jj = 0; jj < 8; ++jj)
                bfx[j][jj] = (short)f2bf(bfu((unsigned short)xs[jj]) * ev[jj]);
        }
        bf16x8 af[2];
#pragma unroll
        for (int i = 0; i < 2; ++i)
            af[i] = *(const bf16x8*)&BT[(nm + i * 16 + l15) * 72 + ks * 32 + quad * 8];
#pragma unroll
        for (int i = 0; i < 2; ++i)
#pragma unroll
            for (int j = 0; j < 4; ++j)
                acc3[i][j] = __builtin_amdgcn_mfma_f32_16x16x32_bf16(af[i], bfx[j], acc3[i][j], 0, 0, 0);
    }
#pragma unroll
    for (int i = 0; i < 2; ++i)
#pragma unroll
        for (int j = 0; j < 4; ++j) {
            int p = j * 16 + l15;
            int n0 = nm + i * 16 + quad * 4;
            ushort4 o = make_ushort4(f2bf(acc3[i][j][0]), f2bf(acc3[i][j][1]),
                                     f2bf(acc3[i][j][2]), f2bf(acc3[i][j][3]));
            *(ushort4*)&Uout[p * 128 + n0] = o;
        }
}

// ---------------- fused cb0 + M ----------------

__global__ void cbm_kernel(const float* __restrict__ convFs, const float* __restrict__ convFp,
                           const float* __restrict__ dtFp, const float* __restrict__ cumF,
                           const unsigned short* __restrict__ UF0,
                           float* __restrict__ cb0, unsigned short* __restrict__ Mb) {
    int blk = blockIdx.x, tid = threadIdx.x;   // 160
    if (blk < 32) {
        int idx = blk * 256 + tid;   // 8192
        int b = idx >> 10, r = idx & 1023, h = r >> 6, tl = r & 63;
        int t = tl + 1;
        const float* crow = (t < 4) ? convFp + (size_t)(b * 4 + t) * CONVD : convFs + (size_t)(t - 4) * CONVD;
        const float* b0 = convFp + (size_t)(b * 4) * CONVD;
        float s = 0.f;
        for (int n = 0; n < 128; ++n) s += crow[1152 + n] * b0[1024 + n];
        cb0[(b * 16 + h) * 64 + tl] = s * dtFp[b * 16 + h];
    } else {
        int bh = blk - 32;   // 128
        int b = bh >> 4, h = bh & 15;
        float D0 = __expf(cumF[h * 2048 + 63]);
        float dt0 = dtFp[b * 16 + h];
        const float* row0 = convFp + (size_t)(b * 4) * CONVD;
        const unsigned short* u = UF0 + (size_t)(b * 16 + h) * 8192;
        unsigned short* m = Mb + (size_t)(b * 16 + h) * 8192;
        for (int e4 = tid; e4 < 2048; e4 += 256) {
            int e = e4 * 4, p = e >> 7, n0 = e & 127;
            float s = D0 * dt0 * row0[h * 64 + p];
            float4 B4 = *(const float4*)&row0[1024 + n0];
            ushort4 uv = *(const ushort4*)&u[e];
            ushort4 o = make_ushort4(f2bf(s * B4.x + bfu(uv.x)), f2bf(s * B4.y + bfu(uv.y)),
                                     f2bf(s * B4.z + bfu(uv.z)), f2bf(s * B4.w + bfu(uv.w)));
            *(ushort4*)&m[e] = o;
        }
    }
}

// ---------------- shared chunk-state scan: T_c, psi_c ----------------

__global__ void tpsi_kernel(const unsigned short* __restrict__ UFs, const unsigned short* __restrict__ UB,
                            const float* __restrict__ cumF, const float* __restrict__ cumB,
                            unsigned short* __restrict__ Tst, float* __restrict__ psiF) {
    int blk = blockIdx.x;   // 256: dir*128 + h*8 + q8
    int dir = blk >> 7, h = (blk >> 3) & 15, q8 = blk & 7;
    int tid = threadIdx.x;
    const unsigned short* U = dir ? UB : UFs;
    const float* cum = dir ? cumB : cumF;
    unsigned short* T = Tst + (size_t)(dir * 16 + h) * 32 * 8192;
    if (dir == 0 && q8 == 0 && tid == 0) {
        float ps = 1.f;
        for (int c = 1; c < 32; ++c) {
            psiF[h * 32 + c] = ps;
            ps *= __expf(cumF[h * 2048 + c * 64 + 63]);
        }
    }
    const size_t e = (size_t)q8 * 1024 + 4 * tid;
    float4 st = make_float4(0.f, 0.f, 0.f, 0.f);
    const int c0 = dir ? 0 : 1;
    ushort4 u = *(const ushort4*)&U[((size_t)c0 * 16 + h) * 8192 + e];
    for (int c = c0; c < 32; ++c) {
        ushort4 un = make_ushort4(0, 0, 0, 0);
        if (c + 1 < 32) un = *(const ushort4*)&U[((size_t)(c + 1) * 16 + h) * 8192 + e];
        float Dc = __expf(cum[h * 2048 + c * 64 + 63]);
        ushort4 o = make_ushort4(f2bf(st.x), f2bf(st.y), f2bf(st.z), f2bf(st.w));
        *(ushort4*)&T[(size_t)c * 8192 + e] = o;
        st.x = Dc * st.x + bfu(u.x);
        st.y = Dc * st.y + bfu(u.y);
        st.z = Dc * st.z + bfu(u.z);
        st.w = Dc * st.w + bfu(u.w);
        u = un;
    }
}

// ---------------- batch-shared Yt = C . T^T ----------------

__global__ __launch_bounds__(256) void yt_kernel(
    const unsigned short* __restrict__ bcF, const unsigned short* __restrict__ bcB,
    const unsigned short* __restrict__ Tst,
    unsigned short* __restrict__ YtF, unsigned short* __restrict__ YtB) {
    const int iid = blockIdx.x;   // 1008
    int dir, h, c;
    if (iid < 496) { dir = 0; c = 1 + (iid >> 4); h = iid & 15; }
    else           { int k = iid - 496; dir = 1; c = k >> 4; h = k & 15; }
    const unsigned short* Cbase = (dir == 0)
        ? bcF + ((size_t)(64 * c - 3)) * 256 + 128
        : bcB + ((size_t)(64 * c)) * 256 + 128;
    const unsigned short* Tp = Tst + ((size_t)(dir * 16 + h) * 32 + c) * 8192;
    unsigned short* Yt = (dir == 0 ? YtF : YtB) + (size_t)(c * 16 + h) * 4096;
    const int tid = threadIdx.x;
    const int lane = tid & 63, wave = tid >> 6;
    const int quad = lane >> 4, l15 = lane & 15;
    const int pm = (wave >> 1) * 32, tb = (wave & 1) * 32;
    f32x4 acc[2][2];
#pragma unroll
    for (int i = 0; i < 2; ++i)
#pragma unroll
        for (int j = 0; j < 2; ++j) acc[i][j] = (f32x4){0.f, 0.f, 0.f, 0.f};
#pragma unroll
    for (int ks = 0; ks < 4; ++ks) {
        bf16x8 af[2], bfr[2];
#pragma unroll
        for (int i = 0; i < 2; ++i)
            af[i] = *(const bf16x8*)&Tp[(size_t)(pm + i * 16 + l15) * 128 + ks * 32 + quad * 8];
#pragma unroll
        for (int j = 0; j < 2; ++j)
            bfr[j] = *(const bf16x8*)&Cbase[(size_t)(tb + j * 16 + l15) * 256 + ks * 32 + quad * 8];
#pragma unroll
        for (int i = 0; i < 2; ++i)
#pragma unroll
            for (int j = 0; j < 2; ++j)
                acc[i][j] = __builtin_amdgcn_mfma_f32_16x16x32_bf16(af[i], bfr[j], acc[i][j], 0, 0, 0);
    }
    // D[p][t]: row p = pm+i*16+quad*4+r, col t = tb+j*16+l15 -> write Yt[t][p] vectorized
#pragma unroll
    for (int i = 0; i < 2; ++i)
#pragma unroll
        for (int j = 0; j < 2; ++j) {
            int t = tb + j * 16 + l15;
            int p0 = pm + i * 16 + quad * 4;
            ushort4 o = make_ushort4(f2bf(acc[i][j][0]), f2bf(acc[i][j][1]),
                                     f2bf(acc[i][j][2]), f2bf(acc[i][j][3]));
            *(ushort4*)&Yt[t * 64 + p0] = o;
        }
}

// ---------------- gate kernel: per-batch cm GEMM + gating + partial RMS dot ----------------

__global__ __launch_bounds__(256, 4) void gate_kernel(
    const unsigned short* __restrict__ bcF,
    const unsigned short* __restrict__ Mb, const float* __restrict__ psiF,
    const unsigned short* __restrict__ YtF, const unsigned short* __restrict__ YtB,
    const unsigned short* __restrict__ xF16, const unsigned short* __restrict__ xFp16,
    const unsigned short* __restrict__ xB16,
    const unsigned short* __restrict__ szF, const unsigned short* __restrict__ szB,
    const float* __restrict__ convFp,
    const float* __restrict__ cumF, const float* __restrict__ cumB,
    const unsigned short* __restrict__ YiF0, const unsigned short* __restrict__ YiFs,
    const unsigned short* __restrict__ YiB,
    const float* __restrict__ cb0,
    const float* __restrict__ fD, const float* __restrict__ bD,
    const float* __restrict__ wf2, const float* __restrict__ wb2,
    float* __restrict__ aF, float* __restrict__ aB) {
    __shared__ __align__(16) float Ysm[64 * 68];

    const int iid = blockIdx.x;
    int dir, b = 0, h, c;
    if (iid < 4096) { dir = 0; b = iid >> 9; int r = iid & 511; h = r >> 5; c = r & 31; }
    else            { int k = iid - 4096; dir = 1; h = k >> 5; c = k & 31; }
    const int tid = threadIdx.x, tx = tid & 15, ty = tid >> 4;
    const int lane = tid & 63, wave = tid >> 6;
    const int quad = lane >> 4, l15 = lane & 15;
    const bool fwdG = (dir == 0 && c > 0);

    if (fwdG) {
        // cm = M_b . C^T  -> D[p][t], stored Ysm[t][p]
        const unsigned short* Cbase = bcF + ((size_t)(64 * c - 3)) * 256 + 128;
        const unsigned short* Mp = Mb + (size_t)(b * 16 + h) * 8192;
        const int pm = (wave >> 1) * 32, tb = (wave & 1) * 32;
        f32x4 acc[2][2];
#pragma unroll
        for (int i = 0; i < 2; ++i)
#pragma unroll
            for (int j = 0; j < 2; ++j) acc[i][j] = (f32x4){0.f, 0.f, 0.f, 0.f};
#pragma unroll
        for (int ks = 0; ks < 4; ++ks) {
            bf16x8 af[2], bfr[2];
#pragma unroll
            for (int i = 0; i < 2; ++i)
                af[i] = *(const bf16x8*)&Mp[(size_t)(pm + i * 16 + l15) * 128 + ks * 32 + quad * 8];
#pragma unroll
            for (int j = 0; j < 2; ++j)
                bfr[j] = *(const bf16x8*)&Cbase[(size_t)(tb + j * 16 + l15) * 256 + ks * 32 + quad * 8];
#pragma unroll
            for (int i = 0; i < 2; ++i)
#pragma unroll
                for (int j = 0; j < 2; ++j)
                    acc[i][j] = __builtin_amdgcn_mfma_f32_16x16x32_bf16(af[i], bfr[j], acc[i][j], 0, 0, 0);
        }
#pragma unroll
        for (int i = 0; i < 2; ++i)
#pragma unroll
            for (int j = 0; j < 2; ++j)
                *(f32x4*)&Ysm[(tb + j * 16 + l15) * 68 + pm + i * 16 + quad * 4] = acc[i][j];
        __syncthreads();
    }

    // gating + partial reduction
    const float Dh = (dir ? bD : fD)[h];
    const float* wvp = dir ? wb2 : wf2;
    float4 wreg = *(const float4*)&wvp[h * 64 + tx * 4];
    const float* cumA = dir ? cumB : cumF;
    const float psi = fwdG ? psiF[h * 32 + c] : 0.f;
    const unsigned short* Ytp = fwdG ? (YtF + (size_t)(c * 16 + h) * 4096)
                                     : (dir ? (YtB + (size_t)(c * 16 + h) * 4096) : nullptr);
    float4 x0v = make_float4(0.f, 0.f, 0.f, 0.f);
    float cbv[4] = {0.f, 0.f, 0.f, 0.f};
    if (dir == 0 && c == 0) {
        x0v = *(const float4*)&convFp[(size_t)(b * 4) * CONVD + h * 64 + tx * 4];
#pragma unroll
        for (int i = 0; i < 4; ++i) cbv[i] = cb0[(b * 16 + h) * 64 + (ty + 16 * i)];
    }
#pragma unroll
    for (int i = 0; i < 4; ++i) {
        int tl = ty + 16 * i;
        int j = 64 * c + tl;
        float et = __expf(cumA[h * 2048 + j]);
        const unsigned short *Yi, *xp, *zp;
        if (dir == 0) {
            Yi = (c == 0) ? YiF0 + (size_t)(b * 16 + h) * 4096 : YiFs + (size_t)(c * 16 + h) * 4096;
            if (c == 0) {
                int t = j + 1;
                xp = (t < 4) ? xFp16 + (size_t)(b * 4 + t) * 1024 : xF16 + (size_t)(t - 4) * 1024;
            } else {
                xp = xF16 + (size_t)(64 * c + tl - 3) * 1024;
            }
            zp = szF + (size_t)j * 1024;
        } else {
            Yi = YiB + (size_t)(c * 16 + h) * 4096;
            xp = xB16 + (size_t)j * 1024;
            zp = szB + (size_t)(2047 - j) * 1024;
        }
        ushort4 yi4 = *(const ushort4*)&Yi[tl * 64 + tx * 4];
        ushort4 x4 = *(const ushort4*)&xp[h * 64 + tx * 4];
        ushort4 z4 = *(const ushort4*)&zp[h * 64 + tx * 4];
        float ya[4] = {0.f, 0.f, 0.f, 0.f};
        if (fwdG) {
            ushort4 yt4 = *(const ushort4*)&Ytp[tl * 64 + tx * 4];
            float4 cm = *(const float4*)&Ysm[tl * 68 + tx * 4];
            ya[0] = bfu(yt4.x) + psi * cm.x;
            ya[1] = bfu(yt4.y) + psi * cm.y;
            ya[2] = bfu(yt4.z) + psi * cm.z;
            ya[3] = bfu(yt4.w) + psi * cm.w;
        } else if (dir == 1) {
            ushort4 yt4 = *(const ushort4*)&Ytp[tl * 64 + tx * 4];
            ya[0] = bfu(yt4.x); ya[1] = bfu(yt4.y); ya[2] = bfu(yt4.z); ya[3] = bfu(yt4.w);
        }
        float yv[4] = {bfu(yi4.x), bfu(yi4.y), bfu(yi4.z), bfu(yi4.w)};
        float xa[4] = {h2f(x4.x), h2f(x4.y), h2f(x4.z), h2f(x4.w)};
        float sza[4] = {h2f(z4.x), h2f(z4.y), h2f(z4.z), h2f(z4.w)};
        float x0a[4] = {x0v.x, x0v.y, x0v.z, x0v.w};
        float wa[4] = {wreg.x, wreg.y, wreg.z, wreg.w};
        float a1 = 0.f, a2 = 0.f;
#pragma unroll
        for (int w = 0; w < 4; ++w) {
            float tot = yv[w] + et * (ya[w] + cbv[i] * x0a[w]) + Dh * xa[w];
            float g = tot * sza[w];
            a1 += g * wa[w];
            a2 += g * g;
        }
#pragma unroll
        for (int m = 1; m < 16; m <<= 1) {
            a1 += __shfl_xor(a1, m);
            a2 += __shfl_xor(a2, m);
        }
        if (tx == 0) {
            if (dir == 0) {
                size_t o = ((size_t)(b * 2048 + j) * 16 + h) * 2;
                aF[o] = a1; aF[o + 1] = a2;
            } else {
                int g = 2047 - j;
                size_t o = ((size_t)g * 16 + h) * 2;
                aB[o] = a1; aB[o + 1] = a2;
            }
        }
    }
}

// ---------------- final combine ----------------

__global__ void final_kernel(const float* __restrict__ aF, const float* __restrict__ aB,
                             const float* __restrict__ headB, float* __restrict__ out) {
    int idx = blockIdx.x * 256 + threadIdx.x;   // 16384
    int b = idx >> 11, g = idx & 2047;
    const float* pf = aF + ((size_t)(b * 2048 + g)) * 32;
    const float* pb = aB + (size_t)g * 32;
    float f1 = 0.f, f2 = 0.f, b1 = 0.f, b2 = 0.f;
#pragma unroll
    for (int h = 0; h < 16; ++h) {
        f1 += pf[2 * h]; f2 += pf[2 * h + 1];
        b1 += pb[2 * h]; b2 += pb[2 * h + 1];
    }
    out[idx] = f1 * rsqrtf(f2 * (1.f / 1024.f) + 1e-5f) +
               b1 * rsqrtf(b2 * (1.f / 1024.f) + 1e-5f) + headB[0];
}

// ---------------- launch ----------------

extern "C" void kernel_launch(void* const* d_in, const int* in_sizes, int n_in,
                              void* d_out, int out_size, void* d_ws, size_t ws_size,
                              hipStream_t stream) {
    const int*   pidx   = (const int*)  d_in[0];
    const int*   chridx = (const int*)  d_in[1];
    const float* locusF = (const float*)d_in[2];
    const float* pathF  = (const float*)d_in[3];
    const float* pertE  = (const float*)d_in[4];
    const float* gidE   = (const float*)d_in[5];
    const float* chrE   = (const float*)d_in[6];
    const float* locusW = (const float*)d_in[7];
    const float* locusB = (const float*)d_in[8];
    const float* condW  = (const float*)d_in[9];
    const float* condB  = (const float*)d_in[10];
    const float* inW    = (const float*)d_in[11];
    const float* inB    = (const float*)d_in[12];
    const float* headW  = (const float*)d_in[13];
    const float* headB  = (const float*)d_in[14];
    const float* fInW   = (const float*)d_in[15];
    const float* fCw    = (const float*)d_in[16];
    const float* fCb    = (const float*)d_in[17];
    const float* fDtB   = (const float*)d_in[18];
    const float* fAlog  = (const float*)d_in[19];
    const float* fDp    = (const float*)d_in[20];
    const float* fNw    = (const float*)d_in[21];
    const float* fOutW  = (const float*)d_in[22];
    const float* bInW   = (const float*)d_in[23];
    const float* bCw    = (const float*)d_in[24];
    const float* bCb    = (const float*)d_in[25];
    const float* bDtB   = (const float*)d_in[26];
    const float* bAlog  = (const float*)d_in[27];
    const float* bDp    = (const float*)d_in[28];
    const float* bNw    = (const float*)d_in[29];
    const float* bOutW  = (const float*)d_in[30];
    float* out = (float*)d_out;
    (void)in_sizes; (void)n_in; (void)out_size; (void)ws_size;

    char* base = (char*)d_ws;
    size_t off = 0;
    auto allocf = [&](size_t n) -> float* {
        char* r = base + off; off += ((n * 4 + 63) & ~(size_t)63); return (float*)r; };
    auto allocu = [&](size_t n) -> unsigned short* {
        char* r = base + off; off += ((n * 2 + 63) & ~(size_t)63); return (unsigned short*)r; };

    float* gf     = allocf(2048UL * 384);
    float* cond   = allocf(8UL * 384);
    float* cemb   = allocf(8UL * 128);
    float* ug     = allocf(2048UL * 512);
    float* uc     = allocf(8UL * 512);
    float* zxf    = allocf(2048UL * DPROJ);
    float* zxb    = allocf(2048UL * DPROJ);
    float* zxc    = allocf(8UL * DPROJ);
    float* convFs = allocf(2045UL * CONVD);
    float* convFp = allocf(8UL * 4 * CONVD);
    float* convBs = allocf(2048UL * CONVD);
    float* dtFs   = allocf(2048UL * 16);
    float* dtFp   = allocf(128);
    float* dtBs   = allocf(2048UL * 16);
    float* cumF   = allocf(16UL * 2048);
    float* cumB   = allocf(16UL * 2048);
    float* wf2    = allocf(1024);
    float* wb2    = allocf(1024);
    float* cb0    = allocf(8UL * 16 * 64);
    float* psiF   = allocf(16UL * 32);
    float* aF     = allocf(8UL * 2048 * 16 * 2);
    float* aB     = allocf(2048UL * 16 * 2);
    unsigned short* YiF0 = allocu(8UL * 16 * 4096);
    unsigned short* YiFs = allocu(32UL * 16 * 4096);
    unsigned short* YiB  = allocu(32UL * 16 * 4096);
    unsigned short* UF0  = allocu(8UL * 16 * 8192);
    unsigned short* UFs  = allocu(32UL * 16 * 8192);
    unsigned short* UB   = allocu(32UL * 16 * 8192);
    unsigned short* Mb   = allocu(8UL * 16 * 8192);
    unsigned short* Tst  = allocu(2UL * 16 * 32 * 8192);
    unsigned short* bcF  = allocu(2045UL * 256);
    unsigned short* bcFp = allocu(32UL * 256);
    unsigned short* bcB  = allocu(2048UL * 256);
    unsigned short* YtF  = allocu(32UL * 16 * 4096);
    unsigned short* YtB  = allocu(32UL * 16 * 4096);
    unsigned short* xF16 = allocu(2045UL * 1024);
    unsigned short* xFp16= allocu(32UL * 1024);
    unsigned short* xB16 = allocu(2048UL * 1024);
    unsigned short* szF  = allocu(2048UL * 1024);
    unsigned short* szB  = allocu(2048UL * 1024);
    unsigned short* gf2   = allocu(2048UL * 384);
    unsigned short* inW2  = allocu(512UL * 384);
    unsigned short* ug2   = allocu(2048UL * 512);
    unsigned short* fInW2 = allocu(2432UL * 512);
    unsigned short* bInW2 = allocu(2432UL * 512);

    gg_kernel<<<3076, 256, 0, stream>>>(chridx, gidE, pathF, chrE, pidx, pertE, gf, cemb);
    wfold_kernel<<<32, 256, 0, stream>>>(headW, fOutW, fNw, bOutW, bNw, wf2, wb2);
    gemm_kernel<<<dim3(1, 32), 256, 0, stream>>>(locusF, locusW, locusB, gf + 320, 2048, 64, 64, 384, 1);
    gemm_kernel<<<dim3(6, 1), 256, 0, stream>>>(cemb, condW, condB, cond, 8, 384, 128, 384, 0);

    tobf4_kernel<<<13568, 256, 0, stream>>>(inW, fInW, bInW, gf, inW2, fInW2, bInW2, gf2);

    mfma_gemm_kernel<<<dim3(4, 16), 256, 0, stream>>>(gf2, inW2, inB, ug, 512, 384, 512);
    gemm_kernel<<<dim3(8, 1), 256, 0, stream>>>(cond, inW, inB, uc, 8, 512, 384, 512, 0);

    tobf_kernel<<<(2048 * 512 + 255) / 256, 256, 0, stream>>>(ug, ug2, 2048, 512, 2048);
    mfma_gemm_kernel<<<dim3(19, 16), 256, 0, stream>>>(ug2, fInW2, nullptr, zxf, 2320, 512, 2320);
    mfma_gemm_kernel<<<dim3(19, 16), 256, 0, stream>>>(ug2, bInW2, nullptr, zxb, 2320, 512, 2320);
    gemm_kernel<<<dim3(37, 1), 256, 0, stream>>>(uc, fInW, nullptr, zxc, 8, DPROJ, 512, DPROJ, 0);

    elem_kernel<<<16640, 256, 0, stream>>>(zxf, zxb, zxc, fDtB, bDtB, szF, szB, dtFs, dtBs, dtFp);
    cum_kernel<<<4, 256, 0, stream>>>(dtFs, dtBs, fAlog, bAlog, cumF, cumB);
    convFsh_kernel<<<(2045 * 1280 + 255) / 256, 256, 0, stream>>>(zxf, fCw, fCb, convFs, bcF, xF16);
    convFpb_kernel<<<160, 256, 0, stream>>>(zxf, zxc, fCw, fCb, convFp, bcFp, xFp16);
    convBsh_kernel<<<10240, 256, 0, stream>>>(zxb, bCw, bCb, convBs, bcB, xB16);
    intra_kernel<<<1136, 256, 0, stream>>>(bcF, bcFp, bcB, convFs, convFp, convBs,
                                           dtFs, dtBs, cumF, cumB,
                                           YiF0, YiFs, YiB, UF0, UFs, UB);
    cbm_kernel<<<160, 256, 0, stream>>>(convFs, convFp, dtFp, cumF, UF0, cb0, Mb);
    tpsi_kernel<<<256, 256, 0, stream>>>(UFs, UB, cumF, cumB, Tst, psiF);
    yt_kernel<<<1008, 256, 0, stream>>>(bcF, bcB, Tst, YtF, YtB);
    gate_kernel<<<4608, 256, 0, stream>>>(bcF, Mb, psiF, YtF, YtB, xF16, xFp16, xB16,
                                          szF, szB, convFp, cumF, cumB,
                                          YiF0, YiFs, YiB, cb0, fDp, bDp, wf2, wb2, aF, aB);
    final_kernel<<<64, 256, 0, stream>>>(aF, aB, headB, out);
}

// Round 7
// 401.288 us; speedup vs baseline: 7.1921x; 1.1100x over previous
//
#include <hip/hip_runtime.h>
#include <hip/hip_bf16.h>
#include <hip/hip_fp16.h>
#include <math.h>

#define DPROJ 2320
#define CONVD 1280

typedef __attribute__((ext_vector_type(8))) short bf16x8;
typedef __attribute__((ext_vector_type(4))) float f32x4;

__device__ __forceinline__ float siluf(float x) { return x / (1.f + __expf(-x)); }
__device__ __forceinline__ float bfu(unsigned short s) { return __uint_as_float(((unsigned)s) << 16); }
__device__ __forceinline__ unsigned short f2bf(float f) {
    unsigned u = __float_as_uint(f);
    unsigned r = (u + 0x7FFFu + ((u >> 16) & 1u)) >> 16;
    return (unsigned short)r;
}
__device__ __forceinline__ unsigned short f2h(float f) {
    __half h = __float2half(f);
    return *(unsigned short*)&h;
}
__device__ __forceinline__ float h2f(unsigned short s) {
    __half h = *(__half*)&s;
    return __half2float(h);
}

// ---------------- fused gather + genefeat + wfold-zero ----------------

__global__ void gg_kernel(const int* __restrict__ chridx, const float* __restrict__ gid,
                          const float* __restrict__ path, const float* __restrict__ chrE,
                          const int* __restrict__ pidx, const float* __restrict__ pertE,
                          float* __restrict__ gf, float* __restrict__ cemb,
                          float* __restrict__ wf2, float* __restrict__ wb2) {
    int blk = blockIdx.x, tid = threadIdx.x;
    if (blk < 3072) {
        int idx = blk * 256 + tid;   // 2048*384
        int g = idx / 384, j = idx % 384;
        float v;
        if (j < 128)      v = gid[(size_t)g * 128 + j];
        else if (j < 256) v = path[(size_t)g * 128 + (j - 128)];
        else if (j < 320) v = chrE[(size_t)chridx[g] * 64 + (j - 256)];
        else return;
        gf[idx] = v;
    } else if (blk < 3076) {
        int idx = (blk - 3072) * 256 + tid;   // 1024
        int b = idx >> 7, k = idx & 127;
        cemb[idx] = pertE[(size_t)pidx[b] * 128 + k];
    } else {
        // zero wf2/wb2 for the atomic wfold
        wf2[tid * 4 + 0] = 0.f; wf2[tid * 4 + 1] = 0.f;
        wf2[tid * 4 + 2] = 0.f; wf2[tid * 4 + 3] = 0.f;
        wb2[tid * 4 + 0] = 0.f; wb2[tid * 4 + 1] = 0.f;
        wb2[tid * 4 + 2] = 0.f; wb2[tid * 4 + 3] = 0.f;
    }
}

// wfold: split-m atomic partial sums. 128 blocks = dir(2) x dseg(4) x mseg(16)
__global__ void wfold_kernel(const float* __restrict__ headW,
                             const float* __restrict__ fOutW, const float* __restrict__ fNw,
                             const float* __restrict__ bOutW, const float* __restrict__ bNw,
                             float* __restrict__ wf2, float* __restrict__ wb2) {
    int blk = blockIdx.x;
    int dir = blk >> 6;
    int rem = blk & 63;
    int dseg = rem >> 4, mseg = rem & 15;
    int tid = threadIdx.x;
    int d = dseg * 256 + tid;
    const float* W = dir ? bOutW : fOutW;
    float s = 0.f;
#pragma unroll
    for (int m = mseg * 32; m < mseg * 32 + 32; ++m)
        s += headW[m] * W[(size_t)m * 1024 + d];
    const float* nw = dir ? bNw : fNw;
    atomicAdd(&(dir ? wb2 : wf2)[d], s * nw[d]);
}

// ---------------- fused bf16 conversions (weights + gf) ----------------

__global__ void tobf4_kernel(const float* __restrict__ inW, const float* __restrict__ fInW,
                             const float* __restrict__ bInW, const float* __restrict__ gf,
                             unsigned short* __restrict__ inW2, unsigned short* __restrict__ fInW2,
                             unsigned short* __restrict__ bInW2, unsigned short* __restrict__ gf2) {
    size_t idx = (size_t)blockIdx.x * 256 + threadIdx.x;
    const size_t A = 512UL * 384, B5 = 2432UL * 512;
    if (idx < A) {
        inW2[idx] = f2bf(inW[idx]);
    } else if (idx < A + B5) {
        size_t k = idx - A; int m = k / 512, kk = k % 512;
        fInW2[k] = f2bf(m < 2320 ? fInW[(size_t)m * 512 + kk] : 0.f);
    } else if (idx < A + 2 * B5) {
        size_t k = idx - A - B5; int m = k / 512, kk = k % 512;
        bInW2[k] = f2bf(m < 2320 ? bInW[(size_t)m * 512 + kk] : 0.f);
    } else {
        size_t k = idx - A - 2 * B5;   // 2048*384
        gf2[k] = f2bf(gf[k]);
    }
}

__global__ void tobf_kernel(const float* __restrict__ in, unsigned short* __restrict__ out,
                            int M, int K, int Mpad) {
    int idx = blockIdx.x * 256 + threadIdx.x;
    if (idx >= Mpad * K) return;
    int m = idx / K, k = idx % K;
    float v = (m < M) ? in[(size_t)m * K + k] : 0.f;
    out[idx] = f2bf(v);
}

// ---------------- MFMA GEMM: C[M x N] = A2[M x K2] . W2[Npad x K2]^T (+bias) ----------------

__global__ __launch_bounds__(256) void mfma_gemm_kernel(
    const unsigned short* __restrict__ A2, const unsigned short* __restrict__ W2,
    const float* __restrict__ bias, float* __restrict__ C,
    int N, int K2, int ldc) {
    __shared__ __align__(16) unsigned short Al[128 * 40];
    __shared__ __align__(16) unsigned short Bl[128 * 40];
    const int tid = threadIdx.x;
    const int bm = blockIdx.y * 128, bn = blockIdx.x * 128;
    const int lane = tid & 63, wave = tid >> 6;
    const int wm = (wave >> 1) * 64, wn = (wave & 1) * 64;
    f32x4 acc[4][4];
#pragma unroll
    for (int i = 0; i < 4; ++i)
#pragma unroll
        for (int j = 0; j < 4; ++j) acc[i][j] = (f32x4){0.f, 0.f, 0.f, 0.f};

    for (int k0 = 0; k0 < K2; k0 += 32) {
        __syncthreads();
#pragma unroll
        for (int s = 0; s < 2; ++s) {
            int ch = tid + 256 * s;
            int row = ch >> 2, q = ch & 3;
            uint4 va = *(const uint4*)&A2[(size_t)(bm + row) * K2 + k0 + q * 8];
            *(uint4*)&Al[row * 40 + q * 8] = va;
            uint4 vb = *(const uint4*)&W2[(size_t)(bn + row) * K2 + k0 + q * 8];
            *(uint4*)&Bl[row * 40 + q * 8] = vb;
        }
        __syncthreads();
        bf16x8 af[4], bfr[4];
#pragma unroll
        for (int i = 0; i < 4; ++i)
            af[i] = *(const bf16x8*)&Al[(wm + i * 16 + (lane & 15)) * 40 + (lane >> 4) * 8];
#pragma unroll
        for (int j = 0; j < 4; ++j)
            bfr[j] = *(const bf16x8*)&Bl[(wn + j * 16 + (lane & 15)) * 40 + (lane >> 4) * 8];
#pragma unroll
        for (int i = 0; i < 4; ++i)
#pragma unroll
            for (int j = 0; j < 4; ++j)
                acc[i][j] = __builtin_amdgcn_mfma_f32_16x16x32_bf16(af[i], bfr[j], acc[i][j], 0, 0, 0);
    }
#pragma unroll
    for (int i = 0; i < 4; ++i) {
        int m = bm + wm + i * 16 + (lane >> 4) * 4;
#pragma unroll
        for (int j = 0; j < 4; ++j) {
            int n = bn + wn + j * 16 + (lane & 15);
            if (n < N) {
                float bv = bias ? bias[n] : 0.f;
#pragma unroll
                for (int r = 0; r < 4; ++r)
                    C[(size_t)(m + r) * ldc + n] = acc[i][j][r] + bv;
            }
        }
    }
}

// ---------------- generic tiled fp32 GEMM (small shapes only) ----------------

__global__ __launch_bounds__(256) void gemm_kernel(
    const float* __restrict__ A, const float* __restrict__ W,
    const float* __restrict__ bias, float* __restrict__ C,
    int M, int N, int K, int ldc, int act) {
    __shared__ __align__(16) float As[16][68];
    __shared__ __align__(16) float Ws[16][68];
    const int tid = threadIdx.x;
    const int tx = tid & 15, ty = tid >> 4;
    const int bm = blockIdx.y * 64, bn = blockIdx.x * 64;
    const int lr = tid >> 2;
    const int lk = (tid & 3) * 4;
    float acc[4][4];
#pragma unroll
    for (int i = 0; i < 4; ++i)
#pragma unroll
        for (int j = 0; j < 4; ++j) acc[i][j] = 0.f;

    for (int k0 = 0; k0 < K; k0 += 16) {
        const int am = bm + lr;
        const int wn = bn + lr;
        float4 av = make_float4(0.f, 0.f, 0.f, 0.f), wv = make_float4(0.f, 0.f, 0.f, 0.f);
        if (am < M) av = *(const float4*)&A[(size_t)am * K + k0 + lk];
        if (wn < N) wv = *(const float4*)&W[(size_t)wn * K + k0 + lk];
        __syncthreads();
        As[lk + 0][lr] = av.x; As[lk + 1][lr] = av.y; As[lk + 2][lr] = av.z; As[lk + 3][lr] = av.w;
        Ws[lk + 0][lr] = wv.x; Ws[lk + 1][lr] = wv.y; Ws[lk + 2][lr] = wv.z; Ws[lk + 3][lr] = wv.w;
        __syncthreads();
#pragma unroll
        for (int kk = 0; kk < 16; ++kk) {
            float4 a = *(const float4*)&As[kk][ty * 4];
            float4 w = *(const float4*)&Ws[kk][tx * 4];
            float aa[4] = {a.x, a.y, a.z, a.w}, ww[4] = {w.x, w.y, w.z, w.w};
#pragma unroll
            for (int i = 0; i < 4; ++i)
#pragma unroll
                for (int j = 0; j < 4; ++j) acc[i][j] += aa[i] * ww[j];
        }
    }
#pragma unroll
    for (int i = 0; i < 4; ++i) {
        const int m = bm + ty * 4 + i;
        if (m >= M) continue;
#pragma unroll
        for (int j = 0; j < 4; ++j) {
            const int n = bn + tx * 4 + j;
            if (n >= N) continue;
            float v = acc[i][j] + (bias ? bias[n] : 0.f);
            if (act == 1) v = 0.5f * v * (1.f + erff(v * 0.70710678118654752f));
            C[(size_t)m * ldc + n] = v;
        }
    }
}

// ---------------- fused elementwise: silu(z) fp16 copies + dt (transposed) ----------------

__global__ void elem_kernel(const float* __restrict__ zxf, const float* __restrict__ zxb,
                            const float* __restrict__ zxc,
                            const float* __restrict__ fDtB, const float* __restrict__ bDtB,
                            unsigned short* __restrict__ szF, unsigned short* __restrict__ szB,
                            float* __restrict__ dtFsT, float* __restrict__ dtBsT,
                            float* __restrict__ dtFp) {
    size_t idx = (size_t)blockIdx.x * 256 + threadIdx.x;
    const size_t SZ = 2048UL * 1024;
    if (idx < SZ) {
        size_t j = idx >> 10, d = idx & 1023;
        szF[idx] = f2h(siluf(zxf[j * DPROJ + d]));
    } else if (idx < 2 * SZ) {
        size_t k = idx - SZ;
        size_t j = k >> 10, d = k & 1023;
        szB[k] = f2h(siluf(zxb[j * DPROJ + d]));
    } else if (idx < 2 * SZ + 32768) {
        int k = (int)(idx - 2 * SZ);
        int r = k >> 4, hh = k & 15;
        float raw = zxf[(size_t)r * DPROJ + 2304 + hh] + fDtB[hh];
        dtFsT[hh * 2048 + r] = (raw > 20.f) ? raw : log1pf(expf(raw));
    } else if (idx < 2 * SZ + 65536) {
        int k = (int)(idx - 2 * SZ - 32768);
        int r = k >> 4, hh = k & 15;
        float raw = zxb[(size_t)(2047 - r) * DPROJ + 2304 + hh] + bDtB[hh];
        dtBsT[hh * 2048 + r] = (raw > 20.f) ? raw : log1pf(expf(raw));
    } else if (idx < 2 * SZ + 65536 + 128) {
        int k = (int)(idx - 2 * SZ - 65536);
        int b = k >> 4, hh = k & 15;
        float raw = zxc[(size_t)b * DPROJ + 2304 + hh] + fDtB[hh];
        dtFp[k] = (raw > 20.f) ? raw : log1pf(expf(raw));
    }
}

// chunk-local inclusive cumsum of ldA = -dt*exp(A_log), transposed input
__global__ void cum_kernel(const float* __restrict__ dtFsT, const float* __restrict__ dtBsT,
                           const float* __restrict__ fAlog, const float* __restrict__ bAlog,
                           float* __restrict__ cumF, float* __restrict__ cumB) {
    int id = blockIdx.x * 256 + threadIdx.x;   // 1024
    int dir = id >> 9, k = id & 511, h = k >> 5, c = k & 31;
    const float* dtT = dir ? dtBsT : dtFsT;
    const float* Al = dir ? bAlog : fAlog;
    float* cum = dir ? cumB : cumF;
    float a = -expf(Al[h]);
    float acc = 0.f;
    for (int s4 = 0; s4 < 16; ++s4) {
        float4 v = *(const float4*)&dtT[h * 2048 + c * 64 + s4 * 4];
        float4 o;
        acc += v.x * a; o.x = acc;
        acc += v.y * a; o.y = acc;
        acc += v.z * a; o.z = acc;
        acc += v.w * a; o.w = acc;
        *(float4*)&cum[h * 2048 + c * 64 + s4 * 4] = o;
    }
}

// ---------------- causal depthwise conv (+SiLU), with bf16 B/C and fp16 x side-copies ----------------

__global__ void convFsh_kernel(const float* __restrict__ zxf, const float* __restrict__ cw,
                               const float* __restrict__ cb, float* __restrict__ outp,
                               unsigned short* __restrict__ bc16, unsigned short* __restrict__ x16) {
    int idx = blockIdx.x * 256 + threadIdx.x;
    if (idx >= 2045 * 1280) return;
    int t4 = idx / 1280, c = idx % 1280;
    float4 w4 = *(const float4*)&cw[c * 4];
    float acc = cb[c];
    acc += zxf[(size_t)(t4 + 0) * DPROJ + 1024 + c] * w4.x;
    acc += zxf[(size_t)(t4 + 1) * DPROJ + 1024 + c] * w4.y;
    acc += zxf[(size_t)(t4 + 2) * DPROJ + 1024 + c] * w4.z;
    acc += zxf[(size_t)(t4 + 3) * DPROJ + 1024 + c] * w4.w;
    float r = siluf(acc);
    outp[idx] = r;
    if (c >= 1024) bc16[(size_t)t4 * 256 + (c - 1024)] = f2bf(r);
    else           x16[(size_t)t4 * 1024 + c] = f2h(r);
}

__global__ void convFpb_kernel(const float* __restrict__ zxf, const float* __restrict__ zxc,
                               const float* __restrict__ cw, const float* __restrict__ cb,
                               float* __restrict__ outp, unsigned short* __restrict__ bc16,
                               unsigned short* __restrict__ x16) {
    int idx = blockIdx.x * 256 + threadIdx.x;   // 8*4*1280
    int b = idx / 5120;
    int r = idx % 5120;
    int t = r / 1280, c = r % 1280;
    float4 w4 = *(const float4*)&cw[c * 4];
    float w[4] = {w4.x, w4.y, w4.z, w4.w};
    float acc = cb[c];
#pragma unroll
    for (int k = 0; k < 4; ++k) {
        int j = t - 3 + k;
        float x = 0.f;
        if (j == 0)      x = zxc[(size_t)b * DPROJ + 1024 + c];
        else if (j >= 1) x = zxf[(size_t)(j - 1) * DPROJ + 1024 + c];
        acc += x * w[k];
    }
    float rr = siluf(acc);
    outp[idx] = rr;
    if (c >= 1024) bc16[(size_t)(b * 4 + t) * 256 + (c - 1024)] = f2bf(rr);
    else           x16[(size_t)(b * 4 + t) * 1024 + c] = f2h(rr);
}

__global__ void convBsh_kernel(const float* __restrict__ zxb, const float* __restrict__ cw,
                               const float* __restrict__ cb, float* __restrict__ outp,
                               unsigned short* __restrict__ bc16, unsigned short* __restrict__ x16) {
    int idx = blockIdx.x * 256 + threadIdx.x;   // 2048*1280
    int s = idx / 1280, c = idx % 1280;
    float4 w4 = *(const float4*)&cw[c * 4];
    float w[4] = {w4.x, w4.y, w4.z, w4.w};
    float acc = cb[c];
#pragma unroll
    for (int k = 0; k < 4; ++k) {
        int j = s - 3 + k;
        if (j >= 0) acc += zxb[(size_t)(2047 - j) * DPROJ + 1024 + c] * w[k];
    }
    float r = siluf(acc);
    outp[idx] = r;
    if (c >= 1024) bc16[(size_t)s * 256 + (c - 1024)] = f2bf(r);
    else           x16[(size_t)s * 1024 + c] = f2h(r);
}

// ---------------- intra-chunk kernel (MFMA) ----------------

__global__ __launch_bounds__(256) void intra_kernel(
    const unsigned short* __restrict__ bcF, const unsigned short* __restrict__ bcFp,
    const unsigned short* __restrict__ bcB,
    const float* __restrict__ convFs, const float* __restrict__ convFp,
    const float* __restrict__ convBs,
    const float* __restrict__ dtFsT, const float* __restrict__ dtBsT,
    const float* __restrict__ cumF, const float* __restrict__ cumB,
    unsigned short* __restrict__ YiF0, unsigned short* __restrict__ YiFs,
    unsigned short* __restrict__ YiB,
    unsigned short* __restrict__ UF0, unsigned short* __restrict__ UFs,
    unsigned short* __restrict__ UB) {
    __shared__ __align__(16) unsigned char smraw[63232];
    unsigned short* Bt = (unsigned short*)smraw;                    // 64 x 136  [s][n]
    unsigned short* Ct = (unsigned short*)(smraw + 17408);          // 64 x 136  [t][n]
    unsigned short* Sm = (unsigned short*)(smraw + 17408);          // 64 x 72   [t][s] (alias Ct)
    unsigned short* BT = (unsigned short*)(smraw + 34816);          // 128 x 72  [n][s]
    unsigned short* XT = (unsigned short*)(smraw + 53248);          // 64 x 72   [p][s]
    float* scum = (float*)(smraw + 62464);                          // 64
    float* sdt  = scum + 64;                                        // 64
    float* se   = scum + 128;                                       // 64

    const int iid = blockIdx.x;
    int dir, b = 0, h, c;
    unsigned short *Yout, *Uout;
    if (iid < 128)      { dir = 0; b = iid >> 4; h = iid & 15; c = 0;
                          Yout = YiF0 + (size_t)(b * 16 + h) * 4096; Uout = UF0 + (size_t)(b * 16 + h) * 8192; }
    else if (iid < 624) { int k = iid - 128; dir = 0; c = 1 + (k >> 4); h = k & 15;
                          Yout = YiFs + (size_t)(c * 16 + h) * 4096; Uout = UFs + (size_t)(c * 16 + h) * 8192; }
    else                { int k = iid - 624; dir = 1; c = k >> 4; h = k & 15;
                          Yout = YiB + (size_t)(c * 16 + h) * 4096;  Uout = UB + (size_t)(c * 16 + h) * 8192; }
    const float* dtAT = dir ? dtBsT : dtFsT;
    const float* cumA = dir ? cumB : cumF;

    const int tid = threadIdx.x;
    const int lane = tid & 63, wave = tid >> 6;
    const int quad = lane >> 4, l15 = lane & 15;

    {
        int r = tid >> 2, q = tid & 3;
        const unsigned short* bsrc;
        const float* xrow;
        if (dir == 0) {
            int t = 64 * c + 1 + r;
            if (t < 4) { bsrc = bcFp + (size_t)(b * 4 + t) * 256; xrow = convFp + (size_t)(b * 4 + t) * CONVD; }
            else       { bsrc = bcF + (size_t)(t - 4) * 256;      xrow = convFs + (size_t)(t - 4) * CONVD; }
        } else {
            int s = 64 * c + r;
            bsrc = bcB + (size_t)s * 256;
            xrow = convBs + (size_t)s * CONVD;
        }
#pragma unroll
        for (int i = 0; i < 4; ++i) {
            int n0 = q * 32 + i * 8;
            uint4 v = *(const uint4*)&bsrc[n0];
            *(uint4*)&Bt[r * 136 + n0] = v;
            const unsigned short* pv = (const unsigned short*)&v;
#pragma unroll
            for (int jj = 0; jj < 8; ++jj) BT[(n0 + jj) * 72 + r] = pv[jj];
        }
#pragma unroll
        for (int i = 0; i < 4; ++i) {
            int n0 = q * 32 + i * 8;
            uint4 v = *(const uint4*)&bsrc[128 + n0];
            *(uint4*)&Ct[r * 136 + n0] = v;
        }
#pragma unroll
        for (int i = 0; i < 4; ++i) {
            int p0 = (q + 4 * i) * 4;
            float4 v = *(const float4*)&xrow[h * 64 + p0];
            XT[(p0 + 0) * 72 + r] = f2bf(v.x);
            XT[(p0 + 1) * 72 + r] = f2bf(v.y);
            XT[(p0 + 2) * 72 + r] = f2bf(v.z);
            XT[(p0 + 3) * 72 + r] = f2bf(v.w);
        }
        if (tid < 64) {
            int j = 64 * c + tid;
            scum[tid] = cumA[h * 2048 + j];
            sdt[tid] = dtAT[h * 2048 + j];
        }
    }
    __syncthreads();
    if (tid < 64) se[tid] = __expf(scum[63] - scum[tid]) * sdt[tid];

    // phase 1: G = C . B^T
    const int tm = (wave >> 1) * 32, sn = (wave & 1) * 32;
    f32x4 acc1[2][2];
#pragma unroll
    for (int i = 0; i < 2; ++i)
#pragma unroll
        for (int j = 0; j < 2; ++j) acc1[i][j] = (f32x4){0.f, 0.f, 0.f, 0.f};
#pragma unroll
    for (int ks = 0; ks < 4; ++ks) {
        bf16x8 af[2], bfr[2];
#pragma unroll
        for (int i = 0; i < 2; ++i)
            af[i] = *(const bf16x8*)&Ct[(tm + i * 16 + l15) * 136 + ks * 32 + quad * 8];
#pragma unroll
        for (int j = 0; j < 2; ++j)
            bfr[j] = *(const bf16x8*)&Bt[(sn + j * 16 + l15) * 136 + ks * 32 + quad * 8];
#pragma unroll
        for (int i = 0; i < 2; ++i)
#pragma unroll
            for (int j = 0; j < 2; ++j)
                acc1[i][j] = __builtin_amdgcn_mfma_f32_16x16x32_bf16(af[i], bfr[j], acc1[i][j], 0, 0, 0);
    }
    __syncthreads();

#pragma unroll
    for (int j = 0; j < 2; ++j) {
        int s = sn + j * 16 + l15;
        float cs = scum[s], ds = sdt[s];
#pragma unroll
        for (int i = 0; i < 2; ++i) {
#pragma unroll
            for (int r = 0; r < 4; ++r) {
                int t = tm + i * 16 + quad * 4 + r;
                float v = (s <= t) ? __expf(scum[t] - cs) * ds * acc1[i][j][r] : 0.f;
                Sm[t * 72 + s] = f2bf(v);
            }
        }
    }
    __syncthreads();

    // phase 2 (swapped): A = X^T rows p, B = Sm rows t -> D[p][t]
    const int pm = (wave >> 1) * 32, tn = (wave & 1) * 32;
    f32x4 acc2[2][2];
#pragma unroll
    for (int i = 0; i < 2; ++i)
#pragma unroll
        for (int j = 0; j < 2; ++j) acc2[i][j] = (f32x4){0.f, 0.f, 0.f, 0.f};
#pragma unroll
    for (int ks = 0; ks < 2; ++ks) {
        bf16x8 af[2], bfr[2];
#pragma unroll
        for (int i = 0; i < 2; ++i)
            af[i] = *(const bf16x8*)&XT[(pm + i * 16 + l15) * 72 + ks * 32 + quad * 8];
#pragma unroll
        for (int j = 0; j < 2; ++j)
            bfr[j] = *(const bf16x8*)&Sm[(tn + j * 16 + l15) * 72 + ks * 32 + quad * 8];
#pragma unroll
        for (int i = 0; i < 2; ++i)
#pragma unroll
            for (int j = 0; j < 2; ++j)
                acc2[i][j] = __builtin_amdgcn_mfma_f32_16x16x32_bf16(af[i], bfr[j], acc2[i][j], 0, 0, 0);
    }
#pragma unroll
    for (int i = 0; i < 2; ++i)
#pragma unroll
        for (int j = 0; j < 2; ++j) {
            int t = tn + j * 16 + l15;
            int p0 = pm + i * 16 + quad * 4;
            ushort4 o = make_ushort4(f2bf(acc2[i][j][0]), f2bf(acc2[i][j][1]),
                                     f2bf(acc2[i][j][2]), f2bf(acc2[i][j][3]));
            *(ushort4*)&Yout[t * 64 + p0] = o;
        }

    // phase 3: U = B^T . (e*X) -> write U[p][n]
    const int nm = wave * 32;
    f32x4 acc3[2][4];
#pragma unroll
    for (int i = 0; i < 2; ++i)
#pragma unroll
        for (int j = 0; j < 4; ++j) acc3[i][j] = (f32x4){0.f, 0.f, 0.f, 0.f};
#pragma unroll
    for (int ks = 0; ks < 2; ++ks) {
        float ev[8];
#pragma unroll
        for (int jj = 0; jj < 8; ++jj) ev[jj] = se[ks * 32 + quad * 8 + jj];
        bf16x8 bfx[4];
#pragma unroll
        for (int j = 0; j < 4; ++j) {
            bf16x8 xs = *(const bf16x8*)&XT[(j * 16 + l15) * 72 + ks * 32 + quad * 8];
#pragma unroll
            for (int jj = 0; jj < 8; ++jj)
                bfx[j][jj] = (short)f2bf(bfu((unsigned short)xs[jj]) * ev[jj]);
        }
        bf16x8 af[2];
#pragma unroll
        for (int i = 0; i < 2; ++i)
            af[i] = *(const bf16x8*)&BT[(nm + i * 16 + l15) * 72 + ks * 32 + quad * 8];
#pragma unroll
        for (int i = 0; i < 2; ++i)
#pragma unroll
            for (int j = 0; j < 4; ++j)
                acc3[i][j] = __builtin_amdgcn_mfma_f32_16x16x32_bf16(af[i], bfx[j], acc3[i][j], 0, 0, 0);
    }
#pragma unroll
    for (int i = 0; i < 2; ++i)
#pragma unroll
        for (int j = 0; j < 4; ++j) {
            int p = j * 16 + l15;
            int n0 = nm + i * 16 + quad * 4;
            ushort4 o = make_ushort4(f2bf(acc3[i][j][0]), f2bf(acc3[i][j][1]),
                                     f2bf(acc3[i][j][2]), f2bf(acc3[i][j][3]));
            *(ushort4*)&Uout[p * 128 + n0] = o;
        }
}

// ---------------- fused cb0 + M ----------------

__global__ void cbm_kernel(const float* __restrict__ convFs, const float* __restrict__ convFp,
                           const float* __restrict__ dtFp, const float* __restrict__ cumF,
                           const unsigned short* __restrict__ UF0,
                           float* __restrict__ cb0, unsigned short* __restrict__ Mb) {
    int blk = blockIdx.x, tid = threadIdx.x;   // 160
    if (blk < 32) {
        int idx = blk * 256 + tid;   // 8192
        int b = idx >> 10, r = idx & 1023, h = r >> 6, tl = r & 63;
        int t = tl + 1;
        const float* crow = (t < 4) ? convFp + (size_t)(b * 4 + t) * CONVD : convFs + (size_t)(t - 4) * CONVD;
        const float* b0 = convFp + (size_t)(b * 4) * CONVD;
        float s = 0.f;
        for (int n = 0; n < 128; ++n) s += crow[1152 + n] * b0[1024 + n];
        cb0[(b * 16 + h) * 64 + tl] = s * dtFp[b * 16 + h];
    } else {
        int bh = blk - 32;   // 128
        int b = bh >> 4, h = bh & 15;
        float D0 = __expf(cumF[h * 2048 + 63]);
        float dt0 = dtFp[b * 16 + h];
        const float* row0 = convFp + (size_t)(b * 4) * CONVD;
        const unsigned short* u = UF0 + (size_t)(b * 16 + h) * 8192;
        unsigned short* m = Mb + (size_t)(b * 16 + h) * 8192;
        for (int e4 = tid; e4 < 2048; e4 += 256) {
            int e = e4 * 4, p = e >> 7, n0 = e & 127;
            float s = D0 * dt0 * row0[h * 64 + p];
            float4 B4 = *(const float4*)&row0[1024 + n0];
            ushort4 uv = *(const ushort4*)&u[e];
            ushort4 o = make_ushort4(f2bf(s * B4.x + bfu(uv.x)), f2bf(s * B4.y + bfu(uv.y)),
                                     f2bf(s * B4.z + bfu(uv.z)), f2bf(s * B4.w + bfu(uv.w)));
            *(ushort4*)&m[e] = o;
        }
    }
}

// ---------------- shared chunk-state scan: T_c, psi_c ----------------

__global__ void tpsi_kernel(const unsigned short* __restrict__ UFs, const unsigned short* __restrict__ UB,
                            const float* __restrict__ cumF, const float* __restrict__ cumB,
                            unsigned short* __restrict__ Tst, float* __restrict__ psiF) {
    int blk = blockIdx.x;   // 256: dir*128 + h*8 + q8
    int dir = blk >> 7, h = (blk >> 3) & 15, q8 = blk & 7;
    int tid = threadIdx.x;
    const unsigned short* U = dir ? UB : UFs;
    const float* cum = dir ? cumB : cumF;
    unsigned short* T = Tst + (size_t)(dir * 16 + h) * 32 * 8192;
    if (dir == 0 && q8 == 0 && tid == 0) {
        float ps = 1.f;
        for (int c = 1; c < 32; ++c) {
            psiF[h * 32 + c] = ps;
            ps *= __expf(cumF[h * 2048 + c * 64 + 63]);
        }
    }
    const size_t e = (size_t)q8 * 1024 + 4 * tid;
    float4 st = make_float4(0.f, 0.f, 0.f, 0.f);
    const int c0 = dir ? 0 : 1;
    ushort4 u = *(const ushort4*)&U[((size_t)c0 * 16 + h) * 8192 + e];
    for (int c = c0; c < 32; ++c) {
        ushort4 un = make_ushort4(0, 0, 0, 0);
        if (c + 1 < 32) un = *(const ushort4*)&U[((size_t)(c + 1) * 16 + h) * 8192 + e];
        float Dc = __expf(cum[h * 2048 + c * 64 + 63]);
        ushort4 o = make_ushort4(f2bf(st.x), f2bf(st.y), f2bf(st.z), f2bf(st.w));
        *(ushort4*)&T[(size_t)c * 8192 + e] = o;
        st.x = Dc * st.x + bfu(u.x);
        st.y = Dc * st.y + bfu(u.y);
        st.z = Dc * st.z + bfu(u.z);
        st.w = Dc * st.w + bfu(u.w);
        u = un;
    }
}

// ---------------- batch-shared Yt = C . T^T ----------------

__global__ __launch_bounds__(256) void yt_kernel(
    const unsigned short* __restrict__ bcF, const unsigned short* __restrict__ bcB,
    const unsigned short* __restrict__ Tst,
    unsigned short* __restrict__ YtF, unsigned short* __restrict__ YtB) {
    const int iid = blockIdx.x;   // 1008
    int dir, h, c;
    if (iid < 496) { dir = 0; c = 1 + (iid >> 4); h = iid & 15; }
    else           { int k = iid - 496; dir = 1; c = k >> 4; h = k & 15; }
    const unsigned short* Cbase = (dir == 0)
        ? bcF + ((size_t)(64 * c - 3)) * 256 + 128
        : bcB + ((size_t)(64 * c)) * 256 + 128;
    const unsigned short* Tp = Tst + ((size_t)(dir * 16 + h) * 32 + c) * 8192;
    unsigned short* Yt = (dir == 0 ? YtF : YtB) + (size_t)(c * 16 + h) * 4096;
    const int tid = threadIdx.x;
    const int lane = tid & 63, wave = tid >> 6;
    const int quad = lane >> 4, l15 = lane & 15;
    const int pm = (wave >> 1) * 32, tb = (wave & 1) * 32;
    f32x4 acc[2][2];
#pragma unroll
    for (int i = 0; i < 2; ++i)
#pragma unroll
        for (int j = 0; j < 2; ++j) acc[i][j] = (f32x4){0.f, 0.f, 0.f, 0.f};
#pragma unroll
    for (int ks = 0; ks < 4; ++ks) {
        bf16x8 af[2], bfr[2];
#pragma unroll
        for (int i = 0; i < 2; ++i)
            af[i] = *(const bf16x8*)&Tp[(size_t)(pm + i * 16 + l15) * 128 + ks * 32 + quad * 8];
#pragma unroll
        for (int j = 0; j < 2; ++j)
            bfr[j] = *(const bf16x8*)&Cbase[(size_t)(tb + j * 16 + l15) * 256 + ks * 32 + quad * 8];
#pragma unroll
        for (int i = 0; i < 2; ++i)
#pragma unroll
            for (int j = 0; j < 2; ++j)
                acc[i][j] = __builtin_amdgcn_mfma_f32_16x16x32_bf16(af[i], bfr[j], acc[i][j], 0, 0, 0);
    }
#pragma unroll
    for (int i = 0; i < 2; ++i)
#pragma unroll
        for (int j = 0; j < 2; ++j) {
            int t = tb + j * 16 + l15;
            int p0 = pm + i * 16 + quad * 4;
            ushort4 o = make_ushort4(f2bf(acc[i][j][0]), f2bf(acc[i][j][1]),
                                     f2bf(acc[i][j][2]), f2bf(acc[i][j][3]));
            *(ushort4*)&Yt[t * 64 + p0] = o;
        }
}

// ---------------- gate kernel: per-batch cm GEMM + batched-load epilogue ----------------

__global__ __launch_bounds__(256, 4) void gate_kernel(
    const unsigned short* __restrict__ bcF,
    const unsigned short* __restrict__ Mb, const float* __restrict__ psiF,
    const unsigned short* __restrict__ YtF, const unsigned short* __restrict__ YtB,
    const unsigned short* __restrict__ xF16, const unsigned short* __restrict__ xFp16,
    const unsigned short* __restrict__ xB16,
    const unsigned short* __restrict__ szF, const unsigned short* __restrict__ szB,
    const float* __restrict__ convFp,
    const float* __restrict__ cumF, const float* __restrict__ cumB,
    const unsigned short* __restrict__ YiF0, const unsigned short* __restrict__ YiFs,
    const unsigned short* __restrict__ YiB,
    const float* __restrict__ cb0,
    const float* __restrict__ fD, const float* __restrict__ bD,
    const float* __restrict__ wf2, const float* __restrict__ wb2,
    float* __restrict__ aF, float* __restrict__ aB) {
    __shared__ __align__(16) float Ysm[64 * 68];

    const int iid = blockIdx.x;
    int dir, b = 0, h, c;
    if (iid < 4096) { dir = 0; b = iid >> 9; int r = iid & 511; h = r >> 5; c = r & 31; }
    else            { int k = iid - 4096; dir = 1; h = k >> 5; c = k & 31; }
    const int tid = threadIdx.x, tx = tid & 15, ty = tid >> 4;
    const int lane = tid & 63, wave = tid >> 6;
    const int quad = lane >> 4, l15 = lane & 15;
    const bool fwdG = (dir == 0 && c > 0);

    if (fwdG) {
        const unsigned short* Cbase = bcF + ((size_t)(64 * c - 3)) * 256 + 128;
        const unsigned short* Mp = Mb + (size_t)(b * 16 + h) * 8192;
        const int pm = (wave >> 1) * 32, tb = (wave & 1) * 32;
        f32x4 acc[2][2];
#pragma unroll
        for (int i = 0; i < 2; ++i)
#pragma unroll
            for (int j = 0; j < 2; ++j) acc[i][j] = (f32x4){0.f, 0.f, 0.f, 0.f};
#pragma unroll
        for (int ks = 0; ks < 4; ++ks) {
            bf16x8 af[2], bfr[2];
#pragma unroll
            for (int i = 0; i < 2; ++i)
                af[i] = *(const bf16x8*)&Mp[(size_t)(pm + i * 16 + l15) * 128 + ks * 32 + quad * 8];
#pragma unroll
            for (int j = 0; j < 2; ++j)
                bfr[j] = *(const bf16x8*)&Cbase[(size_t)(tb + j * 16 + l15) * 256 + ks * 32 + quad * 8];
#pragma unroll
            for (int i = 0; i < 2; ++i)
#pragma unroll
                for (int j = 0; j < 2; ++j)
                    acc[i][j] = __builtin_amdgcn_mfma_f32_16x16x32_bf16(af[i], bfr[j], acc[i][j], 0, 0, 0);
        }
#pragma unroll
        for (int i = 0; i < 2; ++i)
#pragma unroll
            for (int j = 0; j < 2; ++j)
                *(f32x4*)&Ysm[(tb + j * 16 + l15) * 68 + pm + i * 16 + quad * 4] = acc[i][j];
        __syncthreads();
    }

    const float Dh = (dir ? bD : fD)[h];
    const float* wvp = dir ? wb2 : wf2;
    float4 wreg = *(const float4*)&wvp[h * 64 + tx * 4];
    const float* cumA = dir ? cumB : cumF;
    const float psi = fwdG ? psiF[h * 32 + c] : 0.f;
    const unsigned short* Ytp = fwdG ? (YtF + (size_t)(c * 16 + h) * 4096)
                                     : (dir ? (YtB + (size_t)(c * 16 + h) * 4096) : nullptr);
    float4 x0v = make_float4(0.f, 0.f, 0.f, 0.f);
    float cbv[4] = {0.f, 0.f, 0.f, 0.f};
    if (dir == 0 && c == 0) {
        x0v = *(const float4*)&convFp[(size_t)(b * 4) * CONVD + h * 64 + tx * 4];
#pragma unroll
        for (int i = 0; i < 4; ++i) cbv[i] = cb0[(b * 16 + h) * 64 + (ty + 16 * i)];
    }

    // batched loads: issue everything before any use
    float rawet[4];
    ushort4 yi4a[4], x4a[4], z4a[4], yt4a[4];
    float4 cm4a[4];
#pragma unroll
    for (int i = 0; i < 4; ++i) {
        int tl = ty + 16 * i;
        int j = 64 * c + tl;
        rawet[i] = cumA[h * 2048 + j];
        const unsigned short *Yi, *xp, *zp;
        if (dir == 0) {
            Yi = (c == 0) ? YiF0 + (size_t)(b * 16 + h) * 4096 : YiFs + (size_t)(c * 16 + h) * 4096;
            if (c == 0) {
                int t = j + 1;
                xp = (t < 4) ? xFp16 + (size_t)(b * 4 + t) * 1024 : xF16 + (size_t)(t - 4) * 1024;
            } else {
                xp = xF16 + (size_t)(64 * c + tl - 3) * 1024;
            }
            zp = szF + (size_t)j * 1024;
        } else {
            Yi = YiB + (size_t)(c * 16 + h) * 4096;
            xp = xB16 + (size_t)j * 1024;
            zp = szB + (size_t)(2047 - j) * 1024;
        }
        yi4a[i] = *(const ushort4*)&Yi[tl * 64 + tx * 4];
        x4a[i] = *(const ushort4*)&xp[h * 64 + tx * 4];
        z4a[i] = *(const ushort4*)&zp[h * 64 + tx * 4];
        yt4a[i] = Ytp ? *(const ushort4*)&Ytp[tl * 64 + tx * 4] : make_ushort4(0, 0, 0, 0);
        cm4a[i] = fwdG ? *(const float4*)&Ysm[tl * 68 + tx * 4] : make_float4(0.f, 0.f, 0.f, 0.f);
    }

#pragma unroll
    for (int i = 0; i < 4; ++i) {
        int j = 64 * c + ty + 16 * i;
        float et = __expf(rawet[i]);
        float yv[4] = {bfu(yi4a[i].x), bfu(yi4a[i].y), bfu(yi4a[i].z), bfu(yi4a[i].w)};
        float xa[4] = {h2f(x4a[i].x), h2f(x4a[i].y), h2f(x4a[i].z), h2f(x4a[i].w)};
        float sza[4] = {h2f(z4a[i].x), h2f(z4a[i].y), h2f(z4a[i].z), h2f(z4a[i].w)};
        float ya[4] = {bfu(yt4a[i].x) + psi * cm4a[i].x, bfu(yt4a[i].y) + psi * cm4a[i].y,
                       bfu(yt4a[i].z) + psi * cm4a[i].z, bfu(yt4a[i].w) + psi * cm4a[i].w};
        float x0a[4] = {x0v.x, x0v.y, x0v.z, x0v.w};
        float wa[4] = {wreg.x, wreg.y, wreg.z, wreg.w};
        float a1 = 0.f, a2 = 0.f;
#pragma unroll
        for (int w = 0; w < 4; ++w) {
            float tot = yv[w] + et * (ya[w] + cbv[i] * x0a[w]) + Dh * xa[w];
            float g = tot * sza[w];
            a1 += g * wa[w];
            a2 += g * g;
        }
#pragma unroll
        for (int m = 1; m < 16; m <<= 1) {
            a1 += __shfl_xor(a1, m);
            a2 += __shfl_xor(a2, m);
        }
        if (tx == 0) {
            if (dir == 0) {
                size_t o = ((size_t)(b * 2048 + j) * 16 + h) * 2;
                aF[o] = a1; aF[o + 1] = a2;
            } else {
                int g = 2047 - j;
                size_t o = ((size_t)g * 16 + h) * 2;
                aB[o] = a1; aB[o + 1] = a2;
            }
        }
    }
}

// ---------------- final combine ----------------

__global__ void final_kernel(const float* __restrict__ aF, const float* __restrict__ aB,
                             const float* __restrict__ headB, float* __restrict__ out) {
    int idx = blockIdx.x * 256 + threadIdx.x;   // 16384
    int b = idx >> 11, g = idx & 2047;
    const float* pf = aF + ((size_t)(b * 2048 + g)) * 32;
    const float* pb = aB + (size_t)g * 32;
    float f1 = 0.f, f2 = 0.f, b1 = 0.f, b2 = 0.f;
#pragma unroll
    for (int h = 0; h < 16; ++h) {
        f1 += pf[2 * h]; f2 += pf[2 * h + 1];
        b1 += pb[2 * h]; b2 += pb[2 * h + 1];
    }
    out[idx] = f1 * rsqrtf(f2 * (1.f / 1024.f) + 1e-5f) +
               b1 * rsqrtf(b2 * (1.f / 1024.f) + 1e-5f) + headB[0];
}

// ---------------- launch ----------------

extern "C" void kernel_launch(void* const* d_in, const int* in_sizes, int n_in,
                              void* d_out, int out_size, void* d_ws, size_t ws_size,
                              hipStream_t stream) {
    const int*   pidx   = (const int*)  d_in[0];
    const int*   chridx = (const int*)  d_in[1];
    const float* locusF = (const float*)d_in[2];
    const float* pathF  = (const float*)d_in[3];
    const float* pertE  = (const float*)d_in[4];
    const float* gidE   = (const float*)d_in[5];
    const float* chrE   = (const float*)d_in[6];
    const float* locusW = (const float*)d_in[7];
    const float* locusB = (const float*)d_in[8];
    const float* condW  = (const float*)d_in[9];
    const float* condB  = (const float*)d_in[10];
    const float* inW    = (const float*)d_in[11];
    const float* inB    = (const float*)d_in[12];
    const float* headW  = (const float*)d_in[13];
    const float* headB  = (const float*)d_in[14];
    const float* fInW   = (const float*)d_in[15];
    const float* fCw    = (const float*)d_in[16];
    const float* fCb    = (const float*)d_in[17];
    const float* fDtB   = (const float*)d_in[18];
    const float* fAlog  = (const float*)d_in[19];
    const float* fDp    = (const float*)d_in[20];
    const float* fNw    = (const float*)d_in[21];
    const float* fOutW  = (const float*)d_in[22];
    const float* bInW   = (const float*)d_in[23];
    const float* bCw    = (const float*)d_in[24];
    const float* bCb    = (const float*)d_in[25];
    const float* bDtB   = (const float*)d_in[26];
    const float* bAlog  = (const float*)d_in[27];
    const float* bDp    = (const float*)d_in[28];
    const float* bNw    = (const float*)d_in[29];
    const float* bOutW  = (const float*)d_in[30];
    float* out = (float*)d_out;
    (void)in_sizes; (void)n_in; (void)out_size; (void)ws_size;

    char* base = (char*)d_ws;
    size_t off = 0;
    auto allocf = [&](size_t n) -> float* {
        char* r = base + off; off += ((n * 4 + 63) & ~(size_t)63); return (float*)r; };
    auto allocu = [&](size_t n) -> unsigned short* {
        char* r = base + off; off += ((n * 2 + 63) & ~(size_t)63); return (unsigned short*)r; };

    float* gf     = allocf(2048UL * 384);
    float* cond   = allocf(8UL * 384);
    float* cemb   = allocf(8UL * 128);
    float* ug     = allocf(2048UL * 512);
    float* uc     = allocf(8UL * 512);
    float* zxf    = allocf(2048UL * DPROJ);
    float* zxb    = allocf(2048UL * DPROJ);
    float* zxc    = allocf(8UL * DPROJ);
    float* convFs = allocf(2045UL * CONVD);
    float* convFp = allocf(8UL * 4 * CONVD);
    float* convBs = allocf(2048UL * CONVD);
    float* dtFsT  = allocf(16UL * 2048);
    float* dtFp   = allocf(128);
    float* dtBsT  = allocf(16UL * 2048);
    float* cumF   = allocf(16UL * 2048);
    float* cumB   = allocf(16UL * 2048);
    float* wf2    = allocf(1024);
    float* wb2    = allocf(1024);
    float* cb0    = allocf(8UL * 16 * 64);
    float* psiF   = allocf(16UL * 32);
    float* aF     = allocf(8UL * 2048 * 16 * 2);
    float* aB     = allocf(2048UL * 16 * 2);
    unsigned short* YiF0 = allocu(8UL * 16 * 4096);
    unsigned short* YiFs = allocu(32UL * 16 * 4096);
    unsigned short* YiB  = allocu(32UL * 16 * 4096);
    unsigned short* UF0  = allocu(8UL * 16 * 8192);
    unsigned short* UFs  = allocu(32UL * 16 * 8192);
    unsigned short* UB   = allocu(32UL * 16 * 8192);
    unsigned short* Mb   = allocu(8UL * 16 * 8192);
    unsigned short* Tst  = allocu(2UL * 16 * 32 * 8192);
    unsigned short* bcF  = allocu(2045UL * 256);
    unsigned short* bcFp = allocu(32UL * 256);
    unsigned short* bcB  = allocu(2048UL * 256);
    unsigned short* YtF  = allocu(32UL * 16 * 4096);
    unsigned short* YtB  = allocu(32UL * 16 * 4096);
    unsigned short* xF16 = allocu(2045UL * 1024);
    unsigned short* xFp16= allocu(32UL * 1024);
    unsigned short* xB16 = allocu(2048UL * 1024);
    unsigned short* szF  = allocu(2048UL * 1024);
    unsigned short* szB  = allocu(2048UL * 1024);
    unsigned short* gf2   = allocu(2048UL * 384);
    unsigned short* inW2  = allocu(512UL * 384);
    unsigned short* ug2   = allocu(2048UL * 512);
    unsigned short* fInW2 = allocu(2432UL * 512);
    unsigned short* bInW2 = allocu(2432UL * 512);

    gg_kernel<<<3077, 256, 0, stream>>>(chridx, gidE, pathF, chrE, pidx, pertE, gf, cemb, wf2, wb2);
    wfold_kernel<<<128, 256, 0, stream>>>(headW, fOutW, fNw, bOutW, bNw, wf2, wb2);
    gemm_kernel<<<dim3(1, 32), 256, 0, stream>>>(locusF, locusW, locusB, gf + 320, 2048, 64, 64, 384, 1);
    gemm_kernel<<<dim3(6, 1), 256, 0, stream>>>(cemb, condW, condB, cond, 8, 384, 128, 384, 0);

    tobf4_kernel<<<13568, 256, 0, stream>>>(inW, fInW, bInW, gf, inW2, fInW2, bInW2, gf2);

    mfma_gemm_kernel<<<dim3(4, 16), 256, 0, stream>>>(gf2, inW2, inB, ug, 512, 384, 512);
    gemm_kernel<<<dim3(8, 1), 256, 0, stream>>>(cond, inW, inB, uc, 8, 512, 384, 512, 0);

    tobf_kernel<<<(2048 * 512 + 255) / 256, 256, 0, stream>>>(ug, ug2, 2048, 512, 2048);
    mfma_gemm_kernel<<<dim3(19, 16), 256, 0, stream>>>(ug2, fInW2, nullptr, zxf, 2320, 512, 2320);
    mfma_gemm_kernel<<<dim3(19, 16), 256, 0, stream>>>(ug2, bInW2, nullptr, zxb, 2320, 512, 2320);
    gemm_kernel<<<dim3(37, 1), 256, 0, stream>>>(uc, fInW, nullptr, zxc, 8, DPROJ, 512, DPROJ, 0);

    elem_kernel<<<16641, 256, 0, stream>>>(zxf, zxb, zxc, fDtB, bDtB, szF, szB, dtFsT, dtBsT, dtFp);
    cum_kernel<<<4, 256, 0, stream>>>(dtFsT, dtBsT, fAlog, bAlog, cumF, cumB);
    convFsh_kernel<<<(2045 * 1280 + 255) / 256, 256, 0, stream>>>(zxf, fCw, fCb, convFs, bcF, xF16);
    convFpb_kernel<<<160, 256, 0, stream>>>(zxf, zxc, fCw, fCb, convFp, bcFp, xFp16);
    convBsh_kernel<<<10240, 256, 0, stream>>>(zxb, bCw, bCb, convBs, bcB, xB16);
    intra_kernel<<<1136, 256, 0, stream>>>(bcF, bcFp, bcB, convFs, convFp, convBs,
                                           dtFsT, dtBsT, cumF, cumB,
                                           YiF0, YiFs, YiB, UF0, UFs, UB);
    cbm_kernel<<<160, 256, 0, stream>>>(convFs, convFp, dtFp, cumF, UF0, cb0, Mb);
    tpsi_kernel<<<256, 256, 0, stream>>>(UFs, UB, cumF, cumB, Tst, psiF);
    yt_kernel<<<1008, 256, 0, stream>>>(bcF, bcB, Tst, YtF, YtB);
    gate_kernel<<<4608, 256, 0, stream>>>(bcF, Mb, psiF, YtF, YtB, xF16, xFp16, xB16,
                                          szF, szB, convFp, cumF, cumB,
                                          YiF0, YiFs, YiB, cb0, fDp, bDp, wf2, wb2, aF, aB);
    final_kernel<<<64, 256, 0, stream>>>(aF, aB, headB, out);
}

// Round 8
// 398.430 us; speedup vs baseline: 7.2437x; 1.0072x over previous
//
#include <hip/hip_runtime.h>
#include <hip/hip_bf16.h>
#include <hip/hip_fp16.h>
#include <math.h>

#define DPROJ 2320
#define CONVD 1280

typedef __attribute__((ext_vector_type(8))) short bf16x8;
typedef __attribute__((ext_vector_type(4))) float f32x4;

__device__ __forceinline__ float siluf(float x) { return x / (1.f + __expf(-x)); }
__device__ __forceinline__ float bfu(unsigned short s) { return __uint_as_float(((unsigned)s) << 16); }
__device__ __forceinline__ unsigned short f2bf(float f) {
    unsigned u = __float_as_uint(f);
    unsigned r = (u + 0x7FFFu + ((u >> 16) & 1u)) >> 16;
    return (unsigned short)r;
}
__device__ __forceinline__ unsigned short f2h(float f) {
    __half h = __float2half(f);
    return *(unsigned short*)&h;
}
__device__ __forceinline__ float h2f(unsigned short s) {
    __half h = *(__half*)&s;
    return __half2float(h);
}

// ---------------- fused gather + genefeat + wfold-zero ----------------

__global__ void gg_kernel(const int* __restrict__ chridx, const float* __restrict__ gid,
                          const float* __restrict__ path, const float* __restrict__ chrE,
                          const int* __restrict__ pidx, const float* __restrict__ pertE,
                          float* __restrict__ gf, float* __restrict__ cemb,
                          float* __restrict__ wf2, float* __restrict__ wb2) {
    int blk = blockIdx.x, tid = threadIdx.x;
    if (blk < 3072) {
        int idx = blk * 256 + tid;   // 2048*384
        int g = idx / 384, j = idx % 384;
        float v;
        if (j < 128)      v = gid[(size_t)g * 128 + j];
        else if (j < 256) v = path[(size_t)g * 128 + (j - 128)];
        else if (j < 320) v = chrE[(size_t)chridx[g] * 64 + (j - 256)];
        else return;
        gf[idx] = v;
    } else if (blk < 3076) {
        int idx = (blk - 3072) * 256 + tid;   // 1024
        int b = idx >> 7, k = idx & 127;
        cemb[idx] = pertE[(size_t)pidx[b] * 128 + k];
    } else {
        wf2[tid * 4 + 0] = 0.f; wf2[tid * 4 + 1] = 0.f;
        wf2[tid * 4 + 2] = 0.f; wf2[tid * 4 + 3] = 0.f;
        wb2[tid * 4 + 0] = 0.f; wb2[tid * 4 + 1] = 0.f;
        wb2[tid * 4 + 2] = 0.f; wb2[tid * 4 + 3] = 0.f;
    }
}

// wfold: split-m atomic partial sums. 128 blocks = dir(2) x dseg(4) x mseg(16)
__global__ void wfold_kernel(const float* __restrict__ headW,
                             const float* __restrict__ fOutW, const float* __restrict__ fNw,
                             const float* __restrict__ bOutW, const float* __restrict__ bNw,
                             float* __restrict__ wf2, float* __restrict__ wb2) {
    int blk = blockIdx.x;
    int dir = blk >> 6;
    int rem = blk & 63;
    int dseg = rem >> 4, mseg = rem & 15;
    int tid = threadIdx.x;
    int d = dseg * 256 + tid;
    const float* W = dir ? bOutW : fOutW;
    float s = 0.f;
#pragma unroll
    for (int m = mseg * 32; m < mseg * 32 + 32; ++m)
        s += headW[m] * W[(size_t)m * 1024 + d];
    const float* nw = dir ? bNw : fNw;
    atomicAdd(&(dir ? wb2 : wf2)[d], s * nw[d]);
}

// ---------------- fused bf16 conversions (weights + gf) ----------------

__global__ void tobf4_kernel(const float* __restrict__ inW, const float* __restrict__ fInW,
                             const float* __restrict__ bInW, const float* __restrict__ gf,
                             unsigned short* __restrict__ inW2, unsigned short* __restrict__ fInW2,
                             unsigned short* __restrict__ bInW2, unsigned short* __restrict__ gf2) {
    size_t idx = (size_t)blockIdx.x * 256 + threadIdx.x;
    const size_t A = 512UL * 384, B5 = 2432UL * 512;
    if (idx < A) {
        inW2[idx] = f2bf(inW[idx]);
    } else if (idx < A + B5) {
        size_t k = idx - A; int m = k / 512, kk = k % 512;
        fInW2[k] = f2bf(m < 2320 ? fInW[(size_t)m * 512 + kk] : 0.f);
    } else if (idx < A + 2 * B5) {
        size_t k = idx - A - B5; int m = k / 512, kk = k % 512;
        bInW2[k] = f2bf(m < 2320 ? bInW[(size_t)m * 512 + kk] : 0.f);
    } else {
        size_t k = idx - A - 2 * B5;   // 2048*384
        gf2[k] = f2bf(gf[k]);
    }
}

__global__ void tobf_kernel(const float* __restrict__ in, unsigned short* __restrict__ out,
                            int M, int K, int Mpad) {
    int idx = blockIdx.x * 256 + threadIdx.x;
    if (idx >= Mpad * K) return;
    int m = idx / K, k = idx % K;
    float v = (m < M) ? in[(size_t)m * K + k] : 0.f;
    out[idx] = f2bf(v);
}

// ---------------- MFMA GEMM: C[M x N] = A2[M x K2] . W2[Npad x K2]^T (+bias) ----------------

__global__ __launch_bounds__(256) void mfma_gemm_kernel(
    const unsigned short* __restrict__ A2, const unsigned short* __restrict__ W2,
    const float* __restrict__ bias, float* __restrict__ C,
    int N, int K2, int ldc) {
    __shared__ __align__(16) unsigned short Al[128 * 40];
    __shared__ __align__(16) unsigned short Bl[128 * 40];
    const int tid = threadIdx.x;
    const int bm = blockIdx.y * 128, bn = blockIdx.x * 128;
    const int lane = tid & 63, wave = tid >> 6;
    const int wm = (wave >> 1) * 64, wn = (wave & 1) * 64;
    f32x4 acc[4][4];
#pragma unroll
    for (int i = 0; i < 4; ++i)
#pragma unroll
        for (int j = 0; j < 4; ++j) acc[i][j] = (f32x4){0.f, 0.f, 0.f, 0.f};

    for (int k0 = 0; k0 < K2; k0 += 32) {
        __syncthreads();
#pragma unroll
        for (int s = 0; s < 2; ++s) {
            int ch = tid + 256 * s;
            int row = ch >> 2, q = ch & 3;
            uint4 va = *(const uint4*)&A2[(size_t)(bm + row) * K2 + k0 + q * 8];
            *(uint4*)&Al[row * 40 + q * 8] = va;
            uint4 vb = *(const uint4*)&W2[(size_t)(bn + row) * K2 + k0 + q * 8];
            *(uint4*)&Bl[row * 40 + q * 8] = vb;
        }
        __syncthreads();
        bf16x8 af[4], bfr[4];
#pragma unroll
        for (int i = 0; i < 4; ++i)
            af[i] = *(const bf16x8*)&Al[(wm + i * 16 + (lane & 15)) * 40 + (lane >> 4) * 8];
#pragma unroll
        for (int j = 0; j < 4; ++j)
            bfr[j] = *(const bf16x8*)&Bl[(wn + j * 16 + (lane & 15)) * 40 + (lane >> 4) * 8];
#pragma unroll
        for (int i = 0; i < 4; ++i)
#pragma unroll
            for (int j = 0; j < 4; ++j)
                acc[i][j] = __builtin_amdgcn_mfma_f32_16x16x32_bf16(af[i], bfr[j], acc[i][j], 0, 0, 0);
    }
#pragma unroll
    for (int i = 0; i < 4; ++i) {
        int m = bm + wm + i * 16 + (lane >> 4) * 4;
#pragma unroll
        for (int j = 0; j < 4; ++j) {
            int n = bn + wn + j * 16 + (lane & 15);
            if (n < N) {
                float bv = bias ? bias[n] : 0.f;
#pragma unroll
                for (int r = 0; r < 4; ++r)
                    C[(size_t)(m + r) * ldc + n] = acc[i][j][r] + bv;
            }
        }
    }
}

// ---------------- generic tiled fp32 GEMM (small shapes only) ----------------

__global__ __launch_bounds__(256) void gemm_kernel(
    const float* __restrict__ A, const float* __restrict__ W,
    const float* __restrict__ bias, float* __restrict__ C,
    int M, int N, int K, int ldc, int act) {
    __shared__ __align__(16) float As[16][68];
    __shared__ __align__(16) float Ws[16][68];
    const int tid = threadIdx.x;
    const int tx = tid & 15, ty = tid >> 4;
    const int bm = blockIdx.y * 64, bn = blockIdx.x * 64;
    const int lr = tid >> 2;
    const int lk = (tid & 3) * 4;
    float acc[4][4];
#pragma unroll
    for (int i = 0; i < 4; ++i)
#pragma unroll
        for (int j = 0; j < 4; ++j) acc[i][j] = 0.f;

    for (int k0 = 0; k0 < K; k0 += 16) {
        const int am = bm + lr;
        const int wn = bn + lr;
        float4 av = make_float4(0.f, 0.f, 0.f, 0.f), wv = make_float4(0.f, 0.f, 0.f, 0.f);
        if (am < M) av = *(const float4*)&A[(size_t)am * K + k0 + lk];
        if (wn < N) wv = *(const float4*)&W[(size_t)wn * K + k0 + lk];
        __syncthreads();
        As[lk + 0][lr] = av.x; As[lk + 1][lr] = av.y; As[lk + 2][lr] = av.z; As[lk + 3][lr] = av.w;
        Ws[lk + 0][lr] = wv.x; Ws[lk + 1][lr] = wv.y; Ws[lk + 2][lr] = wv.z; Ws[lk + 3][lr] = wv.w;
        __syncthreads();
#pragma unroll
        for (int kk = 0; kk < 16; ++kk) {
            float4 a = *(const float4*)&As[kk][ty * 4];
            float4 w = *(const float4*)&Ws[kk][tx * 4];
            float aa[4] = {a.x, a.y, a.z, a.w}, ww[4] = {w.x, w.y, w.z, w.w};
#pragma unroll
            for (int i = 0; i < 4; ++i)
#pragma unroll
                for (int j = 0; j < 4; ++j) acc[i][j] += aa[i] * ww[j];
        }
    }
#pragma unroll
    for (int i = 0; i < 4; ++i) {
        const int m = bm + ty * 4 + i;
        if (m >= M) continue;
#pragma unroll
        for (int j = 0; j < 4; ++j) {
            const int n = bn + tx * 4 + j;
            if (n >= N) continue;
            float v = acc[i][j] + (bias ? bias[n] : 0.f);
            if (act == 1) v = 0.5f * v * (1.f + erff(v * 0.70710678118654752f));
            C[(size_t)m * ldc + n] = v;
        }
    }
}

// ---------------- fused elementwise: silu(z) fp16 copies + dt (transposed) ----------------

__global__ void elem_kernel(const float* __restrict__ zxf, const float* __restrict__ zxb,
                            const float* __restrict__ zxc,
                            const float* __restrict__ fDtB, const float* __restrict__ bDtB,
                            unsigned short* __restrict__ szF, unsigned short* __restrict__ szB,
                            float* __restrict__ dtFsT, float* __restrict__ dtBsT,
                            float* __restrict__ dtFp) {
    size_t idx = (size_t)blockIdx.x * 256 + threadIdx.x;
    const size_t SZ = 2048UL * 1024;
    if (idx < SZ) {
        size_t j = idx >> 10, d = idx & 1023;
        szF[idx] = f2h(siluf(zxf[j * DPROJ + d]));
    } else if (idx < 2 * SZ) {
        size_t k = idx - SZ;
        size_t j = k >> 10, d = k & 1023;
        szB[k] = f2h(siluf(zxb[j * DPROJ + d]));
    } else if (idx < 2 * SZ + 32768) {
        int k = (int)(idx - 2 * SZ);
        int r = k >> 4, hh = k & 15;
        float raw = zxf[(size_t)r * DPROJ + 2304 + hh] + fDtB[hh];
        dtFsT[hh * 2048 + r] = (raw > 20.f) ? raw : log1pf(expf(raw));
    } else if (idx < 2 * SZ + 65536) {
        int k = (int)(idx - 2 * SZ - 32768);
        int r = k >> 4, hh = k & 15;
        float raw = zxb[(size_t)(2047 - r) * DPROJ + 2304 + hh] + bDtB[hh];
        dtBsT[hh * 2048 + r] = (raw > 20.f) ? raw : log1pf(expf(raw));
    } else if (idx < 2 * SZ + 65536 + 128) {
        int k = (int)(idx - 2 * SZ - 65536);
        int b = k >> 4, hh = k & 15;
        float raw = zxc[(size_t)b * DPROJ + 2304 + hh] + fDtB[hh];
        dtFp[k] = (raw > 20.f) ? raw : log1pf(expf(raw));
    }
}

// chunk-local inclusive cumsum of ldA = -dt*exp(A_log), transposed input
__global__ void cum_kernel(const float* __restrict__ dtFsT, const float* __restrict__ dtBsT,
                           const float* __restrict__ fAlog, const float* __restrict__ bAlog,
                           float* __restrict__ cumF, float* __restrict__ cumB) {
    int id = blockIdx.x * 256 + threadIdx.x;   // 1024
    int dir = id >> 9, k = id & 511, h = k >> 5, c = k & 31;
    const float* dtT = dir ? dtBsT : dtFsT;
    const float* Al = dir ? bAlog : fAlog;
    float* cum = dir ? cumB : cumF;
    float a = -expf(Al[h]);
    float acc = 0.f;
    for (int s4 = 0; s4 < 16; ++s4) {
        float4 v = *(const float4*)&dtT[h * 2048 + c * 64 + s4 * 4];
        float4 o;
        acc += v.x * a; o.x = acc;
        acc += v.y * a; o.y = acc;
        acc += v.z * a; o.z = acc;
        acc += v.w * a; o.w = acc;
        *(float4*)&cum[h * 2048 + c * 64 + s4 * 4] = o;
    }
}

// ---------------- causal depthwise conv (+SiLU): bf16 B/C + bf16 x side-copies only ----------------

__global__ void convFsh_kernel(const float* __restrict__ zxf, const float* __restrict__ cw,
                               const float* __restrict__ cb,
                               unsigned short* __restrict__ bc16, unsigned short* __restrict__ x16) {
    int idx = blockIdx.x * 256 + threadIdx.x;
    if (idx >= 2045 * 1280) return;
    int t4 = idx / 1280, c = idx % 1280;
    float4 w4 = *(const float4*)&cw[c * 4];
    float acc = cb[c];
    acc += zxf[(size_t)(t4 + 0) * DPROJ + 1024 + c] * w4.x;
    acc += zxf[(size_t)(t4 + 1) * DPROJ + 1024 + c] * w4.y;
    acc += zxf[(size_t)(t4 + 2) * DPROJ + 1024 + c] * w4.z;
    acc += zxf[(size_t)(t4 + 3) * DPROJ + 1024 + c] * w4.w;
    float r = siluf(acc);
    if (c >= 1024) bc16[(size_t)t4 * 256 + (c - 1024)] = f2bf(r);
    else           x16[(size_t)t4 * 1024 + c] = f2bf(r);
}

__global__ void convFpb_kernel(const float* __restrict__ zxf, const float* __restrict__ zxc,
                               const float* __restrict__ cw, const float* __restrict__ cb,
                               float* __restrict__ outp, unsigned short* __restrict__ bc16,
                               unsigned short* __restrict__ x16) {
    int idx = blockIdx.x * 256 + threadIdx.x;   // 8*4*1280
    int b = idx / 5120;
    int r = idx % 5120;
    int t = r / 1280, c = r % 1280;
    float4 w4 = *(const float4*)&cw[c * 4];
    float w[4] = {w4.x, w4.y, w4.z, w4.w};
    float acc = cb[c];
#pragma unroll
    for (int k = 0; k < 4; ++k) {
        int j = t - 3 + k;
        float x = 0.f;
        if (j == 0)      x = zxc[(size_t)b * DPROJ + 1024 + c];
        else if (j >= 1) x = zxf[(size_t)(j - 1) * DPROJ + 1024 + c];
        acc += x * w[k];
    }
    float rr = siluf(acc);
    outp[idx] = rr;   // fp32 kept: x0v, cbm rank-1 path
    if (c >= 1024) bc16[(size_t)(b * 4 + t) * 256 + (c - 1024)] = f2bf(rr);
    else           x16[(size_t)(b * 4 + t) * 1024 + c] = f2bf(rr);
}

__global__ void convBsh_kernel(const float* __restrict__ zxb, const float* __restrict__ cw,
                               const float* __restrict__ cb,
                               unsigned short* __restrict__ bc16, unsigned short* __restrict__ x16) {
    int idx = blockIdx.x * 256 + threadIdx.x;   // 2048*1280
    int s = idx / 1280, c = idx % 1280;
    float4 w4 = *(const float4*)&cw[c * 4];
    float w[4] = {w4.x, w4.y, w4.z, w4.w};
    float acc = cb[c];
#pragma unroll
    for (int k = 0; k < 4; ++k) {
        int j = s - 3 + k;
        if (j >= 0) acc += zxb[(size_t)(2047 - j) * DPROJ + 1024 + c] * w[k];
    }
    float r = siluf(acc);
    if (c >= 1024) bc16[(size_t)s * 256 + (c - 1024)] = f2bf(r);
    else           x16[(size_t)s * 1024 + c] = f2bf(r);
}

// ---------------- intra-chunk kernel (MFMA) ----------------

__global__ __launch_bounds__(256) void intra_kernel(
    const unsigned short* __restrict__ bcF, const unsigned short* __restrict__ bcFp,
    const unsigned short* __restrict__ bcB,
    const unsigned short* __restrict__ xF16, const unsigned short* __restrict__ xFp16,
    const unsigned short* __restrict__ xB16,
    const float* __restrict__ dtFsT, const float* __restrict__ dtBsT,
    const float* __restrict__ cumF, const float* __restrict__ cumB,
    unsigned short* __restrict__ YiF0, unsigned short* __restrict__ YiFs,
    unsigned short* __restrict__ YiB,
    unsigned short* __restrict__ UF0, unsigned short* __restrict__ UFs,
    unsigned short* __restrict__ UB) {
    __shared__ __align__(16) unsigned char smraw[63232];
    unsigned short* Bt = (unsigned short*)smraw;                    // 64 x 136  [s][n]
    unsigned short* Ct = (unsigned short*)(smraw + 17408);          // 64 x 136  [t][n]
    unsigned short* Sm = (unsigned short*)(smraw + 17408);          // 64 x 72   [t][s] (alias Ct)
    unsigned short* BT = (unsigned short*)(smraw + 34816);          // 128 x 72  [n][s]
    unsigned short* XT = (unsigned short*)(smraw + 53248);          // 64 x 72   [p][s]
    float* scum = (float*)(smraw + 62464);                          // 64
    float* sdt  = scum + 64;                                        // 64
    float* se   = scum + 128;                                       // 64

    const int iid = blockIdx.x;
    int dir, b = 0, h, c;
    unsigned short *Yout, *Uout;
    if (iid < 128)      { dir = 0; b = iid >> 4; h = iid & 15; c = 0;
                          Yout = YiF0 + (size_t)(b * 16 + h) * 4096; Uout = UF0 + (size_t)(b * 16 + h) * 8192; }
    else if (iid < 624) { int k = iid - 128; dir = 0; c = 1 + (k >> 4); h = k & 15;
                          Yout = YiFs + (size_t)(c * 16 + h) * 4096; Uout = UFs + (size_t)(c * 16 + h) * 8192; }
    else                { int k = iid - 624; dir = 1; c = k >> 4; h = k & 15;
                          Yout = YiB + (size_t)(c * 16 + h) * 4096;  Uout = UB + (size_t)(c * 16 + h) * 8192; }
    const float* dtAT = dir ? dtBsT : dtFsT;
    const float* cumA = dir ? cumB : cumF;

    const int tid = threadIdx.x;
    const int lane = tid & 63, wave = tid >> 6;
    const int quad = lane >> 4, l15 = lane & 15;

    {
        int r = tid >> 2, q = tid & 3;
        const unsigned short *bsrc, *xsrc;
        if (dir == 0) {
            int t = 64 * c + 1 + r;
            if (t < 4) { bsrc = bcFp + (size_t)(b * 4 + t) * 256; xsrc = xFp16 + (size_t)(b * 4 + t) * 1024; }
            else       { bsrc = bcF + (size_t)(t - 4) * 256;      xsrc = xF16 + (size_t)(t - 4) * 1024; }
        } else {
            int s = 64 * c + r;
            bsrc = bcB + (size_t)s * 256;
            xsrc = xB16 + (size_t)s * 1024;
        }
#pragma unroll
        for (int i = 0; i < 4; ++i) {
            int n0 = q * 32 + i * 8;
            uint4 v = *(const uint4*)&bsrc[n0];
            *(uint4*)&Bt[r * 136 + n0] = v;
            const unsigned short* pv = (const unsigned short*)&v;
#pragma unroll
            for (int jj = 0; jj < 8; ++jj) BT[(n0 + jj) * 72 + r] = pv[jj];
        }
#pragma unroll
        for (int i = 0; i < 4; ++i) {
            int n0 = q * 32 + i * 8;
            uint4 v = *(const uint4*)&bsrc[128 + n0];
            *(uint4*)&Ct[r * 136 + n0] = v;
        }
#pragma unroll
        for (int k = 0; k < 2; ++k) {
            uint4 v = *(const uint4*)&xsrc[h * 64 + q * 16 + k * 8];
            const unsigned short* pv = (const unsigned short*)&v;
#pragma unroll
            for (int jj = 0; jj < 8; ++jj) XT[(q * 16 + k * 8 + jj) * 72 + r] = pv[jj];
        }
        if (tid < 64) {
            int j = 64 * c + tid;
            scum[tid] = cumA[h * 2048 + j];
            sdt[tid] = dtAT[h * 2048 + j];
        }
    }
    __syncthreads();
    if (tid < 64) se[tid] = __expf(scum[63] - scum[tid]) * sdt[tid];

    // phase 1: G = C . B^T
    const int tm = (wave >> 1) * 32, sn = (wave & 1) * 32;
    f32x4 acc1[2][2];
#pragma unroll
    for (int i = 0; i < 2; ++i)
#pragma unroll
        for (int j = 0; j < 2; ++j) acc1[i][j] = (f32x4){0.f, 0.f, 0.f, 0.f};
#pragma unroll
    for (int ks = 0; ks < 4; ++ks) {
        bf16x8 af[2], bfr[2];
#pragma unroll
        for (int i = 0; i < 2; ++i)
            af[i] = *(const bf16x8*)&Ct[(tm + i * 16 + l15) * 136 + ks * 32 + quad * 8];
#pragma unroll
        for (int j = 0; j < 2; ++j)
            bfr[j] = *(const bf16x8*)&Bt[(sn + j * 16 + l15) * 136 + ks * 32 + quad * 8];
#pragma unroll
        for (int i = 0; i < 2; ++i)
#pragma unroll
            for (int j = 0; j < 2; ++j)
                acc1[i][j] = __builtin_amdgcn_mfma_f32_16x16x32_bf16(af[i], bfr[j], acc1[i][j], 0, 0, 0);
    }
    __syncthreads();

#pragma unroll
    for (int j = 0; j < 2; ++j) {
        int s = sn + j * 16 + l15;
        float cs = scum[s], ds = sdt[s];
#pragma unroll
        for (int i = 0; i < 2; ++i) {
#pragma unroll
            for (int r = 0; r < 4; ++r) {
                int t = tm + i * 16 + quad * 4 + r;
                float v = (s <= t) ? __expf(scum[t] - cs) * ds * acc1[i][j][r] : 0.f;
                Sm[t * 72 + s] = f2bf(v);
            }
        }
    }
    __syncthreads();

    // phase 2 (swapped): A = X^T rows p, B = Sm rows t -> D[p][t]
    const int pm = (wave >> 1) * 32, tn = (wave & 1) * 32;
    f32x4 acc2[2][2];
#pragma unroll
    for (int i = 0; i < 2; ++i)
#pragma unroll
        for (int j = 0; j < 2; ++j) acc2[i][j] = (f32x4){0.f, 0.f, 0.f, 0.f};
#pragma unroll
    for (int ks = 0; ks < 2; ++ks) {
        bf16x8 af[2], bfr[2];
#pragma unroll
        for (int i = 0; i < 2; ++i)
            af[i] = *(const bf16x8*)&XT[(pm + i * 16 + l15) * 72 + ks * 32 + quad * 8];
#pragma unroll
        for (int j = 0; j < 2; ++j)
            bfr[j] = *(const bf16x8*)&Sm[(tn + j * 16 + l15) * 72 + ks * 32 + quad * 8];
#pragma unroll
        for (int i = 0; i < 2; ++i)
#pragma unroll
            for (int j = 0; j < 2; ++j)
                acc2[i][j] = __builtin_amdgcn_mfma_f32_16x16x32_bf16(af[i], bfr[j], acc2[i][j], 0, 0, 0);
    }
#pragma unroll
    for (int i = 0; i < 2; ++i)
#pragma unroll
        for (int j = 0; j < 2; ++j) {
            int t = tn + j * 16 + l15;
            int p0 = pm + i * 16 + quad * 4;
            ushort4 o = make_ushort4(f2bf(acc2[i][j][0]), f2bf(acc2[i][j][1]),
                                     f2bf(acc2[i][j][2]), f2bf(acc2[i][j][3]));
            *(ushort4*)&Yout[t * 64 + p0] = o;
        }

    // phase 3: U = B^T . (e*X) -> write U[p][n]
    const int nm = wave * 32;
    f32x4 acc3[2][4];
#pragma unroll
    for (int i = 0; i < 2; ++i)
#pragma unroll
        for (int j = 0; j < 4; ++j) acc3[i][j] = (f32x4){0.f, 0.f, 0.f, 0.f};
#pragma unroll
    for (int ks = 0; ks < 2; ++ks) {
        float ev[8];
#pragma unroll
        for (int jj = 0; jj < 8; ++jj) ev[jj] = se[ks * 32 + quad * 8 + jj];
        bf16x8 bfx[4];
#pragma unroll
        for (int j = 0; j < 4; ++j) {
            bf16x8 xs = *(const bf16x8*)&XT[(j * 16 + l15) * 72 + ks * 32 + quad * 8];
#pragma unroll
            for (int jj = 0; jj < 8; ++jj)
                bfx[j][jj] = (short)f2bf(bfu((unsigned short)xs[jj]) * ev[jj]);
        }
        bf16x8 af[2];
#pragma unroll
        for (int i = 0; i < 2; ++i)
            af[i] = *(const bf16x8*)&BT[(nm + i * 16 + l15) * 72 + ks * 32 + quad * 8];
#pragma unroll
        for (int i = 0; i < 2; ++i)
#pragma unroll
            for (int j = 0; j < 4; ++j)
                acc3[i][j] = __builtin_amdgcn_mfma_f32_16x16x32_bf16(af[i], bfx[j], acc3[i][j], 0, 0, 0);
    }
#pragma unroll
    for (int i = 0; i < 2; ++i)
#pragma unroll
        for (int j = 0; j < 4; ++j) {
            int p = j * 16 + l15;
            int n0 = nm + i * 16 + quad * 4;
            ushort4 o = make_ushort4(f2bf(acc3[i][j][0]), f2bf(acc3[i][j][1]),
                                     f2bf(acc3[i][j][2]), f2bf(acc3[i][j][3]));
            *(ushort4*)&Uout[p * 128 + n0] = o;
        }
}

// ---------------- fused cb0 + M ----------------

__global__ void cbm_kernel(const float* __restrict__ convFp, const unsigned short* __restrict__ bcF,
                           const float* __restrict__ dtFp, const float* __restrict__ cumF,
                           const unsigned short* __restrict__ UF0,
                           float* __restrict__ cb0, unsigned short* __restrict__ Mb) {
    int blk = blockIdx.x, tid = threadIdx.x;   // 160
    if (blk < 32) {
        int idx = blk * 256 + tid;   // 8192
        int b = idx >> 10, r = idx & 1023, h = r >> 6, tl = r & 63;
        int t = tl + 1;
        const float* b0 = convFp + (size_t)(b * 4) * CONVD;
        float s = 0.f;
        if (t < 4) {
            const float* crow = convFp + (size_t)(b * 4 + t) * CONVD;
            for (int n = 0; n < 128; ++n) s += crow[1152 + n] * b0[1024 + n];
        } else {
            const unsigned short* cr = bcF + (size_t)(t - 4) * 256 + 128;
            for (int n = 0; n < 128; ++n) s += bfu(cr[n]) * b0[1024 + n];
        }
        cb0[(b * 16 + h) * 64 + tl] = s * dtFp[b * 16 + h];
    } else {
        int bh = blk - 32;   // 128
        int b = bh >> 4, h = bh & 15;
        float D0 = __expf(cumF[h * 2048 + 63]);
        float dt0 = dtFp[b * 16 + h];
        const float* row0 = convFp + (size_t)(b * 4) * CONVD;
        const unsigned short* u = UF0 + (size_t)(b * 16 + h) * 8192;
        unsigned short* m = Mb + (size_t)(b * 16 + h) * 8192;
        for (int e4 = tid; e4 < 2048; e4 += 256) {
            int e = e4 * 4, p = e >> 7, n0 = e & 127;
            float s = D0 * dt0 * row0[h * 64 + p];
            float4 B4 = *(const float4*)&row0[1024 + n0];
            ushort4 uv = *(const ushort4*)&u[e];
            ushort4 o = make_ushort4(f2bf(s * B4.x + bfu(uv.x)), f2bf(s * B4.y + bfu(uv.y)),
                                     f2bf(s * B4.z + bfu(uv.z)), f2bf(s * B4.w + bfu(uv.w)));
            *(ushort4*)&m[e] = o;
        }
    }
}

// ---------------- shared chunk-state scan: T_c, psi_c ----------------

__global__ void tpsi_kernel(const unsigned short* __restrict__ UFs, const unsigned short* __restrict__ UB,
                            const float* __restrict__ cumF, const float* __restrict__ cumB,
                            unsigned short* __restrict__ Tst, float* __restrict__ psiF) {
    int blk = blockIdx.x;   // 256: dir*128 + h*8 + q8
    int dir = blk >> 7, h = (blk >> 3) & 15, q8 = blk & 7;
    int tid = threadIdx.x;
    const unsigned short* U = dir ? UB : UFs;
    const float* cum = dir ? cumB : cumF;
    unsigned short* T = Tst + (size_t)(dir * 16 + h) * 32 * 8192;
    if (dir == 0 && q8 == 0 && tid == 0) {
        float ps = 1.f;
        for (int c = 1; c < 32; ++c) {
            psiF[h * 32 + c] = ps;
            ps *= __expf(cumF[h * 2048 + c * 64 + 63]);
        }
    }
    const size_t e = (size_t)q8 * 1024 + 4 * tid;
    float4 st = make_float4(0.f, 0.f, 0.f, 0.f);
    const int c0 = dir ? 0 : 1;
    ushort4 u = *(const ushort4*)&U[((size_t)c0 * 16 + h) * 8192 + e];
    for (int c = c0; c < 32; ++c) {
        ushort4 un = make_ushort4(0, 0, 0, 0);
        if (c + 1 < 32) un = *(const ushort4*)&U[((size_t)(c + 1) * 16 + h) * 8192 + e];
        float Dc = __expf(cum[h * 2048 + c * 64 + 63]);
        ushort4 o = make_ushort4(f2bf(st.x), f2bf(st.y), f2bf(st.z), f2bf(st.w));
        *(ushort4*)&T[(size_t)c * 8192 + e] = o;
        st.x = Dc * st.x + bfu(u.x);
        st.y = Dc * st.y + bfu(u.y);
        st.z = Dc * st.z + bfu(u.z);
        st.w = Dc * st.w + bfu(u.w);
        u = un;
    }
}

// ---------------- batch-shared Yt = C . T^T ----------------

__global__ __launch_bounds__(256) void yt_kernel(
    const unsigned short* __restrict__ bcF, const unsigned short* __restrict__ bcB,
    const unsigned short* __restrict__ Tst,
    unsigned short* __restrict__ YtF, unsigned short* __restrict__ YtB) {
    const int iid = blockIdx.x;   // 1008
    int dir, h, c;
    if (iid < 496) { dir = 0; c = 1 + (iid >> 4); h = iid & 15; }
    else           { int k = iid - 496; dir = 1; c = k >> 4; h = k & 15; }
    const unsigned short* Cbase = (dir == 0)
        ? bcF + ((size_t)(64 * c - 3)) * 256 + 128
        : bcB + ((size_t)(64 * c)) * 256 + 128;
    const unsigned short* Tp = Tst + ((size_t)(dir * 16 + h) * 32 + c) * 8192;
    unsigned short* Yt = (dir == 0 ? YtF : YtB) + (size_t)(c * 16 + h) * 4096;
    const int tid = threadIdx.x;
    const int lane = tid & 63, wave = tid >> 6;
    const int quad = lane >> 4, l15 = lane & 15;
    const int pm = (wave >> 1) * 32, tb = (wave & 1) * 32;
    f32x4 acc[2][2];
#pragma unroll
    for (int i = 0; i < 2; ++i)
#pragma unroll
        for (int j = 0; j < 2; ++j) acc[i][j] = (f32x4){0.f, 0.f, 0.f, 0.f};
#pragma unroll
    for (int ks = 0; ks < 4; ++ks) {
        bf16x8 af[2], bfr[2];
#pragma unroll
        for (int i = 0; i < 2; ++i)
            af[i] = *(const bf16x8*)&Tp[(size_t)(pm + i * 16 + l15) * 128 + ks * 32 + quad * 8];
#pragma unroll
        for (int j = 0; j < 2; ++j)
            bfr[j] = *(const bf16x8*)&Cbase[(size_t)(tb + j * 16 + l15) * 256 + ks * 32 + quad * 8];
#pragma unroll
        for (int i = 0; i < 2; ++i)
#pragma unroll
            for (int j = 0; j < 2; ++j)
                acc[i][j] = __builtin_amdgcn_mfma_f32_16x16x32_bf16(af[i], bfr[j], acc[i][j], 0, 0, 0);
    }
#pragma unroll
    for (int i = 0; i < 2; ++i)
#pragma unroll
        for (int j = 0; j < 2; ++j) {
            int t = tb + j * 16 + l15;
            int p0 = pm + i * 16 + quad * 4;
            ushort4 o = make_ushort4(f2bf(acc[i][j][0]), f2bf(acc[i][j][1]),
                                     f2bf(acc[i][j][2]), f2bf(acc[i][j][3]));
            *(ushort4*)&Yt[t * 64 + p0] = o;
        }
}

// ---------------- gate kernel: 4 chunks/block, M fragments cached in regs ----------------

__global__ __launch_bounds__(256) void gate_kernel(
    const unsigned short* __restrict__ bcF,
    const unsigned short* __restrict__ Mb, const float* __restrict__ psiF,
    const unsigned short* __restrict__ YtF, const unsigned short* __restrict__ YtB,
    const unsigned short* __restrict__ xF16, const unsigned short* __restrict__ xFp16,
    const unsigned short* __restrict__ xB16,
    const unsigned short* __restrict__ szF, const unsigned short* __restrict__ szB,
    const float* __restrict__ convFp,
    const float* __restrict__ cumF, const float* __restrict__ cumB,
    const unsigned short* __restrict__ YiF0, const unsigned short* __restrict__ YiFs,
    const unsigned short* __restrict__ YiB,
    const float* __restrict__ cb0,
    const float* __restrict__ fD, const float* __restrict__ bD,
    const float* __restrict__ wf2, const float* __restrict__ wb2,
    float* __restrict__ aF, float* __restrict__ aB) {
    __shared__ __align__(16) float Ysm[64 * 68];

    const int iid = blockIdx.x;   // 1152: fwd 1024 (b,h,cg), bwd 128 (h,cg)
    int dir, b = 0, h, cg;
    if (iid < 1024) { dir = 0; b = iid >> 7; int r = iid & 127; h = r >> 3; cg = r & 7; }
    else            { int k = iid - 1024; dir = 1; h = k >> 3; cg = k & 7; }
    const int tid = threadIdx.x, tx = tid & 15, ty = tid >> 4;
    const int lane = tid & 63, wave = tid >> 6;
    const int quad = lane >> 4, l15 = lane & 15;

    const float Dh = (dir ? bD : fD)[h];
    const float* wvp = dir ? wb2 : wf2;
    float4 wreg = *(const float4*)&wvp[h * 64 + tx * 4];
    const float* cumA = dir ? cumB : cumF;

    const int pm = (wave >> 1) * 32, tb = (wave & 1) * 32;
    bf16x8 mfr[4][2];
    if (dir == 0) {
        const unsigned short* Mp = Mb + (size_t)(b * 16 + h) * 8192;
#pragma unroll
        for (int ks = 0; ks < 4; ++ks)
#pragma unroll
            for (int i = 0; i < 2; ++i)
                mfr[ks][i] = *(const bf16x8*)&Mp[(size_t)(pm + i * 16 + l15) * 128 + ks * 32 + quad * 8];
    }

    for (int cc = 0; cc < 4; ++cc) {
        const int c = cg * 4 + cc;
        const bool fwdG = (dir == 0 && c > 0);
        if (fwdG) {
            if (cc > 0) __syncthreads();   // prior epilogue done reading Ysm
            const unsigned short* Cbase = bcF + ((size_t)(64 * c - 3)) * 256 + 128;
            f32x4 acc[2][2];
#pragma unroll
            for (int i = 0; i < 2; ++i)
#pragma unroll
                for (int j = 0; j < 2; ++j) acc[i][j] = (f32x4){0.f, 0.f, 0.f, 0.f};
#pragma unroll
            for (int ks = 0; ks < 4; ++ks) {
                bf16x8 bfr[2];
#pragma unroll
                for (int j = 0; j < 2; ++j)
                    bfr[j] = *(const bf16x8*)&Cbase[(size_t)(tb + j * 16 + l15) * 256 + ks * 32 + quad * 8];
#pragma unroll
                for (int i = 0; i < 2; ++i)
#pragma unroll
                    for (int j = 0; j < 2; ++j)
                        acc[i][j] = __builtin_amdgcn_mfma_f32_16x16x32_bf16(mfr[ks][i], bfr[j], acc[i][j], 0, 0, 0);
            }
#pragma unroll
            for (int i = 0; i < 2; ++i)
#pragma unroll
                for (int j = 0; j < 2; ++j)
                    *(f32x4*)&Ysm[(tb + j * 16 + l15) * 68 + pm + i * 16 + quad * 4] = acc[i][j];
            __syncthreads();
        }

        const float psi = fwdG ? psiF[h * 32 + c] : 0.f;
        const unsigned short* Ytp = fwdG ? (YtF + (size_t)(c * 16 + h) * 4096)
                                         : (dir ? (YtB + (size_t)(c * 16 + h) * 4096) : nullptr);
        float4 x0v = make_float4(0.f, 0.f, 0.f, 0.f);
        float cbv[4] = {0.f, 0.f, 0.f, 0.f};
        if (dir == 0 && c == 0) {
            x0v = *(const float4*)&convFp[(size_t)(b * 4) * CONVD + h * 64 + tx * 4];
#pragma unroll
            for (int i = 0; i < 4; ++i) cbv[i] = cb0[(b * 16 + h) * 64 + (ty + 16 * i)];
        }

        float rawet[4];
        ushort4 yi4a[4], x4a[4], z4a[4], yt4a[4];
        float4 cm4a[4];
#pragma unroll
        for (int i = 0; i < 4; ++i) {
            int tl = ty + 16 * i;
            int j = 64 * c + tl;
            rawet[i] = cumA[h * 2048 + j];
            const unsigned short *Yi, *xp, *zp;
            if (dir == 0) {
                Yi = (c == 0) ? YiF0 + (size_t)(b * 16 + h) * 4096 : YiFs + (size_t)(c * 16 + h) * 4096;
                if (c == 0) {
                    int t = j + 1;
                    xp = (t < 4) ? xFp16 + (size_t)(b * 4 + t) * 1024 : xF16 + (size_t)(t - 4) * 1024;
                } else {
                    xp = xF16 + (size_t)(64 * c + tl - 3) * 1024;
                }
                zp = szF + (size_t)j * 1024;
            } else {
                Yi = YiB + (size_t)(c * 16 + h) * 4096;
                xp = xB16 + (size_t)j * 1024;
                zp = szB + (size_t)(2047 - j) * 1024;
            }
            yi4a[i] = *(const ushort4*)&Yi[tl * 64 + tx * 4];
            x4a[i] = *(const ushort4*)&xp[h * 64 + tx * 4];
            z4a[i] = *(const ushort4*)&zp[h * 64 + tx * 4];
            yt4a[i] = Ytp ? *(const ushort4*)&Ytp[tl * 64 + tx * 4] : make_ushort4(0, 0, 0, 0);
            cm4a[i] = fwdG ? *(const float4*)&Ysm[tl * 68 + tx * 4] : make_float4(0.f, 0.f, 0.f, 0.f);
        }

#pragma unroll
        for (int i = 0; i < 4; ++i) {
            int j = 64 * c + ty + 16 * i;
            float et = __expf(rawet[i]);
            float yv[4] = {bfu(yi4a[i].x), bfu(yi4a[i].y), bfu(yi4a[i].z), bfu(yi4a[i].w)};
            float xa[4] = {bfu(x4a[i].x), bfu(x4a[i].y), bfu(x4a[i].z), bfu(x4a[i].w)};
            float sza[4] = {h2f(z4a[i].x), h2f(z4a[i].y), h2f(z4a[i].z), h2f(z4a[i].w)};
            float ya[4] = {bfu(yt4a[i].x) + psi * cm4a[i].x, bfu(yt4a[i].y) + psi * cm4a[i].y,
                           bfu(yt4a[i].z) + psi * cm4a[i].z, bfu(yt4a[i].w) + psi * cm4a[i].w};
            float x0a[4] = {x0v.x, x0v.y, x0v.z, x0v.w};
            float wa[4] = {wreg.x, wreg.y, wreg.z, wreg.w};
            float a1 = 0.f, a2 = 0.f;
#pragma unroll
            for (int w = 0; w < 4; ++w) {
                float tot = yv[w] + et * (ya[w] + cbv[i] * x0a[w]) + Dh * xa[w];
                float g = tot * sza[w];
                a1 += g * wa[w];
                a2 += g * g;
            }
#pragma unroll
            for (int m = 1; m < 16; m <<= 1) {
                a1 += __shfl_xor(a1, m);
                a2 += __shfl_xor(a2, m);
            }
            if (tx == 0) {
                if (dir == 0) {
                    size_t o = ((size_t)(b * 2048 + j) * 16 + h) * 2;
                    aF[o] = a1; aF[o + 1] = a2;
                } else {
                    int g = 2047 - j;
                    size_t o = ((size_t)g * 16 + h) * 2;
                    aB[o] = a1; aB[o + 1] = a2;
                }
            }
        }
    }
}

// ---------------- final combine ----------------

__global__ void final_kernel(const float* __restrict__ aF, const float* __restrict__ aB,
                             const float* __restrict__ headB, float* __restrict__ out) {
    int idx = blockIdx.x * 256 + threadIdx.x;   // 16384
    int b = idx >> 11, g = idx & 2047;
    const float* pf = aF + ((size_t)(b * 2048 + g)) * 32;
    const float* pb = aB + (size_t)g * 32;
    float f1 = 0.f, f2 = 0.f, b1 = 0.f, b2 = 0.f;
#pragma unroll
    for (int h = 0; h < 16; ++h) {
        f1 += pf[2 * h]; f2 += pf[2 * h + 1];
        b1 += pb[2 * h]; b2 += pb[2 * h + 1];
    }
    out[idx] = f1 * rsqrtf(f2 * (1.f / 1024.f) + 1e-5f) +
               b1 * rsqrtf(b2 * (1.f / 1024.f) + 1e-5f) + headB[0];
}

// ---------------- launch ----------------

extern "C" void kernel_launch(void* const* d_in, const int* in_sizes, int n_in,
                              void* d_out, int out_size, void* d_ws, size_t ws_size,
                              hipStream_t stream) {
    const int*   pidx   = (const int*)  d_in[0];
    const int*   chridx = (const int*)  d_in[1];
    const float* locusF = (const float*)d_in[2];
    const float* pathF  = (const float*)d_in[3];
    const float* pertE  = (const float*)d_in[4];
    const float* gidE   = (const float*)d_in[5];
    const float* chrE   = (const float*)d_in[6];
    const float* locusW = (const float*)d_in[7];
    const float* locusB = (const float*)d_in[8];
    const float* condW  = (const float*)d_in[9];
    const float* condB  = (const float*)d_in[10];
    const float* inW    = (const float*)d_in[11];
    const float* inB    = (const float*)d_in[12];
    const float* headW  = (const float*)d_in[13];
    const float* headB  = (const float*)d_in[14];
    const float* fInW   = (const float*)d_in[15];
    const float* fCw    = (const float*)d_in[16];
    const float* fCb    = (const float*)d_in[17];
    const float* fDtB   = (const float*)d_in[18];
    const float* fAlog  = (const float*)d_in[19];
    const float* fDp    = (const float*)d_in[20];
    const float* fNw    = (const float*)d_in[21];
    const float* fOutW  = (const float*)d_in[22];
    const float* bInW   = (const float*)d_in[23];
    const float* bCw    = (const float*)d_in[24];
    const float* bCb    = (const float*)d_in[25];
    const float* bDtB   = (const float*)d_in[26];
    const float* bAlog  = (const float*)d_in[27];
    const float* bDp    = (const float*)d_in[28];
    const float* bNw    = (const float*)d_in[29];
    const float* bOutW  = (const float*)d_in[30];
    float* out = (float*)d_out;
    (void)in_sizes; (void)n_in; (void)out_size; (void)ws_size;

    char* base = (char*)d_ws;
    size_t off = 0;
    auto allocf = [&](size_t n) -> float* {
        char* r = base + off; off += ((n * 4 + 63) & ~(size_t)63); return (float*)r; };
    auto allocu = [&](size_t n) -> unsigned short* {
        char* r = base + off; off += ((n * 2 + 63) & ~(size_t)63); return (unsigned short*)r; };

    float* gf     = allocf(2048UL * 384);
    float* cond   = allocf(8UL * 384);
    float* cemb   = allocf(8UL * 128);
    float* ug     = allocf(2048UL * 512);
    float* uc     = allocf(8UL * 512);
    float* zxf    = allocf(2048UL * DPROJ);
    float* zxb    = allocf(2048UL * DPROJ);
    float* zxc    = allocf(8UL * DPROJ);
    float* convFp = allocf(8UL * 4 * CONVD);
    float* dtFsT  = allocf(16UL * 2048);
    float* dtFp   = allocf(128);
    float* dtBsT  = allocf(16UL * 2048);
    float* cumF   = allocf(16UL * 2048);
    float* cumB   = allocf(16UL * 2048);
    float* wf2    = allocf(1024);
    float* wb2    = allocf(1024);
    float* cb0    = allocf(8UL * 16 * 64);
    float* psiF   = allocf(16UL * 32);
    float* aF     = allocf(8UL * 2048 * 16 * 2);
    float* aB     = allocf(2048UL * 16 * 2);
    unsigned short* YiF0 = allocu(8UL * 16 * 4096);
    unsigned short* YiFs = allocu(32UL * 16 * 4096);
    unsigned short* YiB  = allocu(32UL * 16 * 4096);
    unsigned short* UF0  = allocu(8UL * 16 * 8192);
    unsigned short* UFs  = allocu(32UL * 16 * 8192);
    unsigned short* UB   = allocu(32UL * 16 * 8192);
    unsigned short* Mb   = allocu(8UL * 16 * 8192);
    unsigned short* Tst  = allocu(2UL * 16 * 32 * 8192);
    unsigned short* bcF  = allocu(2045UL * 256);
    unsigned short* bcFp = allocu(32UL * 256);
    unsigned short* bcB  = allocu(2048UL * 256);
    unsigned short* YtF  = allocu(32UL * 16 * 4096);
    unsigned short* YtB  = allocu(32UL * 16 * 4096);
    unsigned short* xF16 = allocu(2045UL * 1024);
    unsigned short* xFp16= allocu(32UL * 1024);
    unsigned short* xB16 = allocu(2048UL * 1024);
    unsigned short* szF  = allocu(2048UL * 1024);
    unsigned short* szB  = allocu(2048UL * 1024);
    unsigned short* gf2   = allocu(2048UL * 384);
    unsigned short* inW2  = allocu(512UL * 384);
    unsigned short* ug2   = allocu(2048UL * 512);
    unsigned short* fInW2 = allocu(2432UL * 512);
    unsigned short* bInW2 = allocu(2432UL * 512);

    gg_kernel<<<3077, 256, 0, stream>>>(chridx, gidE, pathF, chrE, pidx, pertE, gf, cemb, wf2, wb2);
    wfold_kernel<<<128, 256, 0, stream>>>(headW, fOutW, fNw, bOutW, bNw, wf2, wb2);
    gemm_kernel<<<dim3(1, 32), 256, 0, stream>>>(locusF, locusW, locusB, gf + 320, 2048, 64, 64, 384, 1);
    gemm_kernel<<<dim3(6, 1), 256, 0, stream>>>(cemb, condW, condB, cond, 8, 384, 128, 384, 0);

    tobf4_kernel<<<13568, 256, 0, stream>>>(inW, fInW, bInW, gf, inW2, fInW2, bInW2, gf2);

    mfma_gemm_kernel<<<dim3(4, 16), 256, 0, stream>>>(gf2, inW2, inB, ug, 512, 384, 512);
    gemm_kernel<<<dim3(8, 1), 256, 0, stream>>>(cond, inW, inB, uc, 8, 512, 384, 512, 0);

    tobf_kernel<<<(2048 * 512 + 255) / 256, 256, 0, stream>>>(ug, ug2, 2048, 512, 2048);
    mfma_gemm_kernel<<<dim3(19, 16), 256, 0, stream>>>(ug2, fInW2, nullptr, zxf, 2320, 512, 2320);
    mfma_gemm_kernel<<<dim3(19, 16), 256, 0, stream>>>(ug2, bInW2, nullptr, zxb, 2320, 512, 2320);
    gemm_kernel<<<dim3(37, 1), 256, 0, stream>>>(uc, fInW, nullptr, zxc, 8, DPROJ, 512, DPROJ, 0);

    elem_kernel<<<16641, 256, 0, stream>>>(zxf, zxb, zxc, fDtB, bDtB, szF, szB, dtFsT, dtBsT, dtFp);
    cum_kernel<<<4, 256, 0, stream>>>(dtFsT, dtBsT, fAlog, bAlog, cumF, cumB);
    convFsh_kernel<<<(2045 * 1280 + 255) / 256, 256, 0, stream>>>(zxf, fCw, fCb, bcF, xF16);
    convFpb_kernel<<<160, 256, 0, stream>>>(zxf, zxc, fCw, fCb, convFp, bcFp, xFp16);
    convBsh_kernel<<<10240, 256, 0, stream>>>(zxb, bCw, bCb, bcB, xB16);
    intra_kernel<<<1136, 256, 0, stream>>>(bcF, bcFp, bcB, xF16, xFp16, xB16,
                                           dtFsT, dtBsT, cumF, cumB,
                                           YiF0, YiFs, YiB, UF0, UFs, UB);
    cbm_kernel<<<160, 256, 0, stream>>>(convFp, bcF, dtFp, cumF, UF0, cb0, Mb);
    tpsi_kernel<<<256, 256, 0, stream>>>(UFs, UB, cumF, cumB, Tst, psiF);
    yt_kernel<<<1008, 256, 0, stream>>>(bcF, bcB, Tst, YtF, YtB);
    gate_kernel<<<1152, 256, 0, stream>>>(bcF, Mb, psiF, YtF, YtB, xF16, xFp16, xB16,
                                          szF, szB, convFp, cumF, cumB,
                                          YiF0, YiFs, YiB, cb0, fDp, bDp, wf2, wb2, aF, aB);
    final_kernel<<<64, 256, 0, stream>>>(aF, aB, headB, out);
}